// Round 4
// baseline (2651.022 us; speedup 1.0000x reference)
//
#include <hip/hip_runtime.h>

namespace {
constexpr int G_  = 2048;
constexpr int HID = 128;
constexpr int NVv = 500000, NIv = 300000, NTv = 50000, NAv = 50000, NSv = 10000;
constexpr int EVTv = 500000, EIVv = 1500000, EVIv = 1500000, EVAv = 500000, ETSv = 50000, EIIv = 600000;
// concatenated per-(edge-type,dst-node) CSR space
constexpr int OFF_VT = 0;
constexpr int OFF_IV = OFF_VT + NTv;          // 50000
constexpr int OFF_VI = OFF_IV + NVv;          // 550000
constexpr int OFF_VA = OFF_VI + NIv;          // 850000
constexpr int OFF_TS = OFF_VA + NAv;          // 900000
constexpr int OFF_II = OFF_TS + NSv;          // 910000
constexpr int TOT_N  = OFF_II + NIv;          // 1210000
constexpr int TOT_E  = EVTv + EIVv + EVIv + EVAv + ETSv + EIIv;  // 4650000
constexpr int NCH    = (TOT_N + 1023) / 1024; // 1182
}

typedef short s16x8 __attribute__((ext_vector_type(8)));
typedef float f32x4 __attribute__((ext_vector_type(4)));

__device__ __forceinline__ float4 ld4(const float* p) { return *(const float4*)p; }

__device__ __forceinline__ unsigned short f2bf(float x) {
    unsigned u = __float_as_uint(x);
    u += 0x7fffu + ((u >> 16) & 1u);
    return (unsigned short)(u >> 16);
}

// ---------------------------------------------------------------------------
// CSR build
// ---------------------------------------------------------------------------
__global__ __launch_bounds__(256)
void edge_hist(const int* __restrict__ dst, int* __restrict__ deg, int off, int E)
{
    int i = blockIdx.x * 256 + threadIdx.x;
    if (i < E) atomicAdd(&deg[off + dst[i]], 1);
}

__global__ __launch_bounds__(256)
void scan_chunk_sum(const int* __restrict__ deg, int* __restrict__ csum)
{
    __shared__ int sc[256];
    int blk = blockIdx.x, tid = threadIdx.x;
    int base = blk * 1024 + tid * 4;
    int s = 0;
#pragma unroll
    for (int k = 0; k < 4; ++k) { int idx = base + k; if (idx < TOT_N) s += deg[idx]; }
    sc[tid] = s; __syncthreads();
    for (int d = 128; d > 0; d >>= 1) {
        if (tid < d) sc[tid] += sc[tid + d];
        __syncthreads();
    }
    if (tid == 0) csum[blk] = sc[0];
}

__global__ __launch_bounds__(256)
void scan_offsets(const int* __restrict__ csum, int* __restrict__ coff)
{
    __shared__ int sc[256];
    int tid = threadIdx.x;
    int s[5]; int tsum = 0;
#pragma unroll
    for (int k = 0; k < 5; ++k) { int idx = tid * 5 + k; s[k] = (idx < NCH) ? csum[idx] : 0; tsum += s[k]; }
    sc[tid] = tsum; __syncthreads();
    for (int d = 1; d < 256; d <<= 1) {
        int v = (tid >= d) ? sc[tid - d] : 0;
        __syncthreads();
        sc[tid] += v;
        __syncthreads();
    }
    int run = sc[tid] - tsum;   // exclusive
#pragma unroll
    for (int k = 0; k < 5; ++k) { int idx = tid * 5 + k; if (idx < NCH) coff[idx] = run; run += s[k]; }
}

__global__ __launch_bounds__(256)
void scan_write(const int* __restrict__ deg, const int* __restrict__ coff, int* __restrict__ cur)
{
    __shared__ int sc[256];
    int blk = blockIdx.x, tid = threadIdx.x;
    int base = blk * 1024 + tid * 4;
    int v[4]; int tsum = 0;
#pragma unroll
    for (int k = 0; k < 4; ++k) { int idx = base + k; v[k] = (idx < TOT_N) ? deg[idx] : 0; tsum += v[k]; }
    sc[tid] = tsum; __syncthreads();
    for (int d = 1; d < 256; d <<= 1) {
        int t = (tid >= d) ? sc[tid - d] : 0;
        __syncthreads();
        sc[tid] += t;
        __syncthreads();
    }
    int run = coff[blk] + sc[tid] - tsum;   // global exclusive prefix
#pragma unroll
    for (int k = 0; k < 4; ++k) { int idx = base + k; if (idx < TOT_N) cur[idx] = run; run += v[k]; }
}

__global__ __launch_bounds__(256)
void edge_pos(const int* __restrict__ src, const int* __restrict__ dst,
              int* __restrict__ cur, int2* __restrict__ epair, int off, int E)
{
    int i = blockIdx.x * 256 + threadIdx.x;
    if (i < E) {
        int d = dst[i];
        int p = atomicAdd(&cur[off + d], 1);
        epair[p] = make_int2(src[i], d);
    }
}

__global__ __launch_bounds__(256)
void batch_count(const int* __restrict__ batch, float* __restrict__ cnt, int N)
{
    int i = blockIdx.x * 256 + threadIdx.x;
    if (i < N) atomicAdd(&cnt[batch[i]], 1.0f);
}

// ---------------------------------------------------------------------------
// Weight prep: out[n*K1+k] = bf16 of W1[k][n], W1 rows = [S0(L0) | S1(L1) | S2(+S2b)]
// ---------------------------------------------------------------------------
__global__ __launch_bounds__(256)
void prep_wt(const float* __restrict__ S0, int L0,
             const float* __restrict__ S1, int L1,
             const float* __restrict__ S2, const float* __restrict__ S2b,
             unsigned short* __restrict__ out, int K1)
{
    int i = blockIdx.x * 256 + threadIdx.x;
    if (i >= 128 * K1) return;
    int n = i / K1, k = i - n * K1;
    float v;
    if (k < L0) v = S0[k * 128 + n];
    else if (k < L0 + L1) v = S1[(k - L0) * 128 + n];
    else {
        int kk = k - L0 - L1;
        v = S2[kk * 128 + n];
        if (S2b) v += S2b[kk * 128 + n];
    }
    out[i] = f2bf(v);
}

// ---------------------------------------------------------------------------
// Edge-parallel gather into LDS fp32 tile via atomics. Work item =
// (local edge, 16B chunk); 4 items per thread per loop iter -> high MLP.
// ---------------------------------------------------------------------------
template<int DSa, int GCOL, int COFF>
__device__ __forceinline__ void gather_accum(float* __restrict__ facc,
                                             const int2* __restrict__ epair,
                                             int base, int end,
                                             const float* __restrict__ xs,
                                             int node0, int tid)
{
    constexpr int CPR = DSa / 4;            // float4 chunks per source row
    constexpr int LOG = (CPR == 16) ? 4 : 3;
    const int W = (end - base) * CPR;
    for (int it0 = tid * 4; it0 < W; it0 += 1024) {
        float4 v[4]; int ra[4]; int ca[4]; bool ok[4];
#pragma unroll
        for (int k = 0; k < 4; ++k) {
            int item = it0 + k;
            ok[k] = item < W;
            if (ok[k]) {
                int e  = item >> LOG;
                int ch = item & (CPR - 1);
                int2 sd = epair[base + e];
                ra[k] = sd.y - node0;
                ca[k] = ch * 4;
                v[k]  = ld4(&xs[sd.x * DSa + ch * 4]);
            }
        }
#pragma unroll
        for (int k = 0; k < 4; ++k) {
            if (ok[k]) {
                float* p = &facc[ra[k] * GCOL + COFF + ca[k]];
                atomicAdd(p + 0, v[k].x); atomicAdd(p + 1, v[k].y);
                atomicAdd(p + 2, v[k].z); atomicAdd(p + 3, v[k].w);
            }
        }
    }
}

// ---------------------------------------------------------------------------
// Fused CSR-gather + MFMA node kernel. Block = 256 thr (4 waves), 64 nodes.
// Phase 1: edge-parallel fp32 gather into LDS (atomics).
// Phase 2: divide by deg, bf16-convert into swizzled A-tile (aliases fp32 tile).
// Phase 3: h = relu(A @ W1 + b1) -> bf16 LDS -> z = h @ nW + nb -> pooled atomics.
// ---------------------------------------------------------------------------
template<int DSa, int DD, bool HAS2, int ASTR, int K1>
__global__ __launch_bounds__(256)
void sage_mfma(const int* __restrict__ deg, const int* __restrict__ cur,
               const int2* __restrict__ epair, int off1, int off2,
               const float* __restrict__ xs1, const float* __restrict__ xs2,
               const float* __restrict__ xd,
               const unsigned short* __restrict__ W1T,
               const float* __restrict__ bl, const float* __restrict__ bl2,
               const unsigned short* __restrict__ nWT,
               const float* __restrict__ nbp,
               const int* __restrict__ batch,
               float* __restrict__ pool_sum, int N)
{
    constexpr int KST  = K1 / 32;
    constexpr int XOFF = HAS2 ? 2 * DSa : DSa;
    constexpr int GCOL = HAS2 ? 2 * DSa : DSa;   // gathered columns
    constexpr int UB   = (64 * GCOL * 4 > 64 * ASTR * 2) ? 64 * GCOL * 4 : 64 * ASTR * 2;

    __shared__ __align__(16) char u_sh[UB];          // fp32 gather tile, then bf16 A-tile
    __shared__ __align__(16) unsigned short h_sh[64 * 128];
    __shared__ float invd1[64];
    __shared__ float invd2[HAS2 ? 64 : 4];

    float* facc = (float*)u_sh;
    unsigned short* a_sh = (unsigned short*)u_sh;

    const int tid    = threadIdx.x;
    const int node0  = blockIdx.x * 64;
    const int nvalid = min(64, N - node0);

    // ---- zero fp32 tile + per-row inverse degrees ----
#pragma unroll
    for (int i = tid; i < 64 * GCOL / 4; i += 256)
        ((float4*)facc)[i] = make_float4(0.f, 0.f, 0.f, 0.f);
    if (tid < 64) {
        int n = node0 + tid;
        invd1[tid] = (n < N) ? 1.0f / fmaxf((float)deg[off1 + n], 1.0f) : 0.f;
        if constexpr (HAS2)
            invd2[tid] = (n < N) ? 1.0f / fmaxf((float)deg[off2 + n], 1.0f) : 0.f;
    }
    __syncthreads();

    // ---- phase 1: edge-parallel gather (CSR rows for these 64 nodes are contiguous) ----
    {
        int last  = node0 + nvalid - 1;
        int base1 = cur[off1 + node0] - deg[off1 + node0];
        int end1  = cur[off1 + last];
        gather_accum<DSa, GCOL, 0>(facc, epair, base1, end1, xs1, node0, tid);
        if constexpr (HAS2) {
            int base2 = cur[off2 + node0] - deg[off2 + node0];
            int end2  = cur[off2 + last];
            gather_accum<DSa, GCOL, DSa>(facc, epair, base2, end2, xs2, node0, tid);
        }
    }
    __syncthreads();

    // ---- phase 2: stage fp32 tile to regs, then rewrite as swizzled bf16 A-tile ----
    constexpr int NF4  = GCOL / 16;         // float4s per thread from gather tile
    const int r_st = tid >> 2;
    const int c_st = (tid & 3) * (GCOL / 4);
    float4 st[NF4];
#pragma unroll
    for (int k = 0; k < NF4; ++k)
        st[k] = ((const float4*)&facc[r_st * GCOL + c_st])[k];
    float inv_a = (!HAS2 || c_st < DSa) ? invd1[r_st] : invd2[r_st];

    constexpr int DCH = 64 * (DD / 4) / 256;   // x_dst float4 chunks per thread
    float4 xv[DCH]; int xr[DCH], xc[DCH];
#pragma unroll
    for (int j = 0; j < DCH; ++j) {
        int c = j * 256 + tid;
        int r = c / (DD / 4);
        int col4 = (c - r * (DD / 4)) * 4;
        xr[j] = r; xc[j] = col4;
        int node = node0 + r;
        xv[j] = (node < N) ? ld4(&xd[node * DD + col4]) : make_float4(0.f, 0.f, 0.f, 0.f);
    }
    __syncthreads();   // all facc reads done before a_sh overwrites

#pragma unroll
    for (int k = 0; k < NF4; ++k) {
        float4 v = st[k];
        v.x *= inv_a; v.y *= inv_a; v.z *= inv_a; v.w *= inv_a;
        int col = c_st + k * 4;
        unsigned p0 = (unsigned)f2bf(v.x) | ((unsigned)f2bf(v.y) << 16);
        unsigned p1 = (unsigned)f2bf(v.z) | ((unsigned)f2bf(v.w) << 16);
        unsigned byte = ((unsigned)(r_st * ASTR + col) * 2u) ^ ((unsigned)(r_st & 7) << 4);
        *(uint2*)((char*)a_sh + byte) = make_uint2(p0, p1);
    }
#pragma unroll
    for (int j = 0; j < DCH; ++j) {
        int col = XOFF + xc[j];
        unsigned p0 = (unsigned)f2bf(xv[j].x) | ((unsigned)f2bf(xv[j].y) << 16);
        unsigned p1 = (unsigned)f2bf(xv[j].z) | ((unsigned)f2bf(xv[j].w) << 16);
        unsigned byte = ((unsigned)(xr[j] * ASTR + col) * 2u) ^ ((unsigned)(xr[j] & 7) << 4);
        *(uint2*)((char*)a_sh + byte) = make_uint2(p0, p1);
    }
    __syncthreads();

    const int w  = tid >> 6;
    const int l  = tid & 63;
    const int lg = l >> 4;
    const int lr = l & 15;
    const int rowA = w * 16 + lr;
    const unsigned swz = (unsigned)(rowA & 7) << 4;

    // ---- stage 1: h = A @ W1 ----
    f32x4 acc[8];
#pragma unroll
    for (int nb = 0; nb < 8; ++nb) acc[nb] = (f32x4){0.f, 0.f, 0.f, 0.f};

#pragma unroll
    for (int ks = 0; ks < KST; ++ks) {
        s16x8 af = *(const s16x8*)((const char*)a_sh +
                     (((unsigned)(rowA * ASTR + ks * 32 + lg * 8) * 2u) ^ swz));
#pragma unroll
        for (int nb = 0; nb < 8; ++nb) {
            s16x8 bf = *(const s16x8*)&W1T[(nb * 16 + lr) * K1 + ks * 32 + lg * 8];
            acc[nb] = __builtin_amdgcn_mfma_f32_16x16x32_bf16(af, bf, acc[nb], 0, 0, 0);
        }
    }

    // ---- bias + relu -> bf16 h in LDS ----
#pragma unroll
    for (int nb = 0; nb < 8; ++nb) {
        int col = nb * 16 + lr;
        float b = bl[col];
        if constexpr (HAS2) b += bl2[col];
#pragma unroll
        for (int rg = 0; rg < 4; ++rg) {
            float hv = fmaxf(acc[nb][rg] + b, 0.0f);
            int row = w * 16 + lg * 4 + rg;
            unsigned byte = ((unsigned)(row * 128 + col) * 2u) ^ ((unsigned)(row & 7) << 4);
            *(unsigned short*)((char*)h_sh + byte) = f2bf(hv);
        }
    }
    __syncthreads();

    // ---- stage 2: z = h @ nW ----
    f32x4 acc2[8];
#pragma unroll
    for (int nb = 0; nb < 8; ++nb) acc2[nb] = (f32x4){0.f, 0.f, 0.f, 0.f};

#pragma unroll
    for (int ks = 0; ks < 4; ++ks) {
        s16x8 hf = *(const s16x8*)((const char*)h_sh +
                     (((unsigned)(rowA * 128 + ks * 32 + lg * 8) * 2u) ^ swz));
#pragma unroll
        for (int nb = 0; nb < 8; ++nb) {
            s16x8 bf = *(const s16x8*)&nWT[(nb * 16 + lr) * 128 + ks * 32 + lg * 8];
            acc2[nb] = __builtin_amdgcn_mfma_f32_16x16x32_bf16(hf, bf, acc2[nb], 0, 0, 0);
        }
    }

    // ---- pool: run-length reduce over 4 consecutive rows, then atomics ----
    const int base = node0 + w * 16 + lg * 4;
    float nbias[8];
#pragma unroll
    for (int nb = 0; nb < 8; ++nb) nbias[nb] = nbp[nb * 16 + lr];

    int bt[4];
#pragma unroll
    for (int rg = 0; rg < 4; ++rg) bt[rg] = (base + rg < N) ? batch[base + rg] : -1;

    float run[8];
    int cb = bt[0];
#pragma unroll
    for (int nb = 0; nb < 8; ++nb) run[nb] = acc2[nb][0] + nbias[nb];
#pragma unroll
    for (int rg = 1; rg < 4; ++rg) {
        if (bt[rg] == cb) {
#pragma unroll
            for (int nb = 0; nb < 8; ++nb) run[nb] += acc2[nb][rg] + nbias[nb];
        } else {
            if (cb >= 0) {
#pragma unroll
                for (int nb = 0; nb < 8; ++nb)
                    atomicAdd(&pool_sum[cb * 128 + nb * 16 + lr], run[nb]);
            }
            cb = bt[rg];
#pragma unroll
            for (int nb = 0; nb < 8; ++nb) run[nb] = acc2[nb][rg] + nbias[nb];
        }
    }
    if (cb >= 0) {
#pragma unroll
        for (int nb = 0; nb < 8; ++nb)
            atomicAdd(&pool_sum[cb * 128 + nb * 16 + lr], run[nb]);
    }
}

// ---------------------------------------------------------------------------
__global__ __launch_bounds__(64)
void final_kernel(const float* __restrict__ pool_sum, const float* __restrict__ pool_cnt,
                  const float* __restrict__ gW, const float* __restrict__ gb,
                  float* __restrict__ out)
{
    __shared__ float p_sh[5 * HID];
    int g = blockIdx.x, tid = threadIdx.x;
    for (int i = tid; i < 5 * HID; i += 64) {
        int t  = i >> 7;
        int jj = i & 127;
        float c = fmaxf(pool_cnt[t * G_ + g], 1.0f);
        p_sh[i] = pool_sum[((size_t)t * G_ + g) * HID + jj] / c;
    }
    __syncthreads();
    float acc = gb[tid];
#pragma unroll 8
    for (int k = 0; k < 5 * HID; ++k)
        acc += p_sh[k] * gW[k * 64 + tid];
    out[g * 64 + tid] = acc;
}

// ---------------------------------------------------------------------------
extern "C" void kernel_launch(void* const* d_in, const int* in_sizes, int n_in,
                              void* d_out, int out_size, void* d_ws, size_t ws_size,
                              hipStream_t stream)
{
    const float* x_value       = (const float*)d_in[0];
    const float* x_typ         = (const float*)d_in[1];
    const float* x_size_       = (const float*)d_in[2];
    const float* x_attribute   = (const float*)d_in[3];
    const float* x_instruction = (const float*)d_in[4];
    const float* Wl_vt = (const float*)d_in[5];
    const float* bl_vt = (const float*)d_in[6];
    const float* Wr_vt = (const float*)d_in[7];
    const float* Wl_iv = (const float*)d_in[8];
    const float* bl_iv = (const float*)d_in[9];
    const float* Wr_iv = (const float*)d_in[10];
    const float* Wl_vi = (const float*)d_in[11];
    const float* bl_vi = (const float*)d_in[12];
    const float* Wr_vi = (const float*)d_in[13];
    const float* Wl_va = (const float*)d_in[14];
    const float* bl_va = (const float*)d_in[15];
    const float* Wr_va = (const float*)d_in[16];
    const float* Wl_ts = (const float*)d_in[17];
    const float* bl_ts = (const float*)d_in[18];
    const float* Wr_ts = (const float*)d_in[19];
    const float* Wl_ii = (const float*)d_in[20];
    const float* bl_ii = (const float*)d_in[21];
    const float* Wr_ii = (const float*)d_in[22];
    const float* nW_typ         = (const float*)d_in[23];
    const float* nb_typ         = (const float*)d_in[24];
    const float* nW_value       = (const float*)d_in[25];
    const float* nb_value       = (const float*)d_in[26];
    const float* nW_instruction = (const float*)d_in[27];
    const float* nb_instruction = (const float*)d_in[28];
    const float* nW_attribute   = (const float*)d_in[29];
    const float* nb_attribute   = (const float*)d_in[30];
    const float* nW_size        = (const float*)d_in[31];
    const float* nb_size        = (const float*)d_in[32];
    const float* gW = (const float*)d_in[33];
    const float* gb = (const float*)d_in[34];
    const int* src_vt = (const int*)d_in[35];
    const int* dst_vt = (const int*)d_in[36];
    const int* src_iv = (const int*)d_in[37];
    const int* dst_iv = (const int*)d_in[38];
    const int* src_vi = (const int*)d_in[39];
    const int* dst_vi = (const int*)d_in[40];
    const int* src_va = (const int*)d_in[41];
    const int* dst_va = (const int*)d_in[42];
    const int* src_ts = (const int*)d_in[43];
    const int* dst_ts = (const int*)d_in[44];
    const int* src_ii = (const int*)d_in[45];
    const int* dst_ii = (const int*)d_in[46];
    const int* batch_typ         = (const int*)d_in[47];
    const int* batch_value       = (const int*)d_in[48];
    const int* batch_instruction = (const int*)d_in[49];
    const int* batch_attribute   = (const int*)d_in[50];
    const int* batch_size        = (const int*)d_in[51];

    // ---- workspace layout ----
    int* deg = (int*)d_ws;                                   // TOT_N (zeroed)
    float* pool_sum = (float*)(deg + TOT_N);                 // 5*G*HID (zeroed)
    float* pool_cnt = pool_sum + (size_t)5 * G_ * HID;       // 5*G (zeroed)
    size_t zero_bytes = (size_t)TOT_N * 4 + ((size_t)5 * G_ * HID + 5 * G_) * 4;

    int* cur  = (int*)(pool_cnt + 5 * G_);                   // TOT_N
    int* csum = cur + TOT_N;                                 // NCH
    int* coff = csum + NCH;                                  // NCH
    int2* epair = (int2*)(((uintptr_t)(coff + NCH) + 15) & ~(uintptr_t)15);  // TOT_E pairs
    unsigned short* wt = (unsigned short*)(((uintptr_t)(epair + TOT_E) + 63) & ~(uintptr_t)63);
    size_t wo = 0;
    unsigned short* w1t_vt = wt + wo; wo += 128 * 96;
    unsigned short* w1t_iv = wt + wo; wo += 128 * 128;
    unsigned short* w1t_vi = wt + wo; wo += 128 * 192;
    unsigned short* w1t_va = wt + wo; wo += 128 * 96;
    unsigned short* w1t_ts = wt + wo; wo += 128 * 64;
    unsigned short* nwt_t  = wt + wo; wo += 128 * 128;
    unsigned short* nwt_v  = wt + wo; wo += 128 * 128;
    unsigned short* nwt_i  = wt + wo; wo += 128 * 128;
    unsigned short* nwt_a  = wt + wo; wo += 128 * 128;
    unsigned short* nwt_s  = wt + wo; wo += 128 * 128;

    hipMemsetAsync(d_ws, 0, zero_bytes, stream);

    // weight prep (tiny)
    prep_wt<<<(128 *  96 + 255) / 256, 256, 0, stream>>>(Wl_vt, 64, nullptr, 0, Wr_vt, nullptr, w1t_vt,  96);
    prep_wt<<<(128 * 128 + 255) / 256, 256, 0, stream>>>(Wl_iv, 64, nullptr, 0, Wr_iv, nullptr, w1t_iv, 128);
    prep_wt<<<(128 * 192 + 255) / 256, 256, 0, stream>>>(Wl_vi, 64, Wl_ii, 64, Wr_vi, Wr_ii,   w1t_vi, 192);
    prep_wt<<<(128 *  96 + 255) / 256, 256, 0, stream>>>(Wl_va, 64, nullptr, 0, Wr_va, nullptr, w1t_va,  96);
    prep_wt<<<(128 *  64 + 255) / 256, 256, 0, stream>>>(Wl_ts, 32, nullptr, 0, Wr_ts, nullptr, w1t_ts,  64);
    prep_wt<<<(128 * 128 + 255) / 256, 256, 0, stream>>>(nW_typ,         128, nullptr, 0, nullptr, nullptr, nwt_t, 128);
    prep_wt<<<(128 * 128 + 255) / 256, 256, 0, stream>>>(nW_value,       128, nullptr, 0, nullptr, nullptr, nwt_v, 128);
    prep_wt<<<(128 * 128 + 255) / 256, 256, 0, stream>>>(nW_instruction, 128, nullptr, 0, nullptr, nullptr, nwt_i, 128);
    prep_wt<<<(128 * 128 + 255) / 256, 256, 0, stream>>>(nW_attribute,   128, nullptr, 0, nullptr, nullptr, nwt_a, 128);
    prep_wt<<<(128 * 128 + 255) / 256, 256, 0, stream>>>(nW_size,        128, nullptr, 0, nullptr, nullptr, nwt_s, 128);

    // CSR build: histogram -> scan -> position scatter (writes (src,dst) pairs)
    edge_hist<<<(EVTv + 255) / 256, 256, 0, stream>>>(dst_vt, deg, OFF_VT, EVTv);
    edge_hist<<<(EIVv + 255) / 256, 256, 0, stream>>>(dst_iv, deg, OFF_IV, EIVv);
    edge_hist<<<(EVIv + 255) / 256, 256, 0, stream>>>(dst_vi, deg, OFF_VI, EVIv);
    edge_hist<<<(EVAv + 255) / 256, 256, 0, stream>>>(dst_va, deg, OFF_VA, EVAv);
    edge_hist<<<(ETSv + 255) / 256, 256, 0, stream>>>(dst_ts, deg, OFF_TS, ETSv);
    edge_hist<<<(EIIv + 255) / 256, 256, 0, stream>>>(dst_ii, deg, OFF_II, EIIv);

    scan_chunk_sum<<<NCH, 256, 0, stream>>>(deg, csum);
    scan_offsets<<<1, 256, 0, stream>>>(csum, coff);
    scan_write<<<NCH, 256, 0, stream>>>(deg, coff, cur);

    edge_pos<<<(EVTv + 255) / 256, 256, 0, stream>>>(src_vt, dst_vt, cur, epair, OFF_VT, EVTv);
    edge_pos<<<(EIVv + 255) / 256, 256, 0, stream>>>(src_iv, dst_iv, cur, epair, OFF_IV, EIVv);
    edge_pos<<<(EVIv + 255) / 256, 256, 0, stream>>>(src_vi, dst_vi, cur, epair, OFF_VI, EVIv);
    edge_pos<<<(EVAv + 255) / 256, 256, 0, stream>>>(src_va, dst_va, cur, epair, OFF_VA, EVAv);
    edge_pos<<<(ETSv + 255) / 256, 256, 0, stream>>>(src_ts, dst_ts, cur, epair, OFF_TS, ETSv);
    edge_pos<<<(EIIv + 255) / 256, 256, 0, stream>>>(src_ii, dst_ii, cur, epair, OFF_II, EIIv);

    batch_count<<<(NTv + 255) / 256, 256, 0, stream>>>(batch_typ,         pool_cnt + 0 * G_, NTv);
    batch_count<<<(NVv + 255) / 256, 256, 0, stream>>>(batch_value,       pool_cnt + 1 * G_, NVv);
    batch_count<<<(NIv + 255) / 256, 256, 0, stream>>>(batch_instruction, pool_cnt + 2 * G_, NIv);
    batch_count<<<(NAv + 255) / 256, 256, 0, stream>>>(batch_attribute,   pool_cnt + 3 * G_, NAv);
    batch_count<<<(NSv + 255) / 256, 256, 0, stream>>>(batch_size,        pool_cnt + 4 * G_, NSv);

    // fused gather + node GEMMs
    sage_mfma<64, 32, false, 128,  96><<<(NTv + 63) / 64, 256, 0, stream>>>(
        deg, cur, epair, OFF_VT, 0, x_value, nullptr, x_typ,
        w1t_vt, bl_vt, nullptr, nwt_t, nb_typ, batch_typ,
        pool_sum + (size_t)0 * G_ * HID, NTv);
    sage_mfma<64, 64, false, 128, 128><<<(NVv + 63) / 64, 256, 0, stream>>>(
        deg, cur, epair, OFF_IV, 0, x_instruction, nullptr, x_value,
        w1t_iv, bl_iv, nullptr, nwt_v, nb_value, batch_value,
        pool_sum + (size_t)1 * G_ * HID, NVv);
    sage_mfma<64, 64, true,  192, 192><<<(NIv + 63) / 64, 256, 0, stream>>>(
        deg, cur, epair, OFF_VI, OFF_II, x_value, x_instruction, x_instruction,
        w1t_vi, bl_vi, bl_ii, nwt_i, nb_instruction, batch_instruction,
        pool_sum + (size_t)2 * G_ * HID, NIv);
    sage_mfma<64, 32, false, 128,  96><<<(NAv + 63) / 64, 256, 0, stream>>>(
        deg, cur, epair, OFF_VA, 0, x_value, nullptr, x_attribute,
        w1t_va, bl_va, nullptr, nwt_a, nb_attribute, batch_attribute,
        pool_sum + (size_t)3 * G_ * HID, NAv);
    sage_mfma<32, 32, false,  64,  64><<<(NSv + 63) / 64, 256, 0, stream>>>(
        deg, cur, epair, OFF_TS, 0, x_typ, nullptr, x_size_,
        w1t_ts, bl_ts, nullptr, nwt_s, nb_size, batch_size,
        pool_sum + (size_t)4 * G_ * HID, NSv);

    final_kernel<<<G_, 64, 0, stream>>>(pool_sum, pool_cnt, gW, gb, (float*)d_out);
}

// Round 5
// 1918.877 us; speedup vs baseline: 1.3815x; 1.3815x over previous
//
#include <hip/hip_runtime.h>

namespace {
constexpr int G_  = 2048;
constexpr int HID = 128;
constexpr int NVv = 500000, NIv = 300000, NTv = 50000, NAv = 50000, NSv = 10000;
constexpr int EVTv = 500000, EIVv = 1500000, EVIv = 1500000, EVAv = 500000, ETSv = 50000, EIIv = 600000;
// concatenated per-(edge-type,dst-node) CSR space
constexpr int OFF_VT = 0;
constexpr int OFF_IV = OFF_VT + NTv;          // 50000
constexpr int OFF_VI = OFF_IV + NVv;          // 550000
constexpr int OFF_VA = OFF_VI + NIv;          // 850000
constexpr int OFF_TS = OFF_VA + NAv;          // 900000
constexpr int OFF_II = OFF_TS + NSv;          // 910000
constexpr int TOT_N  = OFF_II + NIv;          // 1210000
constexpr int TOT_E  = EVTv + EIVv + EVIv + EVAv + ETSv + EIIv;  // 4650000
constexpr int NCH    = (TOT_N + 1023) / 1024; // 1182
}

typedef short s16x8 __attribute__((ext_vector_type(8)));
typedef float f32x4 __attribute__((ext_vector_type(4)));

__device__ __forceinline__ float4 ld4(const float* p) { return *(const float4*)p; }

__device__ __forceinline__ unsigned short f2bf(float x) {
    unsigned u = __float_as_uint(x);
    u += 0x7fffu + ((u >> 16) & 1u);
    return (unsigned short)(u >> 16);
}

// ---------------------------------------------------------------------------
// CSR build
// ---------------------------------------------------------------------------
__global__ __launch_bounds__(256)
void edge_hist(const int* __restrict__ dst, int* __restrict__ deg, int off, int E)
{
    int i = blockIdx.x * 256 + threadIdx.x;
    if (i < E) atomicAdd(&deg[off + dst[i]], 1);
}

__global__ __launch_bounds__(256)
void scan_chunk_sum(const int* __restrict__ deg, int* __restrict__ csum)
{
    __shared__ int sc[256];
    int blk = blockIdx.x, tid = threadIdx.x;
    int base = blk * 1024 + tid * 4;
    int s = 0;
#pragma unroll
    for (int k = 0; k < 4; ++k) { int idx = base + k; if (idx < TOT_N) s += deg[idx]; }
    sc[tid] = s; __syncthreads();
    for (int d = 128; d > 0; d >>= 1) {
        if (tid < d) sc[tid] += sc[tid + d];
        __syncthreads();
    }
    if (tid == 0) csum[blk] = sc[0];
}

__global__ __launch_bounds__(256)
void scan_offsets(const int* __restrict__ csum, int* __restrict__ coff)
{
    __shared__ int sc[256];
    int tid = threadIdx.x;
    int s[5]; int tsum = 0;
#pragma unroll
    for (int k = 0; k < 5; ++k) { int idx = tid * 5 + k; s[k] = (idx < NCH) ? csum[idx] : 0; tsum += s[k]; }
    sc[tid] = tsum; __syncthreads();
    for (int d = 1; d < 256; d <<= 1) {
        int v = (tid >= d) ? sc[tid - d] : 0;
        __syncthreads();
        sc[tid] += v;
        __syncthreads();
    }
    int run = sc[tid] - tsum;   // exclusive
#pragma unroll
    for (int k = 0; k < 5; ++k) { int idx = tid * 5 + k; if (idx < NCH) coff[idx] = run; run += s[k]; }
}

__global__ __launch_bounds__(256)
void scan_write(const int* __restrict__ deg, const int* __restrict__ coff, int* __restrict__ cur)
{
    __shared__ int sc[256];
    int blk = blockIdx.x, tid = threadIdx.x;
    int base = blk * 1024 + tid * 4;
    int v[4]; int tsum = 0;
#pragma unroll
    for (int k = 0; k < 4; ++k) { int idx = base + k; v[k] = (idx < TOT_N) ? deg[idx] : 0; tsum += v[k]; }
    sc[tid] = tsum; __syncthreads();
    for (int d = 1; d < 256; d <<= 1) {
        int t = (tid >= d) ? sc[tid - d] : 0;
        __syncthreads();
        sc[tid] += t;
        __syncthreads();
    }
    int run = coff[blk] + sc[tid] - tsum;   // global exclusive prefix
#pragma unroll
    for (int k = 0; k < 4; ++k) { int idx = base + k; if (idx < TOT_N) cur[idx] = run; run += v[k]; }
}

__global__ __launch_bounds__(256)
void edge_pos(const int* __restrict__ src, const int* __restrict__ dst,
              int* __restrict__ cur, int* __restrict__ eidx, int off, int E)
{
    int i = blockIdx.x * 256 + threadIdx.x;
    if (i < E) {
        int p = atomicAdd(&cur[off + dst[i]], 1);
        eidx[p] = src[i];
    }
}

__global__ __launch_bounds__(256)
void batch_count(const int* __restrict__ batch, float* __restrict__ cnt, int N)
{
    int i = blockIdx.x * 256 + threadIdx.x;
    if (i < N) atomicAdd(&cnt[batch[i]], 1.0f);
}

// ---------------------------------------------------------------------------
// Weight prep: out[n*K1+k] = bf16 of W1[k][n], W1 rows = [S0(L0) | S1(L1) | S2(+S2b)]
// ---------------------------------------------------------------------------
__global__ __launch_bounds__(256)
void prep_wt(const float* __restrict__ S0, int L0,
             const float* __restrict__ S1, int L1,
             const float* __restrict__ S2, const float* __restrict__ S2b,
             unsigned short* __restrict__ out, int K1)
{
    int i = blockIdx.x * 256 + threadIdx.x;
    if (i >= 128 * K1) return;
    int n = i / K1, k = i - n * K1;
    float v;
    if (k < L0) v = S0[k * 128 + n];
    else if (k < L0 + L1) v = S1[(k - L0) * 128 + n];
    else {
        int kk = k - L0 - L1;
        v = S2[kk * 128 + n];
        if (S2b) v += S2b[kk * 128 + n];
    }
    out[i] = f2bf(v);
}

// ---------------------------------------------------------------------------
// Wave-per-node CSR mean gather. Lane = column (D=64: 1 node/wave, D=32: 2).
// Registers accumulate; coalesced 256B row loads; unroll-4 for MLP.
// Writes bf16 MEAN to agg (every node written, incl. degree 0 -> 0).
// ---------------------------------------------------------------------------
template<int D>
__global__ __launch_bounds__(256)
void gather_mean(const int* __restrict__ deg, const int* __restrict__ cur,
                 const int* __restrict__ eidx, int off,
                 const float* __restrict__ xs,
                 unsigned short* __restrict__ agg, int N)
{
    constexpr int NPW = 64 / D;          // nodes per wave
    const int wid   = (blockIdx.x * 256 + threadIdx.x) >> 6;
    const int nwave = (gridDim.x * 256) >> 6;
    const int lane  = threadIdx.x & 63;
    const int sub   = lane / D;
    const int col   = lane & (D - 1);

    for (int n = wid * NPW + sub; n < N; n += nwave * NPW) {
        int e_end = cur[off + n];
        int d     = deg[off + n];
        int e0    = e_end - d;
        float acc = 0.f;
        int t = 0;
        for (; t + 4 <= d; t += 4) {
            int s0 = eidx[e0 + t + 0];
            int s1 = eidx[e0 + t + 1];
            int s2 = eidx[e0 + t + 2];
            int s3 = eidx[e0 + t + 3];
            float v0 = xs[(size_t)s0 * D + col];
            float v1 = xs[(size_t)s1 * D + col];
            float v2 = xs[(size_t)s2 * D + col];
            float v3 = xs[(size_t)s3 * D + col];
            acc += (v0 + v1) + (v2 + v3);
        }
        for (; t < d; ++t) {
            int s = eidx[e0 + t];
            acc += xs[(size_t)s * D + col];
        }
        float m = acc / fmaxf((float)d, 1.0f);
        agg[(size_t)n * D + col] = f2bf(m);
    }
}

// ---------------------------------------------------------------------------
// MFMA node kernel (round-2 structure). Block = 256 thr (4 waves), 64 nodes.
// A-tile rows = [mean1(bf16) | (mean2 bf16) | x_dst(fp32->bf16)] in swizzled LDS.
// h = relu(A @ W1 + b1) -> bf16 LDS -> z = h @ nW + nb -> pooled atomics.
// ---------------------------------------------------------------------------
template<int DSa, int DD, bool HAS2, int ASTR, int K1>
__global__ __launch_bounds__(256)
void sage_mfma(const unsigned short* __restrict__ agg1,
               const unsigned short* __restrict__ agg2,
               const float* __restrict__ xd,
               const unsigned short* __restrict__ W1T,
               const float* __restrict__ bl, const float* __restrict__ bl2,
               const unsigned short* __restrict__ nWT,
               const float* __restrict__ nbp,
               const int* __restrict__ batch,
               float* __restrict__ pool_sum, int N)
{
    constexpr int KST  = K1 / 32;
    constexpr int GCOL = HAS2 ? 2 * DSa : DSa;
    constexpr int XOFF = GCOL;
    __shared__ __align__(16) unsigned short a_sh[64 * ASTR];
    __shared__ __align__(16) unsigned short h_sh[64 * 128];

    const int tid   = threadIdx.x;
    const int node0 = blockIdx.x * 64;

    // ---- A-tile: bf16 agg part (16B chunks) ----
    constexpr int C8g = GCOL / 8;
    for (int c = tid; c < 64 * C8g; c += 256) {
        int r   = c / C8g;
        int col = (c - r * C8g) * 8;
        int node = node0 + r;
        uint4 pk = make_uint4(0u, 0u, 0u, 0u);
        if (node < N) {
            const unsigned short* sp = (!HAS2 || col < DSa)
                ? &agg1[(size_t)node * DSa + col]
                : &agg2[(size_t)node * DSa + (col - DSa)];
            pk = *(const uint4*)sp;
        }
        unsigned byte = ((unsigned)(r * ASTR + col) * 2u) ^ ((unsigned)(r & 7) << 4);
        *(uint4*)((char*)a_sh + byte) = pk;
    }
    // ---- A-tile: x_dst part (fp32 -> bf16, 8B chunks) ----
    constexpr int C4d = DD / 4;
    for (int c = tid; c < 64 * C4d; c += 256) {
        int r    = c / C4d;
        int col4 = (c - r * C4d) * 4;
        int node = node0 + r;
        float4 v = (node < N) ? ld4(&xd[(size_t)node * DD + col4])
                              : make_float4(0.f, 0.f, 0.f, 0.f);
        unsigned p0 = (unsigned)f2bf(v.x) | ((unsigned)f2bf(v.y) << 16);
        unsigned p1 = (unsigned)f2bf(v.z) | ((unsigned)f2bf(v.w) << 16);
        int col = XOFF + col4;
        unsigned byte = ((unsigned)(r * ASTR + col) * 2u) ^ ((unsigned)(r & 7) << 4);
        *(uint2*)((char*)a_sh + byte) = make_uint2(p0, p1);
    }
    __syncthreads();

    const int w  = tid >> 6;
    const int l  = tid & 63;
    const int lg = l >> 4;
    const int lr = l & 15;
    const int rowA = w * 16 + lr;
    const unsigned swz = (unsigned)(rowA & 7) << 4;

    // ---- stage 1: h = A @ W1 ----
    f32x4 acc[8];
#pragma unroll
    for (int nb = 0; nb < 8; ++nb) acc[nb] = (f32x4){0.f, 0.f, 0.f, 0.f};

#pragma unroll
    for (int ks = 0; ks < KST; ++ks) {
        s16x8 af = *(const s16x8*)((const char*)a_sh +
                     (((unsigned)(rowA * ASTR + ks * 32 + lg * 8) * 2u) ^ swz));
#pragma unroll
        for (int nb = 0; nb < 8; ++nb) {
            s16x8 bf = *(const s16x8*)&W1T[(nb * 16 + lr) * K1 + ks * 32 + lg * 8];
            acc[nb] = __builtin_amdgcn_mfma_f32_16x16x32_bf16(af, bf, acc[nb], 0, 0, 0);
        }
    }

    // ---- bias + relu -> bf16 h in LDS ----
#pragma unroll
    for (int nb = 0; nb < 8; ++nb) {
        int col = nb * 16 + lr;
        float b = bl[col];
        if constexpr (HAS2) b += bl2[col];
#pragma unroll
        for (int rg = 0; rg < 4; ++rg) {
            float hv = fmaxf(acc[nb][rg] + b, 0.0f);
            int row = w * 16 + lg * 4 + rg;
            unsigned byte = ((unsigned)(row * 128 + col) * 2u) ^ ((unsigned)(row & 7) << 4);
            *(unsigned short*)((char*)h_sh + byte) = f2bf(hv);
        }
    }
    __syncthreads();

    // ---- stage 2: z = h @ nW ----
    f32x4 acc2[8];
#pragma unroll
    for (int nb = 0; nb < 8; ++nb) acc2[nb] = (f32x4){0.f, 0.f, 0.f, 0.f};

#pragma unroll
    for (int ks = 0; ks < 4; ++ks) {
        s16x8 hf = *(const s16x8*)((const char*)h_sh +
                     (((unsigned)(rowA * 128 + ks * 32 + lg * 8) * 2u) ^ swz));
#pragma unroll
        for (int nb = 0; nb < 8; ++nb) {
            s16x8 bf = *(const s16x8*)&nWT[(nb * 16 + lr) * 128 + ks * 32 + lg * 8];
            acc2[nb] = __builtin_amdgcn_mfma_f32_16x16x32_bf16(hf, bf, acc2[nb], 0, 0, 0);
        }
    }

    // ---- pool: run-length reduce over 4 consecutive rows, then atomics ----
    const int base = node0 + w * 16 + lg * 4;
    float nbias[8];
#pragma unroll
    for (int nb = 0; nb < 8; ++nb) nbias[nb] = nbp[nb * 16 + lr];

    int bt[4];
#pragma unroll
    for (int rg = 0; rg < 4; ++rg) bt[rg] = (base + rg < N) ? batch[base + rg] : -1;

    float run[8];
    int cb = bt[0];
#pragma unroll
    for (int nb = 0; nb < 8; ++nb) run[nb] = acc2[nb][0] + nbias[nb];
#pragma unroll
    for (int rg = 1; rg < 4; ++rg) {
        if (bt[rg] == cb) {
#pragma unroll
            for (int nb = 0; nb < 8; ++nb) run[nb] += acc2[nb][rg] + nbias[nb];
        } else {
            if (cb >= 0) {
#pragma unroll
                for (int nb = 0; nb < 8; ++nb)
                    atomicAdd(&pool_sum[cb * 128 + nb * 16 + lr], run[nb]);
            }
            cb = bt[rg];
#pragma unroll
            for (int nb = 0; nb < 8; ++nb) run[nb] = acc2[nb][rg] + nbias[nb];
        }
    }
    if (cb >= 0) {
#pragma unroll
        for (int nb = 0; nb < 8; ++nb)
            atomicAdd(&pool_sum[cb * 128 + nb * 16 + lr], run[nb]);
    }
}

// ---------------------------------------------------------------------------
__global__ __launch_bounds__(64)
void final_kernel(const float* __restrict__ pool_sum, const float* __restrict__ pool_cnt,
                  const float* __restrict__ gW, const float* __restrict__ gb,
                  float* __restrict__ out)
{
    __shared__ float p_sh[5 * HID];
    int g = blockIdx.x, tid = threadIdx.x;
    for (int i = tid; i < 5 * HID; i += 64) {
        int t  = i >> 7;
        int jj = i & 127;
        float c = fmaxf(pool_cnt[t * G_ + g], 1.0f);
        p_sh[i] = pool_sum[((size_t)t * G_ + g) * HID + jj] / c;
    }
    __syncthreads();
    float acc = gb[tid];
#pragma unroll 8
    for (int k = 0; k < 5 * HID; ++k)
        acc += p_sh[k] * gW[k * 64 + tid];
    out[g * 64 + tid] = acc;
}

// ---------------------------------------------------------------------------
extern "C" void kernel_launch(void* const* d_in, const int* in_sizes, int n_in,
                              void* d_out, int out_size, void* d_ws, size_t ws_size,
                              hipStream_t stream)
{
    const float* x_value       = (const float*)d_in[0];
    const float* x_typ         = (const float*)d_in[1];
    const float* x_size_       = (const float*)d_in[2];
    const float* x_attribute   = (const float*)d_in[3];
    const float* x_instruction = (const float*)d_in[4];
    const float* Wl_vt = (const float*)d_in[5];
    const float* bl_vt = (const float*)d_in[6];
    const float* Wr_vt = (const float*)d_in[7];
    const float* Wl_iv = (const float*)d_in[8];
    const float* bl_iv = (const float*)d_in[9];
    const float* Wr_iv = (const float*)d_in[10];
    const float* Wl_vi = (const float*)d_in[11];
    const float* bl_vi = (const float*)d_in[12];
    const float* Wr_vi = (const float*)d_in[13];
    const float* Wl_va = (const float*)d_in[14];
    const float* bl_va = (const float*)d_in[15];
    const float* Wr_va = (const float*)d_in[16];
    const float* Wl_ts = (const float*)d_in[17];
    const float* bl_ts = (const float*)d_in[18];
    const float* Wr_ts = (const float*)d_in[19];
    const float* Wl_ii = (const float*)d_in[20];
    const float* bl_ii = (const float*)d_in[21];
    const float* Wr_ii = (const float*)d_in[22];
    const float* nW_typ         = (const float*)d_in[23];
    const float* nb_typ         = (const float*)d_in[24];
    const float* nW_value       = (const float*)d_in[25];
    const float* nb_value       = (const float*)d_in[26];
    const float* nW_instruction = (const float*)d_in[27];
    const float* nb_instruction = (const float*)d_in[28];
    const float* nW_attribute   = (const float*)d_in[29];
    const float* nb_attribute   = (const float*)d_in[30];
    const float* nW_size        = (const float*)d_in[31];
    const float* nb_size        = (const float*)d_in[32];
    const float* gW = (const float*)d_in[33];
    const float* gb = (const float*)d_in[34];
    const int* src_vt = (const int*)d_in[35];
    const int* dst_vt = (const int*)d_in[36];
    const int* src_iv = (const int*)d_in[37];
    const int* dst_iv = (const int*)d_in[38];
    const int* src_vi = (const int*)d_in[39];
    const int* dst_vi = (const int*)d_in[40];
    const int* src_va = (const int*)d_in[41];
    const int* dst_va = (const int*)d_in[42];
    const int* src_ts = (const int*)d_in[43];
    const int* dst_ts = (const int*)d_in[44];
    const int* src_ii = (const int*)d_in[45];
    const int* dst_ii = (const int*)d_in[46];
    const int* batch_typ         = (const int*)d_in[47];
    const int* batch_value       = (const int*)d_in[48];
    const int* batch_instruction = (const int*)d_in[49];
    const int* batch_attribute   = (const int*)d_in[50];
    const int* batch_size        = (const int*)d_in[51];

    // ---- workspace layout ----
    int* deg = (int*)d_ws;                                   // TOT_N (zeroed)
    float* pool_sum = (float*)(deg + TOT_N);                 // 5*G*HID (zeroed)
    float* pool_cnt = pool_sum + (size_t)5 * G_ * HID;       // 5*G (zeroed)
    size_t zero_bytes = (size_t)TOT_N * 4 + ((size_t)5 * G_ * HID + 5 * G_) * 4;

    int* cur  = (int*)(pool_cnt + 5 * G_);                   // TOT_N
    int* csum = cur + TOT_N;                                 // NCH
    int* coff = csum + NCH;                                  // NCH
    int* eidx = coff + NCH;                                  // TOT_E
    // bf16 agg buffers (written fully by gather_mean; no zeroing needed)
    unsigned short* ab = (unsigned short*)(((uintptr_t)(eidx + TOT_E) + 63) & ~(uintptr_t)63);
    size_t ao = 0;
    unsigned short* agg_vt = ab + ao; ao += (size_t)NTv * 64;
    unsigned short* agg_iv = ab + ao; ao += (size_t)NVv * 64;
    unsigned short* agg_vi = ab + ao; ao += (size_t)NIv * 64;
    unsigned short* agg_va = ab + ao; ao += (size_t)NAv * 64;
    unsigned short* agg_ts = ab + ao; ao += (size_t)NSv * 32;
    unsigned short* agg_ii = ab + ao; ao += (size_t)NIv * 64;
    unsigned short* wt = (unsigned short*)(((uintptr_t)(ab + ao) + 63) & ~(uintptr_t)63);
    size_t wo = 0;
    unsigned short* w1t_vt = wt + wo; wo += 128 * 96;
    unsigned short* w1t_iv = wt + wo; wo += 128 * 128;
    unsigned short* w1t_vi = wt + wo; wo += 128 * 192;
    unsigned short* w1t_va = wt + wo; wo += 128 * 96;
    unsigned short* w1t_ts = wt + wo; wo += 128 * 64;
    unsigned short* nwt_t  = wt + wo; wo += 128 * 128;
    unsigned short* nwt_v  = wt + wo; wo += 128 * 128;
    unsigned short* nwt_i  = wt + wo; wo += 128 * 128;
    unsigned short* nwt_a  = wt + wo; wo += 128 * 128;
    unsigned short* nwt_s  = wt + wo; wo += 128 * 128;

    hipMemsetAsync(d_ws, 0, zero_bytes, stream);

    // weight prep (tiny)
    prep_wt<<<(128 *  96 + 255) / 256, 256, 0, stream>>>(Wl_vt, 64, nullptr, 0, Wr_vt, nullptr, w1t_vt,  96);
    prep_wt<<<(128 * 128 + 255) / 256, 256, 0, stream>>>(Wl_iv, 64, nullptr, 0, Wr_iv, nullptr, w1t_iv, 128);
    prep_wt<<<(128 * 192 + 255) / 256, 256, 0, stream>>>(Wl_vi, 64, Wl_ii, 64, Wr_vi, Wr_ii,   w1t_vi, 192);
    prep_wt<<<(128 *  96 + 255) / 256, 256, 0, stream>>>(Wl_va, 64, nullptr, 0, Wr_va, nullptr, w1t_va,  96);
    prep_wt<<<(128 *  64 + 255) / 256, 256, 0, stream>>>(Wl_ts, 32, nullptr, 0, Wr_ts, nullptr, w1t_ts,  64);
    prep_wt<<<(128 * 128 + 255) / 256, 256, 0, stream>>>(nW_typ,         128, nullptr, 0, nullptr, nullptr, nwt_t, 128);
    prep_wt<<<(128 * 128 + 255) / 256, 256, 0, stream>>>(nW_value,       128, nullptr, 0, nullptr, nullptr, nwt_v, 128);
    prep_wt<<<(128 * 128 + 255) / 256, 256, 0, stream>>>(nW_instruction, 128, nullptr, 0, nullptr, nullptr, nwt_i, 128);
    prep_wt<<<(128 * 128 + 255) / 256, 256, 0, stream>>>(nW_attribute,   128, nullptr, 0, nullptr, nullptr, nwt_a, 128);
    prep_wt<<<(128 * 128 + 255) / 256, 256, 0, stream>>>(nW_size,        128, nullptr, 0, nullptr, nullptr, nwt_s, 128);

    // CSR build: histogram -> scan -> position scatter
    edge_hist<<<(EVTv + 255) / 256, 256, 0, stream>>>(dst_vt, deg, OFF_VT, EVTv);
    edge_hist<<<(EIVv + 255) / 256, 256, 0, stream>>>(dst_iv, deg, OFF_IV, EIVv);
    edge_hist<<<(EVIv + 255) / 256, 256, 0, stream>>>(dst_vi, deg, OFF_VI, EVIv);
    edge_hist<<<(EVAv + 255) / 256, 256, 0, stream>>>(dst_va, deg, OFF_VA, EVAv);
    edge_hist<<<(ETSv + 255) / 256, 256, 0, stream>>>(dst_ts, deg, OFF_TS, ETSv);
    edge_hist<<<(EIIv + 255) / 256, 256, 0, stream>>>(dst_ii, deg, OFF_II, EIIv);

    scan_chunk_sum<<<NCH, 256, 0, stream>>>(deg, csum);
    scan_offsets<<<1, 256, 0, stream>>>(csum, coff);
    scan_write<<<NCH, 256, 0, stream>>>(deg, coff, cur);

    edge_pos<<<(EVTv + 255) / 256, 256, 0, stream>>>(src_vt, dst_vt, cur, eidx, OFF_VT, EVTv);
    edge_pos<<<(EIVv + 255) / 256, 256, 0, stream>>>(src_iv, dst_iv, cur, eidx, OFF_IV, EIVv);
    edge_pos<<<(EVIv + 255) / 256, 256, 0, stream>>>(src_vi, dst_vi, cur, eidx, OFF_VI, EVIv);
    edge_pos<<<(EVAv + 255) / 256, 256, 0, stream>>>(src_va, dst_va, cur, eidx, OFF_VA, EVAv);
    edge_pos<<<(ETSv + 255) / 256, 256, 0, stream>>>(src_ts, dst_ts, cur, eidx, OFF_TS, ETSv);
    edge_pos<<<(EIIv + 255) / 256, 256, 0, stream>>>(src_ii, dst_ii, cur, eidx, OFF_II, EIIv);

    batch_count<<<(NTv + 255) / 256, 256, 0, stream>>>(batch_typ,         pool_cnt + 0 * G_, NTv);
    batch_count<<<(NVv + 255) / 256, 256, 0, stream>>>(batch_value,       pool_cnt + 1 * G_, NVv);
    batch_count<<<(NIv + 255) / 256, 256, 0, stream>>>(batch_instruction, pool_cnt + 2 * G_, NIv);
    batch_count<<<(NAv + 255) / 256, 256, 0, stream>>>(batch_attribute,   pool_cnt + 3 * G_, NAv);
    batch_count<<<(NSv + 255) / 256, 256, 0, stream>>>(batch_size,        pool_cnt + 4 * G_, NSv);

    // wave-per-node register gather -> bf16 mean
    auto gb_ = [](int N, int npw) {
        int waves  = (N + npw - 1) / npw;
        int blocks = (waves + 3) / 4;
        return blocks > 2048 ? 2048 : blocks;
    };
    gather_mean<64><<<gb_(NTv, 1), 256, 0, stream>>>(deg, cur, eidx, OFF_VT, x_value,       agg_vt, NTv);
    gather_mean<64><<<gb_(NVv, 1), 256, 0, stream>>>(deg, cur, eidx, OFF_IV, x_instruction, agg_iv, NVv);
    gather_mean<64><<<gb_(NIv, 1), 256, 0, stream>>>(deg, cur, eidx, OFF_VI, x_value,       agg_vi, NIv);
    gather_mean<64><<<gb_(NAv, 1), 256, 0, stream>>>(deg, cur, eidx, OFF_VA, x_value,       agg_va, NAv);
    gather_mean<32><<<gb_(NSv, 2), 256, 0, stream>>>(deg, cur, eidx, OFF_TS, x_typ,         agg_ts, NSv);
    gather_mean<64><<<gb_(NIv, 1), 256, 0, stream>>>(deg, cur, eidx, OFF_II, x_instruction, agg_ii, NIv);

    // node GEMMs (MFMA) + pooling
    sage_mfma<64, 32, false, 128,  96><<<(NTv + 63) / 64, 256, 0, stream>>>(
        agg_vt, nullptr, x_typ, w1t_vt, bl_vt, nullptr,
        nwt_t, nb_typ, batch_typ, pool_sum + (size_t)0 * G_ * HID, NTv);
    sage_mfma<64, 64, false, 128, 128><<<(NVv + 63) / 64, 256, 0, stream>>>(
        agg_iv, nullptr, x_value, w1t_iv, bl_iv, nullptr,
        nwt_v, nb_value, batch_value, pool_sum + (size_t)1 * G_ * HID, NVv);
    sage_mfma<64, 64, true,  192, 192><<<(NIv + 63) / 64, 256, 0, stream>>>(
        agg_vi, agg_ii, x_instruction, w1t_vi, bl_vi, bl_ii,
        nwt_i, nb_instruction, batch_instruction, pool_sum + (size_t)2 * G_ * HID, NIv);
    sage_mfma<64, 32, false, 128,  96><<<(NAv + 63) / 64, 256, 0, stream>>>(
        agg_va, nullptr, x_attribute, w1t_va, bl_va, nullptr,
        nwt_a, nb_attribute, batch_attribute, pool_sum + (size_t)3 * G_ * HID, NAv);
    sage_mfma<32, 32, false,  64,  64><<<(NSv + 63) / 64, 256, 0, stream>>>(
        agg_ts, nullptr, x_size_, w1t_ts, bl_ts, nullptr,
        nwt_s, nb_size, batch_size, pool_sum + (size_t)4 * G_ * HID, NSv);

    final_kernel<<<G_, 64, 0, stream>>>(pool_sum, pool_cnt, gW, gb, (float*)d_out);
}

// Round 6
// 1914.657 us; speedup vs baseline: 1.3846x; 1.0022x over previous
//
#include <hip/hip_runtime.h>

namespace {
constexpr int G_  = 2048;
constexpr int HID = 128;
constexpr int NVv = 500000, NIv = 300000, NTv = 50000, NAv = 50000, NSv = 10000;
constexpr int EVTv = 500000, EIVv = 1500000, EVIv = 1500000, EVAv = 500000, ETSv = 50000, EIIv = 600000;
// concatenated per-(edge-type,dst-node) CSR space
constexpr int OFF_VT = 0;
constexpr int OFF_IV = OFF_VT + NTv;
constexpr int OFF_VI = OFF_IV + NVv;
constexpr int OFF_VA = OFF_VI + NIv;
constexpr int OFF_TS = OFF_VA + NAv;
constexpr int OFF_II = OFF_TS + NSv;
constexpr int TOT_N  = OFF_II + NIv;          // 1210000
constexpr int TOT_E  = EVTv + EIVv + EVIv + EVAv + ETSv + EIIv;  // 4650000
constexpr int NCH    = (TOT_N + 1023) / 1024; // 1182
}

typedef short s16x8 __attribute__((ext_vector_type(8)));
typedef float f32x4 __attribute__((ext_vector_type(4)));

__device__ __forceinline__ float4 ld4(const float* p) { return *(const float4*)p; }

__device__ __forceinline__ unsigned short f2bf(float x) {
    unsigned u = __float_as_uint(x);
    u += 0x7fffu + ((u >> 16) & 1u);
    return (unsigned short)(u >> 16);
}

// ---------------------------------------------------------------------------
// CSR build
// ---------------------------------------------------------------------------
__global__ __launch_bounds__(256)
void edge_hist(const int* __restrict__ dst, int* __restrict__ deg, int off, int E)
{
    int i = blockIdx.x * 256 + threadIdx.x;
    if (i < E) atomicAdd(&deg[off + dst[i]], 1);
}

__global__ __launch_bounds__(256)
void scan_chunk_sum(const int* __restrict__ deg, int* __restrict__ csum)
{
    __shared__ int sc[256];
    int blk = blockIdx.x, tid = threadIdx.x;
    int base = blk * 1024 + tid * 4;
    int s = 0;
#pragma unroll
    for (int k = 0; k < 4; ++k) { int idx = base + k; if (idx < TOT_N) s += deg[idx]; }
    sc[tid] = s; __syncthreads();
    for (int d = 128; d > 0; d >>= 1) {
        if (tid < d) sc[tid] += sc[tid + d];
        __syncthreads();
    }
    if (tid == 0) csum[blk] = sc[0];
}

__global__ __launch_bounds__(256)
void scan_offsets(const int* __restrict__ csum, int* __restrict__ coff)
{
    __shared__ int sc[256];
    int tid = threadIdx.x;
    int s[5]; int tsum = 0;
#pragma unroll
    for (int k = 0; k < 5; ++k) { int idx = tid * 5 + k; s[k] = (idx < NCH) ? csum[idx] : 0; tsum += s[k]; }
    sc[tid] = tsum; __syncthreads();
    for (int d = 1; d < 256; d <<= 1) {
        int v = (tid >= d) ? sc[tid - d] : 0;
        __syncthreads();
        sc[tid] += v;
        __syncthreads();
    }
    int run = sc[tid] - tsum;   // exclusive
#pragma unroll
    for (int k = 0; k < 5; ++k) { int idx = tid * 5 + k; if (idx < NCH) coff[idx] = run; run += s[k]; }
}

__global__ __launch_bounds__(256)
void scan_write(const int* __restrict__ deg, const int* __restrict__ coff, int* __restrict__ cur)
{
    __shared__ int sc[256];
    int blk = blockIdx.x, tid = threadIdx.x;
    int base = blk * 1024 + tid * 4;
    int v[4]; int tsum = 0;
#pragma unroll
    for (int k = 0; k < 4; ++k) { int idx = base + k; v[k] = (idx < TOT_N) ? deg[idx] : 0; tsum += v[k]; }
    sc[tid] = tsum; __syncthreads();
    for (int d = 1; d < 256; d <<= 1) {
        int t = (tid >= d) ? sc[tid - d] : 0;
        __syncthreads();
        sc[tid] += t;
        __syncthreads();
    }
    int run = coff[blk] + sc[tid] - tsum;
#pragma unroll
    for (int k = 0; k < 4; ++k) { int idx = base + k; if (idx < TOT_N) cur[idx] = run; run += v[k]; }
}

__global__ __launch_bounds__(256)
void edge_pos(const int* __restrict__ src, const int* __restrict__ dst,
              int* __restrict__ cur, int* __restrict__ eidx, int off, int E)
{
    int i = blockIdx.x * 256 + threadIdx.x;
    if (i < E) {
        int p = atomicAdd(&cur[off + dst[i]], 1);
        eidx[p] = src[i];
    }
}

__global__ __launch_bounds__(256)
void batch_count(const int* __restrict__ batch, float* __restrict__ cnt, int N)
{
    int i = blockIdx.x * 256 + threadIdx.x;
    if (i < N) atomicAdd(&cnt[batch[i]], 1.0f);
}

// ---------------------------------------------------------------------------
// Packed weight prep: fragment layout so a wave reads 1KB coalesced per
// MFMA B-operand. out[(ks*8+nb)*512 + l*8 + j] = bf16(W1[k][row]),
// row = nb*16 + (l&15), k = ks*32 + (l>>4)*8 + j.
// W1 rows (k-major) = [S0(L0) | S1(L1) | S2(+S2b)].
// ---------------------------------------------------------------------------
__global__ __launch_bounds__(256)
void prep_wpack(const float* __restrict__ S0, int L0,
                const float* __restrict__ S1, int L1,
                const float* __restrict__ S2, const float* __restrict__ S2b,
                unsigned short* __restrict__ out, int K1)
{
    int i = blockIdx.x * 256 + threadIdx.x;
    int total = (K1 / 32) * 8 * 512;
    if (i >= total) return;
    int frag = i >> 9;
    int rem  = i & 511;
    int l = rem >> 3, j = rem & 7;
    int ks = frag >> 3, nb = frag & 7;
    int row = nb * 16 + (l & 15);
    int k = ks * 32 + (l >> 4) * 8 + j;
    float v;
    if (k < L0) v = S0[k * 128 + row];
    else if (k < L0 + L1) v = S1[(k - L0) * 128 + row];
    else {
        int kk = k - L0 - L1;
        v = S2[kk * 128 + row];
        if (S2b) v += S2b[kk * 128 + row];
    }
    out[i] = f2bf(v);
}

// ---------------------------------------------------------------------------
// Gather v2: 16-lane float4 groups -> 4 nodes per wave (8 for D=32),
// unroll-2 -> up to 8 independent 256B row loads in flight per wave.
// Writes bf16 MEAN to agg (deg 0 -> 0).
// ---------------------------------------------------------------------------
template<int D>
__global__ __launch_bounds__(256)
void gather_mean(const int* __restrict__ deg, const int* __restrict__ cur,
                 const int* __restrict__ eidx, int off,
                 const float* __restrict__ xs,
                 unsigned short* __restrict__ agg, int N)
{
    constexpr int LPG = D / 4;           // lanes per group
    constexpr int NPW = 64 / LPG;        // nodes per wave
    const int wid   = (blockIdx.x * 256 + threadIdx.x) >> 6;
    const int nwave = (gridDim.x * 256) >> 6;
    const int lane  = threadIdx.x & 63;
    const int sub   = lane / LPG;
    const int col4  = (lane % LPG) * 4;

    for (int n = wid * NPW + sub; n < N; n += nwave * NPW) {
        int e_end = cur[off + n];
        int d     = deg[off + n];
        int e0    = e_end - d;
        float ax = 0.f, ay = 0.f, az = 0.f, aw = 0.f;
        int t = 0;
        for (; t + 2 <= d; t += 2) {
            int s0 = eidx[e0 + t];
            int s1 = eidx[e0 + t + 1];
            float4 v0 = ld4(&xs[(size_t)s0 * D + col4]);
            float4 v1 = ld4(&xs[(size_t)s1 * D + col4]);
            ax += v0.x + v1.x; ay += v0.y + v1.y;
            az += v0.z + v1.z; aw += v0.w + v1.w;
        }
        if (t < d) {
            int s = eidx[e0 + t];
            float4 v = ld4(&xs[(size_t)s * D + col4]);
            ax += v.x; ay += v.y; az += v.z; aw += v.w;
        }
        float inv = 1.0f / fmaxf((float)d, 1.0f);
        unsigned p0 = (unsigned)f2bf(ax * inv) | ((unsigned)f2bf(ay * inv) << 16);
        unsigned p1 = (unsigned)f2bf(az * inv) | ((unsigned)f2bf(aw * inv) << 16);
        *(uint2*)&agg[(size_t)n * D + col4] = make_uint2(p0, p1);
    }
}

// ---------------------------------------------------------------------------
// Persistent MFMA node kernel. Block = 256 thr (4 waves); grid-strides over
// 64-node tiles. Per tile: regs -> swizzled bf16 A-tile in LDS; next tile's
// global loads issued right after the barrier (latency hidden under MFMA);
// h = relu(A@W1+b1) in wave-private LDS rows (no block barrier);
// z = h@nW + nb -> run-length-reduced pool atomics. Weights read as packed
// coalesced fragments.
// ---------------------------------------------------------------------------
template<int DSa, int DD, bool HAS2, int ASTR, int K1>
__global__ __launch_bounds__(256)
void sage_mfma(const unsigned short* __restrict__ agg1,
               const unsigned short* __restrict__ agg2,
               const float* __restrict__ xd,
               const unsigned short* __restrict__ W1P,
               const float* __restrict__ bl, const float* __restrict__ bl2,
               const unsigned short* __restrict__ nWP,
               const float* __restrict__ nbp,
               const int* __restrict__ batch,
               float* __restrict__ pool_sum, int N)
{
    constexpr int KST  = K1 / 32;
    constexpr int GCOL = HAS2 ? 2 * DSa : DSa;
    constexpr int XOFF = GCOL;
    constexpr int NAG  = GCOL / 32;   // uint4 chunks per thread (agg, bf16)
    constexpr int NXV  = DD / 16;     // uint2 chunks per thread (x, bf16-packed)
    constexpr int C8g  = GCOL / 8;
    constexpr int C4d  = DD / 4;

    __shared__ __align__(16) unsigned short a_sh[64 * ASTR];
    __shared__ __align__(16) unsigned short h_sh[64 * 128];

    const int tid = threadIdx.x;
    const int w = tid >> 6, l = tid & 63, lg = l >> 4, lr = l & 15;
    const int rowA = w * 16 + lr;
    const unsigned swzA = (unsigned)(rowA & 7) << 4;

    // hoisted per-thread constants
    float b1v[8], nbv[8];
#pragma unroll
    for (int nb = 0; nb < 8; ++nb) {
        int col = nb * 16 + lr;
        float b = bl[col];
        if constexpr (HAS2) b += bl2[col];
        b1v[nb] = b;
        nbv[nb] = nbp[col];
    }

    const int ntiles = (N + 63) >> 6;
    int tile = blockIdx.x;
    if (tile >= ntiles) return;
    const int stride = gridDim.x;

    uint4 agA[NAG], agB[NAG];
    uint2 xpA[NXV], xpB[NXV];

    auto load_tile = [&](int t, uint4 (&ag)[NAG], uint2 (&xp)[NXV]) {
        int node0 = t * 64;
#pragma unroll
        for (int j = 0; j < NAG; ++j) {
            int c = j * 256 + tid;
            int r = c / C8g;
            int col = (c - r * C8g) * 8;
            int node = node0 + r;
            uint4 pk = make_uint4(0u, 0u, 0u, 0u);
            if (node < N) {
                const unsigned short* sp = (!HAS2 || col < DSa)
                    ? &agg1[(size_t)node * DSa + col]
                    : &agg2[(size_t)node * DSa + (col - DSa)];
                pk = *(const uint4*)sp;
            }
            ag[j] = pk;
        }
#pragma unroll
        for (int j = 0; j < NXV; ++j) {
            int c = j * 256 + tid;
            int r = c / C4d;
            int col4 = (c - r * C4d) * 4;
            int node = node0 + r;
            float4 v = (node < N) ? ld4(&xd[(size_t)node * DD + col4])
                                  : make_float4(0.f, 0.f, 0.f, 0.f);
            xp[j].x = (unsigned)f2bf(v.x) | ((unsigned)f2bf(v.y) << 16);
            xp[j].y = (unsigned)f2bf(v.z) | ((unsigned)f2bf(v.w) << 16);
        }
    };

    auto store_tile = [&](uint4 (&ag)[NAG], uint2 (&xp)[NXV]) {
#pragma unroll
        for (int j = 0; j < NAG; ++j) {
            int c = j * 256 + tid;
            int r = c / C8g;
            int col = (c - r * C8g) * 8;
            unsigned byte = ((unsigned)(r * ASTR + col) * 2u) ^ ((unsigned)(r & 7) << 4);
            *(uint4*)((char*)a_sh + byte) = ag[j];
        }
#pragma unroll
        for (int j = 0; j < NXV; ++j) {
            int c = j * 256 + tid;
            int r = c / C4d;
            int col = XOFF + (c - r * C4d) * 4;
            unsigned byte = ((unsigned)(r * ASTR + col) * 2u) ^ ((unsigned)(r & 7) << 4);
            *(uint2*)((char*)a_sh + byte) = xp[j];
        }
    };

    auto compute = [&](int t, bool hasNext, int nextT,
                       uint4 (&agC)[NAG], uint2 (&xpC)[NXV],
                       uint4 (&agN)[NAG], uint2 (&xpN)[NXV]) {
        __syncthreads();                 // a_sh free (prev stage1 reads done)
        store_tile(agC, xpC);
        __syncthreads();                 // a_sh ready
        if (hasNext) load_tile(nextT, agN, xpN);   // async: consumed next iter

        const int node0 = t * 64;

        // ---- stage 1: h = A @ W1 ----
        f32x4 acc[8];
#pragma unroll
        for (int nb = 0; nb < 8; ++nb) acc[nb] = (f32x4){0.f, 0.f, 0.f, 0.f};
#pragma unroll
        for (int ks = 0; ks < KST; ++ks) {
            s16x8 af = *(const s16x8*)((const char*)a_sh +
                         (((unsigned)(rowA * ASTR + ks * 32 + lg * 8) * 2u) ^ swzA));
#pragma unroll
            for (int nb = 0; nb < 8; ++nb) {
                s16x8 bf = *(const s16x8*)&W1P[(unsigned)(ks * 8 + nb) * 512 + (unsigned)l * 8];
                acc[nb] = __builtin_amdgcn_mfma_f32_16x16x32_bf16(af, bf, acc[nb], 0, 0, 0);
            }
        }

        // ---- bias + relu -> bf16 h (wave-private LDS rows; no block barrier) ----
#pragma unroll
        for (int nb = 0; nb < 8; ++nb) {
            int col = nb * 16 + lr;
#pragma unroll
            for (int rg = 0; rg < 4; ++rg) {
                float hv = fmaxf(acc[nb][rg] + b1v[nb], 0.0f);
                int row = w * 16 + lg * 4 + rg;
                unsigned byte = ((unsigned)(row * 128 + col) * 2u) ^ ((unsigned)(row & 7) << 4);
                *(unsigned short*)((char*)h_sh + byte) = f2bf(hv);
            }
        }
        asm volatile("s_waitcnt lgkmcnt(0)" ::: "memory");

        // ---- stage 2: z = h @ nW ----
        f32x4 acc2[8];
#pragma unroll
        for (int nb = 0; nb < 8; ++nb) acc2[nb] = (f32x4){0.f, 0.f, 0.f, 0.f};
#pragma unroll
        for (int ks = 0; ks < 4; ++ks) {
            s16x8 hf = *(const s16x8*)((const char*)h_sh +
                         (((unsigned)(rowA * 128 + ks * 32 + lg * 8) * 2u) ^ swzA));
#pragma unroll
            for (int nb = 0; nb < 8; ++nb) {
                s16x8 bf = *(const s16x8*)&nWP[(unsigned)(ks * 8 + nb) * 512 + (unsigned)l * 8];
                acc2[nb] = __builtin_amdgcn_mfma_f32_16x16x32_bf16(hf, bf, acc2[nb], 0, 0, 0);
            }
        }

        // ---- pool: run-length reduce over 4 consecutive rows, then atomics ----
        const int base = node0 + w * 16 + lg * 4;
        int bt[4];
#pragma unroll
        for (int rg = 0; rg < 4; ++rg) bt[rg] = (base + rg < N) ? batch[base + rg] : -1;

        float run[8];
        int cb = bt[0];
#pragma unroll
        for (int nb = 0; nb < 8; ++nb) run[nb] = acc2[nb][0] + nbv[nb];
#pragma unroll
        for (int rg = 1; rg < 4; ++rg) {
            if (bt[rg] == cb) {
#pragma unroll
                for (int nb = 0; nb < 8; ++nb) run[nb] += acc2[nb][rg] + nbv[nb];
            } else {
                if (cb >= 0) {
#pragma unroll
                    for (int nb = 0; nb < 8; ++nb)
                        atomicAdd(&pool_sum[cb * 128 + nb * 16 + lr], run[nb]);
                }
                cb = bt[rg];
#pragma unroll
                for (int nb = 0; nb < 8; ++nb) run[nb] = acc2[nb][rg] + nbv[nb];
            }
        }
        if (cb >= 0) {
#pragma unroll
            for (int nb = 0; nb < 8; ++nb)
                atomicAdd(&pool_sum[cb * 128 + nb * 16 + lr], run[nb]);
        }
    };

    load_tile(tile, agA, xpA);
    while (true) {
        int nt = tile + stride;
        compute(tile, nt < ntiles, nt, agA, xpA, agB, xpB);
        tile = nt; if (tile >= ntiles) break;
        nt = tile + stride;
        compute(tile, nt < ntiles, nt, agB, xpB, agA, xpA);
        tile = nt; if (tile >= ntiles) break;
    }
}

// ---------------------------------------------------------------------------
__global__ __launch_bounds__(64)
void final_kernel(const float* __restrict__ pool_sum, const float* __restrict__ pool_cnt,
                  const float* __restrict__ gW, const float* __restrict__ gb,
                  float* __restrict__ out)
{
    __shared__ float p_sh[5 * HID];
    int g = blockIdx.x, tid = threadIdx.x;
    for (int i = tid; i < 5 * HID; i += 64) {
        int t  = i >> 7;
        int jj = i & 127;
        float c = fmaxf(pool_cnt[t * G_ + g], 1.0f);
        p_sh[i] = pool_sum[((size_t)t * G_ + g) * HID + jj] / c;
    }
    __syncthreads();
    float acc = gb[tid];
#pragma unroll 8
    for (int k = 0; k < 5 * HID; ++k)
        acc += p_sh[k] * gW[k * 64 + tid];
    out[g * 64 + tid] = acc;
}

// ---------------------------------------------------------------------------
extern "C" void kernel_launch(void* const* d_in, const int* in_sizes, int n_in,
                              void* d_out, int out_size, void* d_ws, size_t ws_size,
                              hipStream_t stream)
{
    const float* x_value       = (const float*)d_in[0];
    const float* x_typ         = (const float*)d_in[1];
    const float* x_size_       = (const float*)d_in[2];
    const float* x_attribute   = (const float*)d_in[3];
    const float* x_instruction = (const float*)d_in[4];
    const float* Wl_vt = (const float*)d_in[5];
    const float* bl_vt = (const float*)d_in[6];
    const float* Wr_vt = (const float*)d_in[7];
    const float* Wl_iv = (const float*)d_in[8];
    const float* bl_iv = (const float*)d_in[9];
    const float* Wr_iv = (const float*)d_in[10];
    const float* Wl_vi = (const float*)d_in[11];
    const float* bl_vi = (const float*)d_in[12];
    const float* Wr_vi = (const float*)d_in[13];
    const float* Wl_va = (const float*)d_in[14];
    const float* bl_va = (const float*)d_in[15];
    const float* Wr_va = (const float*)d_in[16];
    const float* Wl_ts = (const float*)d_in[17];
    const float* bl_ts = (const float*)d_in[18];
    const float* Wr_ts = (const float*)d_in[19];
    const float* Wl_ii = (const float*)d_in[20];
    const float* bl_ii = (const float*)d_in[21];
    const float* Wr_ii = (const float*)d_in[22];
    const float* nW_typ         = (const float*)d_in[23];
    const float* nb_typ         = (const float*)d_in[24];
    const float* nW_value       = (const float*)d_in[25];
    const float* nb_value       = (const float*)d_in[26];
    const float* nW_instruction = (const float*)d_in[27];
    const float* nb_instruction = (const float*)d_in[28];
    const float* nW_attribute   = (const float*)d_in[29];
    const float* nb_attribute   = (const float*)d_in[30];
    const float* nW_size        = (const float*)d_in[31];
    const float* nb_size        = (const float*)d_in[32];
    const float* gW = (const float*)d_in[33];
    const float* gb = (const float*)d_in[34];
    const int* src_vt = (const int*)d_in[35];
    const int* dst_vt = (const int*)d_in[36];
    const int* src_iv = (const int*)d_in[37];
    const int* dst_iv = (const int*)d_in[38];
    const int* src_vi = (const int*)d_in[39];
    const int* dst_vi = (const int*)d_in[40];
    const int* src_va = (const int*)d_in[41];
    const int* dst_va = (const int*)d_in[42];
    const int* src_ts = (const int*)d_in[43];
    const int* dst_ts = (const int*)d_in[44];
    const int* src_ii = (const int*)d_in[45];
    const int* dst_ii = (const int*)d_in[46];
    const int* batch_typ         = (const int*)d_in[47];
    const int* batch_value       = (const int*)d_in[48];
    const int* batch_instruction = (const int*)d_in[49];
    const int* batch_attribute   = (const int*)d_in[50];
    const int* batch_size        = (const int*)d_in[51];

    // ---- workspace layout ----
    int* deg = (int*)d_ws;                                   // TOT_N (zeroed)
    float* pool_sum = (float*)(deg + TOT_N);                 // 5*G*HID (zeroed)
    float* pool_cnt = pool_sum + (size_t)5 * G_ * HID;       // 5*G (zeroed)
    size_t zero_bytes = (size_t)TOT_N * 4 + ((size_t)5 * G_ * HID + 5 * G_) * 4;

    int* cur  = (int*)(pool_cnt + 5 * G_);                   // TOT_N
    int* csum = cur + TOT_N;                                 // NCH
    int* coff = csum + NCH;                                  // NCH
    int* eidx = coff + NCH;                                  // TOT_E
    unsigned short* ab = (unsigned short*)(((uintptr_t)(eidx + TOT_E) + 63) & ~(uintptr_t)63);
    size_t ao = 0;
    unsigned short* agg_vt = ab + ao; ao += (size_t)NTv * 64;
    unsigned short* agg_iv = ab + ao; ao += (size_t)NVv * 64;
    unsigned short* agg_vi = ab + ao; ao += (size_t)NIv * 64;
    unsigned short* agg_va = ab + ao; ao += (size_t)NAv * 64;
    unsigned short* agg_ts = ab + ao; ao += (size_t)NSv * 32;
    unsigned short* agg_ii = ab + ao; ao += (size_t)NIv * 64;
    unsigned short* wt = (unsigned short*)(((uintptr_t)(ab + ao) + 63) & ~(uintptr_t)63);
    size_t wo = 0;
    unsigned short* w1p_vt = wt + wo; wo += 128 * 96;
    unsigned short* w1p_iv = wt + wo; wo += 128 * 128;
    unsigned short* w1p_vi = wt + wo; wo += 128 * 192;
    unsigned short* w1p_va = wt + wo; wo += 128 * 96;
    unsigned short* w1p_ts = wt + wo; wo += 128 * 64;
    unsigned short* nwp_t  = wt + wo; wo += 128 * 128;
    unsigned short* nwp_v  = wt + wo; wo += 128 * 128;
    unsigned short* nwp_i  = wt + wo; wo += 128 * 128;
    unsigned short* nwp_a  = wt + wo; wo += 128 * 128;
    unsigned short* nwp_s  = wt + wo; wo += 128 * 128;

    hipMemsetAsync(d_ws, 0, zero_bytes, stream);

    // packed weight prep (tiny)
    prep_wpack<<<(128 *  96 + 255) / 256, 256, 0, stream>>>(Wl_vt, 64, nullptr, 0, Wr_vt, nullptr, w1p_vt,  96);
    prep_wpack<<<(128 * 128 + 255) / 256, 256, 0, stream>>>(Wl_iv, 64, nullptr, 0, Wr_iv, nullptr, w1p_iv, 128);
    prep_wpack<<<(128 * 192 + 255) / 256, 256, 0, stream>>>(Wl_vi, 64, Wl_ii, 64, Wr_vi, Wr_ii,   w1p_vi, 192);
    prep_wpack<<<(128 *  96 + 255) / 256, 256, 0, stream>>>(Wl_va, 64, nullptr, 0, Wr_va, nullptr, w1p_va,  96);
    prep_wpack<<<(128 *  64 + 255) / 256, 256, 0, stream>>>(Wl_ts, 32, nullptr, 0, Wr_ts, nullptr, w1p_ts,  64);
    prep_wpack<<<(128 * 128 + 255) / 256, 256, 0, stream>>>(nW_typ,         128, nullptr, 0, nullptr, nullptr, nwp_t, 128);
    prep_wpack<<<(128 * 128 + 255) / 256, 256, 0, stream>>>(nW_value,       128, nullptr, 0, nullptr, nullptr, nwp_v, 128);
    prep_wpack<<<(128 * 128 + 255) / 256, 256, 0, stream>>>(nW_instruction, 128, nullptr, 0, nullptr, nullptr, nwp_i, 128);
    prep_wpack<<<(128 * 128 + 255) / 256, 256, 0, stream>>>(nW_attribute,   128, nullptr, 0, nullptr, nullptr, nwp_a, 128);
    prep_wpack<<<(128 * 128 + 255) / 256, 256, 0, stream>>>(nW_size,        128, nullptr, 0, nullptr, nullptr, nwp_s, 128);

    // CSR build
    edge_hist<<<(EVTv + 255) / 256, 256, 0, stream>>>(dst_vt, deg, OFF_VT, EVTv);
    edge_hist<<<(EIVv + 255) / 256, 256, 0, stream>>>(dst_iv, deg, OFF_IV, EIVv);
    edge_hist<<<(EVIv + 255) / 256, 256, 0, stream>>>(dst_vi, deg, OFF_VI, EVIv);
    edge_hist<<<(EVAv + 255) / 256, 256, 0, stream>>>(dst_va, deg, OFF_VA, EVAv);
    edge_hist<<<(ETSv + 255) / 256, 256, 0, stream>>>(dst_ts, deg, OFF_TS, ETSv);
    edge_hist<<<(EIIv + 255) / 256, 256, 0, stream>>>(dst_ii, deg, OFF_II, EIIv);

    scan_chunk_sum<<<NCH, 256, 0, stream>>>(deg, csum);
    scan_offsets<<<1, 256, 0, stream>>>(csum, coff);
    scan_write<<<NCH, 256, 0, stream>>>(deg, coff, cur);

    edge_pos<<<(EVTv + 255) / 256, 256, 0, stream>>>(src_vt, dst_vt, cur, eidx, OFF_VT, EVTv);
    edge_pos<<<(EIVv + 255) / 256, 256, 0, stream>>>(src_iv, dst_iv, cur, eidx, OFF_IV, EIVv);
    edge_pos<<<(EVIv + 255) / 256, 256, 0, stream>>>(src_vi, dst_vi, cur, eidx, OFF_VI, EVIv);
    edge_pos<<<(EVAv + 255) / 256, 256, 0, stream>>>(src_va, dst_va, cur, eidx, OFF_VA, EVAv);
    edge_pos<<<(ETSv + 255) / 256, 256, 0, stream>>>(src_ts, dst_ts, cur, eidx, OFF_TS, ETSv);
    edge_pos<<<(EIIv + 255) / 256, 256, 0, stream>>>(src_ii, dst_ii, cur, eidx, OFF_II, EIIv);

    batch_count<<<(NTv + 255) / 256, 256, 0, stream>>>(batch_typ,         pool_cnt + 0 * G_, NTv);
    batch_count<<<(NVv + 255) / 256, 256, 0, stream>>>(batch_value,       pool_cnt + 1 * G_, NVv);
    batch_count<<<(NIv + 255) / 256, 256, 0, stream>>>(batch_instruction, pool_cnt + 2 * G_, NIv);
    batch_count<<<(NAv + 255) / 256, 256, 0, stream>>>(batch_attribute,   pool_cnt + 3 * G_, NAv);
    batch_count<<<(NSv + 255) / 256, 256, 0, stream>>>(batch_size,        pool_cnt + 4 * G_, NSv);

    // gathers (16-lane groups, multi-node per wave)
    auto gblk = [](int N, int npw) {
        long waves = ((long)N + npw - 1) / npw;
        long blocks = (waves + 3) / 4;
        return (int)(blocks > 2048 ? 2048 : blocks);
    };
    gather_mean<64><<<gblk(NTv, 4), 256, 0, stream>>>(deg, cur, eidx, OFF_VT, x_value,       agg_vt, NTv);
    gather_mean<64><<<gblk(NVv, 4), 256, 0, stream>>>(deg, cur, eidx, OFF_IV, x_instruction, agg_iv, NVv);
    gather_mean<64><<<gblk(NIv, 4), 256, 0, stream>>>(deg, cur, eidx, OFF_VI, x_value,       agg_vi, NIv);
    gather_mean<64><<<gblk(NAv, 4), 256, 0, stream>>>(deg, cur, eidx, OFF_VA, x_value,       agg_va, NAv);
    gather_mean<32><<<gblk(NSv, 8), 256, 0, stream>>>(deg, cur, eidx, OFF_TS, x_typ,         agg_ts, NSv);
    gather_mean<64><<<gblk(NIv, 4), 256, 0, stream>>>(deg, cur, eidx, OFF_II, x_instruction, agg_ii, NIv);

    // persistent MFMA node kernels
    auto mgrid = [](int N) {
        int ntiles = (N + 63) / 64;
        return ntiles < 1280 ? ntiles : 1280;
    };
    sage_mfma<64, 32, false, 128,  96><<<mgrid(NTv), 256, 0, stream>>>(
        agg_vt, nullptr, x_typ, w1p_vt, bl_vt, nullptr,
        nwp_t, nb_typ, batch_typ, pool_sum + (size_t)0 * G_ * HID, NTv);
    sage_mfma<64, 64, false, 128, 128><<<mgrid(NVv), 256, 0, stream>>>(
        agg_iv, nullptr, x_value, w1p_iv, bl_iv, nullptr,
        nwp_v, nb_value, batch_value, pool_sum + (size_t)1 * G_ * HID, NVv);
    sage_mfma<64, 64, true,  192, 192><<<mgrid(NIv), 256, 0, stream>>>(
        agg_vi, agg_ii, x_instruction, w1p_vi, bl_vi, bl_ii,
        nwp_i, nb_instruction, batch_instruction, pool_sum + (size_t)2 * G_ * HID, NIv);
    sage_mfma<64, 32, false, 128,  96><<<mgrid(NAv), 256, 0, stream>>>(
        agg_va, nullptr, x_attribute, w1p_va, bl_va, nullptr,
        nwp_a, nb_attribute, batch_attribute, pool_sum + (size_t)3 * G_ * HID, NAv);
    sage_mfma<32, 32, false,  64,  64><<<mgrid(NSv), 256, 0, stream>>>(
        agg_ts, nullptr, x_size_, w1p_ts, bl_ts, nullptr,
        nwp_s, nb_size, batch_size, pool_sum + (size_t)4 * G_ * HID, NSv);

    final_kernel<<<G_, 64, 0, stream>>>(pool_sum, pool_cnt, gW, gb, (float*)d_out);
}

// Round 7
// 1305.915 us; speedup vs baseline: 2.0300x; 1.4661x over previous
//
#include <hip/hip_runtime.h>

namespace {
constexpr int G_  = 2048;
constexpr int HID = 128;
constexpr int NVv = 500000, NIv = 300000, NTv = 50000, NAv = 50000, NSv = 10000;
constexpr int EVTv = 500000, EIVv = 1500000, EVIv = 1500000, EVAv = 500000, ETSv = 50000, EIIv = 600000;
// concatenated per-(edge-type,dst-node) CSR space
constexpr int OFF_VT = 0;
constexpr int OFF_IV = OFF_VT + NTv;
constexpr int OFF_VI = OFF_IV + NVv;
constexpr int OFF_VA = OFF_VI + NIv;
constexpr int OFF_TS = OFF_VA + NAv;
constexpr int OFF_II = OFF_TS + NSv;
constexpr int TOT_N  = OFF_II + NIv;          // 1210000
constexpr int TOT_E  = EVTv + EIVv + EVIv + EVAv + ETSv + EIIv;  // 4650000
constexpr int NCH    = (TOT_N + 1023) / 1024; // 1182
}

typedef short s16x8 __attribute__((ext_vector_type(8)));
typedef float f32x4 __attribute__((ext_vector_type(4)));

__device__ __forceinline__ float4 ld4(const float* p) { return *(const float4*)p; }

__device__ __forceinline__ unsigned short f2bf(float x) {
    unsigned u = __float_as_uint(x);
    u += 0x7fffu + ((u >> 16) & 1u);
    return (unsigned short)(u >> 16);
}

// ---------------------------------------------------------------------------
// CSR build
// ---------------------------------------------------------------------------
__global__ __launch_bounds__(256)
void edge_hist(const int* __restrict__ dst, int* __restrict__ deg, int off, int E)
{
    int i = blockIdx.x * 256 + threadIdx.x;
    if (i < E) atomicAdd(&deg[off + dst[i]], 1);
}

__global__ __launch_bounds__(256)
void scan_chunk_sum(const int* __restrict__ deg, int* __restrict__ csum)
{
    __shared__ int sc[256];
    int blk = blockIdx.x, tid = threadIdx.x;
    int base = blk * 1024 + tid * 4;
    int s = 0;
#pragma unroll
    for (int k = 0; k < 4; ++k) { int idx = base + k; if (idx < TOT_N) s += deg[idx]; }
    sc[tid] = s; __syncthreads();
    for (int d = 128; d > 0; d >>= 1) {
        if (tid < d) sc[tid] += sc[tid + d];
        __syncthreads();
    }
    if (tid == 0) csum[blk] = sc[0];
}

__global__ __launch_bounds__(256)
void scan_offsets(const int* __restrict__ csum, int* __restrict__ coff)
{
    __shared__ int sc[256];
    int tid = threadIdx.x;
    int s[5]; int tsum = 0;
#pragma unroll
    for (int k = 0; k < 5; ++k) { int idx = tid * 5 + k; s[k] = (idx < NCH) ? csum[idx] : 0; tsum += s[k]; }
    sc[tid] = tsum; __syncthreads();
    for (int d = 1; d < 256; d <<= 1) {
        int v = (tid >= d) ? sc[tid - d] : 0;
        __syncthreads();
        sc[tid] += v;
        __syncthreads();
    }
    int run = sc[tid] - tsum;   // exclusive
#pragma unroll
    for (int k = 0; k < 5; ++k) { int idx = tid * 5 + k; if (idx < NCH) coff[idx] = run; run += s[k]; }
}

__global__ __launch_bounds__(256)
void scan_write(const int* __restrict__ deg, const int* __restrict__ coff, int* __restrict__ cur)
{
    __shared__ int sc[256];
    int blk = blockIdx.x, tid = threadIdx.x;
    int base = blk * 1024 + tid * 4;
    int v[4]; int tsum = 0;
#pragma unroll
    for (int k = 0; k < 4; ++k) { int idx = base + k; v[k] = (idx < TOT_N) ? deg[idx] : 0; tsum += v[k]; }
    sc[tid] = tsum; __syncthreads();
    for (int d = 1; d < 256; d <<= 1) {
        int t = (tid >= d) ? sc[tid - d] : 0;
        __syncthreads();
        sc[tid] += t;
        __syncthreads();
    }
    int run = coff[blk] + sc[tid] - tsum;
#pragma unroll
    for (int k = 0; k < 4; ++k) { int idx = base + k; if (idx < TOT_N) cur[idx] = run; run += v[k]; }
}

__global__ __launch_bounds__(256)
void edge_pos(const int* __restrict__ src, const int* __restrict__ dst,
              int* __restrict__ cur, int* __restrict__ eidx, int off, int E)
{
    int i = blockIdx.x * 256 + threadIdx.x;
    if (i < E) {
        int p = atomicAdd(&cur[off + dst[i]], 1);
        eidx[p] = src[i];
    }
}

__global__ __launch_bounds__(256)
void batch_count(const int* __restrict__ batch, float* __restrict__ cnt, int N)
{
    int i = blockIdx.x * 256 + threadIdx.x;
    if (i < N) atomicAdd(&cnt[batch[i]], 1.0f);
}

// ---------------------------------------------------------------------------
// Packed weight prep: out[(ks*8+nb)*512 + l*8 + j] = bf16(W1[k][row]),
// row = nb*16 + (l&15), k = ks*32 + (l>>4)*8 + j.
// W1 rows (k-major) = [S0(L0) | S1(L1) | S2(+S2b)].
// ---------------------------------------------------------------------------
__global__ __launch_bounds__(256)
void prep_wpack(const float* __restrict__ S0, int L0,
                const float* __restrict__ S1, int L1,
                const float* __restrict__ S2, const float* __restrict__ S2b,
                unsigned short* __restrict__ out, int K1)
{
    int i = blockIdx.x * 256 + threadIdx.x;
    int total = (K1 / 32) * 8 * 512;
    if (i >= total) return;
    int frag = i >> 9;
    int rem  = i & 511;
    int l = rem >> 3, j = rem & 7;
    int ks = frag >> 3, nb = frag & 7;
    int row = nb * 16 + (l & 15);
    int k = ks * 32 + (l >> 4) * 8 + j;
    float v;
    if (k < L0) v = S0[k * 128 + row];
    else if (k < L0 + L1) v = S1[(k - L0) * 128 + row];
    else {
        int kk = k - L0 - L1;
        v = S2[kk * 128 + row];
        if (S2b) v += S2b[kk * 128 + row];
    }
    out[i] = f2bf(v);
}

// ---------------------------------------------------------------------------
// Gather v2: 16-lane float4 groups -> 4 nodes per wave (8 for D=32).
// ---------------------------------------------------------------------------
template<int D>
__global__ __launch_bounds__(256)
void gather_mean(const int* __restrict__ deg, const int* __restrict__ cur,
                 const int* __restrict__ eidx, int off,
                 const float* __restrict__ xs,
                 unsigned short* __restrict__ agg, int N)
{
    constexpr int LPG = D / 4;
    constexpr int NPW = 64 / LPG;
    const int wid   = (blockIdx.x * 256 + threadIdx.x) >> 6;
    const int nwave = (gridDim.x * 256) >> 6;
    const int lane  = threadIdx.x & 63;
    const int sub   = lane / LPG;
    const int col4  = (lane % LPG) * 4;

    for (int n = wid * NPW + sub; n < N; n += nwave * NPW) {
        int e_end = cur[off + n];
        int d     = deg[off + n];
        int e0    = e_end - d;
        float ax = 0.f, ay = 0.f, az = 0.f, aw = 0.f;
        int t = 0;
        for (; t + 2 <= d; t += 2) {
            int s0 = eidx[e0 + t];
            int s1 = eidx[e0 + t + 1];
            float4 v0 = ld4(&xs[(size_t)s0 * D + col4]);
            float4 v1 = ld4(&xs[(size_t)s1 * D + col4]);
            ax += v0.x + v1.x; ay += v0.y + v1.y;
            az += v0.z + v1.z; aw += v0.w + v1.w;
        }
        if (t < d) {
            int s = eidx[e0 + t];
            float4 v = ld4(&xs[(size_t)s * D + col4]);
            ax += v.x; ay += v.y; az += v.z; aw += v.w;
        }
        float inv = 1.0f / fmaxf((float)d, 1.0f);
        unsigned p0 = (unsigned)f2bf(ax * inv) | ((unsigned)f2bf(ay * inv) << 16);
        unsigned p1 = (unsigned)f2bf(az * inv) | ((unsigned)f2bf(aw * inv) << 16);
        *(uint2*)&agg[(size_t)n * D + col4] = make_uint2(p0, p1);
    }
}

// ---------------------------------------------------------------------------
// MFMA node kernel, register-resident weights. Block = 256 thr (4 waves),
// one 64-node tile. Wave w owns output cols [w*32, w*32+32) and iterates all
// 64 rows (4 row-frags). W1/nW fragments live in VGPRs (loaded once,
// coalesced from packed layout) -> no global loads in the MFMA loop.
// Pooling: 16-row same-graph fast path via shfl_xor -> 16x fewer atomics.
// ---------------------------------------------------------------------------
template<int DSa, int DD, bool HAS2, int ASTR, int K1, int MINW>
__global__ __launch_bounds__(256, MINW)
void sage_mfma(const unsigned short* __restrict__ agg1,
               const unsigned short* __restrict__ agg2,
               const float* __restrict__ xd,
               const unsigned short* __restrict__ W1P,
               const float* __restrict__ bl, const float* __restrict__ bl2,
               const unsigned short* __restrict__ nWP,
               const float* __restrict__ nbp,
               const int* __restrict__ batch,
               float* __restrict__ pool_sum, int N)
{
    constexpr int KST  = K1 / 32;
    constexpr int GCOL = HAS2 ? 2 * DSa : DSa;
    constexpr int XOFF = GCOL;
    constexpr int C8g  = GCOL / 8;
    constexpr int C4d  = DD / 4;

    __shared__ __align__(16) unsigned short a_sh[64 * ASTR];
    __shared__ __align__(16) unsigned short h_sh[64 * 128];
    __shared__ int batch_sh[64];

    const int tid = threadIdx.x;
    const int w = tid >> 6, l = tid & 63, lg = l >> 4, lr = l & 15;
    const int node0 = blockIdx.x * 64;
    const unsigned swz = (unsigned)(lr & 7) << 4;

    if (tid < 64) batch_sh[tid] = (node0 + tid < N) ? batch[node0 + tid] : -1;

    // ---- stage A tile (direct global -> swizzled LDS) ----
    for (int c = tid; c < 64 * C8g; c += 256) {
        int r = c / C8g; int col = (c - r * C8g) * 8; int node = node0 + r;
        uint4 pk = make_uint4(0u, 0u, 0u, 0u);
        if (node < N) {
            const unsigned short* sp = (!HAS2 || col < DSa)
                ? &agg1[(size_t)node * DSa + col]
                : &agg2[(size_t)node * DSa + (col - DSa)];
            pk = *(const uint4*)sp;
        }
        unsigned byte = ((unsigned)(r * ASTR + col) * 2u) ^ ((unsigned)(r & 7) << 4);
        *(uint4*)((char*)a_sh + byte) = pk;
    }
    for (int c = tid; c < 64 * C4d; c += 256) {
        int r = c / C4d; int col4 = (c - r * C4d) * 4; int node = node0 + r;
        float4 v = (node < N) ? ld4(&xd[(size_t)node * DD + col4])
                              : make_float4(0.f, 0.f, 0.f, 0.f);
        uint2 p;
        p.x = (unsigned)f2bf(v.x) | ((unsigned)f2bf(v.y) << 16);
        p.y = (unsigned)f2bf(v.z) | ((unsigned)f2bf(v.w) << 16);
        unsigned byte = ((unsigned)(r * ASTR + XOFF + col4) * 2u) ^ ((unsigned)(r & 7) << 4);
        *(uint2*)((char*)a_sh + byte) = p;
    }

    // ---- stage-1 weights -> registers (coalesced 1KB per fragment) ----
    s16x8 w1[2][KST];
#pragma unroll
    for (int j = 0; j < 2; ++j)
#pragma unroll
        for (int ks = 0; ks < KST; ++ks)
            w1[j][ks] = *(const s16x8*)&W1P[(unsigned)(ks * 8 + (w * 2 + j)) * 512 + (unsigned)l * 8];

    float b1[2];
#pragma unroll
    for (int j = 0; j < 2; ++j) {
        int col = (w * 2 + j) * 16 + lr;
        float b = bl[col];
        if constexpr (HAS2) b += bl2[col];
        b1[j] = b;
    }

    __syncthreads();

    // ---- stage 1: h = A @ W1 (ds_read + MFMA only) ----
    f32x4 acc[4][2];
#pragma unroll
    for (int rf = 0; rf < 4; ++rf)
#pragma unroll
        for (int j = 0; j < 2; ++j) acc[rf][j] = (f32x4){0.f, 0.f, 0.f, 0.f};

#pragma unroll
    for (int ks = 0; ks < KST; ++ks) {
        s16x8 af[4];
#pragma unroll
        for (int rf = 0; rf < 4; ++rf)
            af[rf] = *(const s16x8*)((const char*)a_sh +
                        (((unsigned)((rf * 16 + lr) * ASTR + ks * 32 + lg * 8) * 2u) ^ swz));
#pragma unroll
        for (int rf = 0; rf < 4; ++rf)
#pragma unroll
            for (int j = 0; j < 2; ++j)
                acc[rf][j] = __builtin_amdgcn_mfma_f32_16x16x32_bf16(af[rf], w1[j][ks], acc[rf][j], 0, 0, 0);
    }

    // ---- bias + relu -> bf16 h in LDS ----
#pragma unroll
    for (int rf = 0; rf < 4; ++rf)
#pragma unroll
        for (int j = 0; j < 2; ++j) {
            int col = (w * 2 + j) * 16 + lr;
#pragma unroll
            for (int rg = 0; rg < 4; ++rg) {
                float hv = fmaxf(acc[rf][j][rg] + b1[j], 0.0f);
                int row = rf * 16 + lg * 4 + rg;
                unsigned byte = ((unsigned)(row * 128 + col) * 2u) ^ ((unsigned)(row & 7) << 4);
                *(unsigned short*)((char*)h_sh + byte) = f2bf(hv);
            }
        }

    // ---- stage-2 weights -> registers ----
    s16x8 w2[2][4];
#pragma unroll
    for (int j = 0; j < 2; ++j)
#pragma unroll
        for (int ks = 0; ks < 4; ++ks)
            w2[j][ks] = *(const s16x8*)&nWP[(unsigned)(ks * 8 + (w * 2 + j)) * 512 + (unsigned)l * 8];

    float nbv[2];
#pragma unroll
    for (int j = 0; j < 2; ++j) nbv[j] = nbp[(w * 2 + j) * 16 + lr];

    __syncthreads();

    // ---- stage 2: z = h @ nW ----
    f32x4 acc2[4][2];
#pragma unroll
    for (int rf = 0; rf < 4; ++rf)
#pragma unroll
        for (int j = 0; j < 2; ++j) acc2[rf][j] = (f32x4){0.f, 0.f, 0.f, 0.f};

#pragma unroll
    for (int ks = 0; ks < 4; ++ks) {
        s16x8 hf[4];
#pragma unroll
        for (int rf = 0; rf < 4; ++rf)
            hf[rf] = *(const s16x8*)((const char*)h_sh +
                        (((unsigned)((rf * 16 + lr) * 128 + ks * 32 + lg * 8) * 2u) ^ swz));
#pragma unroll
        for (int rf = 0; rf < 4; ++rf)
#pragma unroll
            for (int j = 0; j < 2; ++j)
                acc2[rf][j] = __builtin_amdgcn_mfma_f32_16x16x32_bf16(hf[rf], w2[j][ks], acc2[rf][j], 0, 0, 0);
    }

    // ---- pooling ----
#pragma unroll
    for (int rf = 0; rf < 4; ++rf) {
        int gf = batch_sh[rf * 16];
        int gl = batch_sh[rf * 16 + 15];
        if (gf == gl && gf >= 0) {
            // whole 16-row group is one graph: shfl-reduce across lg, 1 atomic/16 rows
#pragma unroll
            for (int j = 0; j < 2; ++j) {
                float s = acc2[rf][j][0] + acc2[rf][j][1] + acc2[rf][j][2] + acc2[rf][j][3]
                        + 4.0f * nbv[j];
                s += __shfl_xor(s, 16);
                s += __shfl_xor(s, 32);
                if (lg == 0)
                    atomicAdd(&pool_sum[gf * 128 + (w * 2 + j) * 16 + lr], s);
            }
        } else {
            int rbase = rf * 16 + lg * 4;
            int bt[4];
#pragma unroll
            for (int rg = 0; rg < 4; ++rg) bt[rg] = batch_sh[rbase + rg];
#pragma unroll
            for (int j = 0; j < 2; ++j) {
                int col = (w * 2 + j) * 16 + lr;
                float run = acc2[rf][j][0] + nbv[j];
                int cb = bt[0];
#pragma unroll
                for (int rg = 1; rg < 4; ++rg) {
                    float z = acc2[rf][j][rg] + nbv[j];
                    if (bt[rg] == cb) run += z;
                    else {
                        if (cb >= 0) atomicAdd(&pool_sum[cb * 128 + col], run);
                        cb = bt[rg]; run = z;
                    }
                }
                if (cb >= 0) atomicAdd(&pool_sum[cb * 128 + col], run);
            }
        }
    }
}

// ---------------------------------------------------------------------------
__global__ __launch_bounds__(64)
void final_kernel(const float* __restrict__ pool_sum, const float* __restrict__ pool_cnt,
                  const float* __restrict__ gW, const float* __restrict__ gb,
                  float* __restrict__ out)
{
    __shared__ float p_sh[5 * HID];
    int g = blockIdx.x, tid = threadIdx.x;
    for (int i = tid; i < 5 * HID; i += 64) {
        int t  = i >> 7;
        int jj = i & 127;
        float c = fmaxf(pool_cnt[t * G_ + g], 1.0f);
        p_sh[i] = pool_sum[((size_t)t * G_ + g) * HID + jj] / c;
    }
    __syncthreads();
    float acc = gb[tid];
#pragma unroll 8
    for (int k = 0; k < 5 * HID; ++k)
        acc += p_sh[k] * gW[k * 64 + tid];
    out[g * 64 + tid] = acc;
}

// ---------------------------------------------------------------------------
extern "C" void kernel_launch(void* const* d_in, const int* in_sizes, int n_in,
                              void* d_out, int out_size, void* d_ws, size_t ws_size,
                              hipStream_t stream)
{
    const float* x_value       = (const float*)d_in[0];
    const float* x_typ         = (const float*)d_in[1];
    const float* x_size_       = (const float*)d_in[2];
    const float* x_attribute   = (const float*)d_in[3];
    const float* x_instruction = (const float*)d_in[4];
    const float* Wl_vt = (const float*)d_in[5];
    const float* bl_vt = (const float*)d_in[6];
    const float* Wr_vt = (const float*)d_in[7];
    const float* Wl_iv = (const float*)d_in[8];
    const float* bl_iv = (const float*)d_in[9];
    const float* Wr_iv = (const float*)d_in[10];
    const float* Wl_vi = (const float*)d_in[11];
    const float* bl_vi = (const float*)d_in[12];
    const float* Wr_vi = (const float*)d_in[13];
    const float* Wl_va = (const float*)d_in[14];
    const float* bl_va = (const float*)d_in[15];
    const float* Wr_va = (const float*)d_in[16];
    const float* Wl_ts = (const float*)d_in[17];
    const float* bl_ts = (const float*)d_in[18];
    const float* Wr_ts = (const float*)d_in[19];
    const float* Wl_ii = (const float*)d_in[20];
    const float* bl_ii = (const float*)d_in[21];
    const float* Wr_ii = (const float*)d_in[22];
    const float* nW_typ         = (const float*)d_in[23];
    const float* nb_typ         = (const float*)d_in[24];
    const float* nW_value       = (const float*)d_in[25];
    const float* nb_value       = (const float*)d_in[26];
    const float* nW_instruction = (const float*)d_in[27];
    const float* nb_instruction = (const float*)d_in[28];
    const float* nW_attribute   = (const float*)d_in[29];
    const float* nb_attribute   = (const float*)d_in[30];
    const float* nW_size        = (const float*)d_in[31];
    const float* nb_size        = (const float*)d_in[32];
    const float* gW = (const float*)d_in[33];
    const float* gb = (const float*)d_in[34];
    const int* src_vt = (const int*)d_in[35];
    const int* dst_vt = (const int*)d_in[36];
    const int* src_iv = (const int*)d_in[37];
    const int* dst_iv = (const int*)d_in[38];
    const int* src_vi = (const int*)d_in[39];
    const int* dst_vi = (const int*)d_in[40];
    const int* src_va = (const int*)d_in[41];
    const int* dst_va = (const int*)d_in[42];
    const int* src_ts = (const int*)d_in[43];
    const int* dst_ts = (const int*)d_in[44];
    const int* src_ii = (const int*)d_in[45];
    const int* dst_ii = (const int*)d_in[46];
    const int* batch_typ         = (const int*)d_in[47];
    const int* batch_value       = (const int*)d_in[48];
    const int* batch_instruction = (const int*)d_in[49];
    const int* batch_attribute   = (const int*)d_in[50];
    const int* batch_size        = (const int*)d_in[51];

    // ---- workspace layout ----
    int* deg = (int*)d_ws;                                   // TOT_N (zeroed)
    float* pool_sum = (float*)(deg + TOT_N);                 // 5*G*HID (zeroed)
    float* pool_cnt = pool_sum + (size_t)5 * G_ * HID;       // 5*G (zeroed)
    size_t zero_bytes = (size_t)TOT_N * 4 + ((size_t)5 * G_ * HID + 5 * G_) * 4;

    int* cur  = (int*)(pool_cnt + 5 * G_);                   // TOT_N
    int* csum = cur + TOT_N;                                 // NCH
    int* coff = csum + NCH;                                  // NCH
    int* eidx = coff + NCH;                                  // TOT_E
    unsigned short* ab = (unsigned short*)(((uintptr_t)(eidx + TOT_E) + 63) & ~(uintptr_t)63);
    size_t ao = 0;
    unsigned short* agg_vt = ab + ao; ao += (size_t)NTv * 64;
    unsigned short* agg_iv = ab + ao; ao += (size_t)NVv * 64;
    unsigned short* agg_vi = ab + ao; ao += (size_t)NIv * 64;
    unsigned short* agg_va = ab + ao; ao += (size_t)NAv * 64;
    unsigned short* agg_ts = ab + ao; ao += (size_t)NSv * 32;
    unsigned short* agg_ii = ab + ao; ao += (size_t)NIv * 64;
    unsigned short* wt = (unsigned short*)(((uintptr_t)(ab + ao) + 63) & ~(uintptr_t)63);
    size_t wo = 0;
    unsigned short* w1p_vt = wt + wo; wo += 128 * 96;
    unsigned short* w1p_iv = wt + wo; wo += 128 * 128;
    unsigned short* w1p_vi = wt + wo; wo += 128 * 192;
    unsigned short* w1p_va = wt + wo; wo += 128 * 96;
    unsigned short* w1p_ts = wt + wo; wo += 128 * 64;
    unsigned short* nwp_t  = wt + wo; wo += 128 * 128;
    unsigned short* nwp_v  = wt + wo; wo += 128 * 128;
    unsigned short* nwp_i  = wt + wo; wo += 128 * 128;
    unsigned short* nwp_a  = wt + wo; wo += 128 * 128;
    unsigned short* nwp_s  = wt + wo; wo += 128 * 128;

    hipMemsetAsync(d_ws, 0, zero_bytes, stream);

    // packed weight prep (tiny)
    prep_wpack<<<(128 *  96 + 255) / 256, 256, 0, stream>>>(Wl_vt, 64, nullptr, 0, Wr_vt, nullptr, w1p_vt,  96);
    prep_wpack<<<(128 * 128 + 255) / 256, 256, 0, stream>>>(Wl_iv, 64, nullptr, 0, Wr_iv, nullptr, w1p_iv, 128);
    prep_wpack<<<(128 * 192 + 255) / 256, 256, 0, stream>>>(Wl_vi, 64, Wl_ii, 64, Wr_vi, Wr_ii,   w1p_vi, 192);
    prep_wpack<<<(128 *  96 + 255) / 256, 256, 0, stream>>>(Wl_va, 64, nullptr, 0, Wr_va, nullptr, w1p_va,  96);
    prep_wpack<<<(128 *  64 + 255) / 256, 256, 0, stream>>>(Wl_ts, 32, nullptr, 0, Wr_ts, nullptr, w1p_ts,  64);
    prep_wpack<<<(128 * 128 + 255) / 256, 256, 0, stream>>>(nW_typ,         128, nullptr, 0, nullptr, nullptr, nwp_t, 128);
    prep_wpack<<<(128 * 128 + 255) / 256, 256, 0, stream>>>(nW_value,       128, nullptr, 0, nullptr, nullptr, nwp_v, 128);
    prep_wpack<<<(128 * 128 + 255) / 256, 256, 0, stream>>>(nW_instruction, 128, nullptr, 0, nullptr, nullptr, nwp_i, 128);
    prep_wpack<<<(128 * 128 + 255) / 256, 256, 0, stream>>>(nW_attribute,   128, nullptr, 0, nullptr, nullptr, nwp_a, 128);
    prep_wpack<<<(128 * 128 + 255) / 256, 256, 0, stream>>>(nW_size,        128, nullptr, 0, nullptr, nullptr, nwp_s, 128);

    // CSR build
    edge_hist<<<(EVTv + 255) / 256, 256, 0, stream>>>(dst_vt, deg, OFF_VT, EVTv);
    edge_hist<<<(EIVv + 255) / 256, 256, 0, stream>>>(dst_iv, deg, OFF_IV, EIVv);
    edge_hist<<<(EVIv + 255) / 256, 256, 0, stream>>>(dst_vi, deg, OFF_VI, EVIv);
    edge_hist<<<(EVAv + 255) / 256, 256, 0, stream>>>(dst_va, deg, OFF_VA, EVAv);
    edge_hist<<<(ETSv + 255) / 256, 256, 0, stream>>>(dst_ts, deg, OFF_TS, ETSv);
    edge_hist<<<(EIIv + 255) / 256, 256, 0, stream>>>(dst_ii, deg, OFF_II, EIIv);

    scan_chunk_sum<<<NCH, 256, 0, stream>>>(deg, csum);
    scan_offsets<<<1, 256, 0, stream>>>(csum, coff);
    scan_write<<<NCH, 256, 0, stream>>>(deg, coff, cur);

    edge_pos<<<(EVTv + 255) / 256, 256, 0, stream>>>(src_vt, dst_vt, cur, eidx, OFF_VT, EVTv);
    edge_pos<<<(EIVv + 255) / 256, 256, 0, stream>>>(src_iv, dst_iv, cur, eidx, OFF_IV, EIVv);
    edge_pos<<<(EVIv + 255) / 256, 256, 0, stream>>>(src_vi, dst_vi, cur, eidx, OFF_VI, EVIv);
    edge_pos<<<(EVAv + 255) / 256, 256, 0, stream>>>(src_va, dst_va, cur, eidx, OFF_VA, EVAv);
    edge_pos<<<(ETSv + 255) / 256, 256, 0, stream>>>(src_ts, dst_ts, cur, eidx, OFF_TS, ETSv);
    edge_pos<<<(EIIv + 255) / 256, 256, 0, stream>>>(src_ii, dst_ii, cur, eidx, OFF_II, EIIv);

    batch_count<<<(NTv + 255) / 256, 256, 0, stream>>>(batch_typ,         pool_cnt + 0 * G_, NTv);
    batch_count<<<(NVv + 255) / 256, 256, 0, stream>>>(batch_value,       pool_cnt + 1 * G_, NVv);
    batch_count<<<(NIv + 255) / 256, 256, 0, stream>>>(batch_instruction, pool_cnt + 2 * G_, NIv);
    batch_count<<<(NAv + 255) / 256, 256, 0, stream>>>(batch_attribute,   pool_cnt + 3 * G_, NAv);
    batch_count<<<(NSv + 255) / 256, 256, 0, stream>>>(batch_size,        pool_cnt + 4 * G_, NSv);

    // gathers (16-lane groups, multi-node per wave)
    auto gblk = [](int N, int npw) {
        long waves = ((long)N + npw - 1) / npw;
        long blocks = (waves + 3) / 4;
        return (int)(blocks > 2048 ? 2048 : blocks);
    };
    gather_mean<64><<<gblk(NTv, 4), 256, 0, stream>>>(deg, cur, eidx, OFF_VT, x_value,       agg_vt, NTv);
    gather_mean<64><<<gblk(NVv, 4), 256, 0, stream>>>(deg, cur, eidx, OFF_IV, x_instruction, agg_iv, NVv);
    gather_mean<64><<<gblk(NIv, 4), 256, 0, stream>>>(deg, cur, eidx, OFF_VI, x_value,       agg_vi, NIv);
    gather_mean<64><<<gblk(NAv, 4), 256, 0, stream>>>(deg, cur, eidx, OFF_VA, x_value,       agg_va, NAv);
    gather_mean<32><<<gblk(NSv, 8), 256, 0, stream>>>(deg, cur, eidx, OFF_TS, x_typ,         agg_ts, NSv);
    gather_mean<64><<<gblk(NIv, 4), 256, 0, stream>>>(deg, cur, eidx, OFF_II, x_instruction, agg_ii, NIv);

    // MFMA node kernels (one 64-node tile per block)
    sage_mfma<64, 32, false, 128,  96, 4><<<(NTv + 63) / 64, 256, 0, stream>>>(
        agg_vt, nullptr, x_typ, w1p_vt, bl_vt, nullptr,
        nwp_t, nb_typ, batch_typ, pool_sum + (size_t)0 * G_ * HID, NTv);
    sage_mfma<64, 64, false, 128, 128, 4><<<(NVv + 63) / 64, 256, 0, stream>>>(
        agg_iv, nullptr, x_value, w1p_iv, bl_iv, nullptr,
        nwp_v, nb_value, batch_value, pool_sum + (size_t)1 * G_ * HID, NVv);
    sage_mfma<64, 64, true,  192, 192, 3><<<(NIv + 63) / 64, 256, 0, stream>>>(
        agg_vi, agg_ii, x_instruction, w1p_vi, bl_vi, bl_ii,
        nwp_i, nb_instruction, batch_instruction, pool_sum + (size_t)2 * G_ * HID, NIv);
    sage_mfma<64, 32, false, 128,  96, 4><<<(NAv + 63) / 64, 256, 0, stream>>>(
        agg_va, nullptr, x_attribute, w1p_va, bl_va, nullptr,
        nwp_a, nb_attribute, batch_attribute, pool_sum + (size_t)3 * G_ * HID, NAv);
    sage_mfma<32, 32, false,  64,  64, 4><<<(NSv + 63) / 64, 256, 0, stream>>>(
        agg_ts, nullptr, x_size_, w1p_ts, bl_ts, nullptr,
        nwp_s, nb_size, batch_size, pool_sum + (size_t)4 * G_ * HID, NSv);

    final_kernel<<<G_, 64, 0, stream>>>(pool_sum, pool_cnt, gW, gb, (float*)d_out);
}

// Round 8
// 1055.571 us; speedup vs baseline: 2.5115x; 1.2372x over previous
//
#include <hip/hip_runtime.h>

namespace {
constexpr int G_  = 2048;
constexpr int HID = 128;
constexpr int NVv = 500000, NIv = 300000, NTv = 50000, NAv = 50000, NSv = 10000;
constexpr int EVTv = 500000, EIVv = 1500000, EVIv = 1500000, EVAv = 500000, ETSv = 50000, EIIv = 600000;
// concatenated per-(edge-type,dst-node) CSR space
constexpr int OFF_VT = 0;
constexpr int OFF_IV = OFF_VT + NTv;
constexpr int OFF_VI = OFF_IV + NVv;
constexpr int OFF_VA = OFF_VI + NIv;
constexpr int OFF_TS = OFF_VA + NAv;
constexpr int OFF_II = OFF_TS + NSv;
constexpr int TOT_N  = OFF_II + NIv;          // 1210000
constexpr int TOT_E  = EVTv + EIVv + EVIv + EVAv + ETSv + EIIv;  // 4650000
constexpr int NCH    = (TOT_N + 1023) / 1024; // 1182
}

typedef short s16x8 __attribute__((ext_vector_type(8)));
typedef float f32x4 __attribute__((ext_vector_type(4)));

__device__ __forceinline__ float4 ld4(const float* p) { return *(const float4*)p; }

__device__ __forceinline__ unsigned short f2bf(float x) {
    unsigned u = __float_as_uint(x);
    u += 0x7fffu + ((u >> 16) & 1u);
    return (unsigned short)(u >> 16);
}

__device__ __forceinline__ void addbf8(float (&acc)[8], uint4 v) {
    acc[0] += __uint_as_float((v.x & 0xFFFFu) << 16);
    acc[1] += __uint_as_float(v.x & 0xFFFF0000u);
    acc[2] += __uint_as_float((v.y & 0xFFFFu) << 16);
    acc[3] += __uint_as_float(v.y & 0xFFFF0000u);
    acc[4] += __uint_as_float((v.z & 0xFFFFu) << 16);
    acc[5] += __uint_as_float(v.z & 0xFFFF0000u);
    acc[6] += __uint_as_float((v.w & 0xFFFFu) << 16);
    acc[7] += __uint_as_float(v.w & 0xFFFF0000u);
}

// ---------------------------------------------------------------------------
// fp32 -> bf16 table conversion (8 elems/thread)
// ---------------------------------------------------------------------------
__global__ __launch_bounds__(256)
void conv_bf16(const float* __restrict__ src, unsigned short* __restrict__ dst, int n8)
{
    int i = blockIdx.x * 256 + threadIdx.x;
    if (i >= n8) return;
    float4 a = ld4(&src[(size_t)i * 8]);
    float4 b = ld4(&src[(size_t)i * 8 + 4]);
    uint4 o;
    o.x = (unsigned)f2bf(a.x) | ((unsigned)f2bf(a.y) << 16);
    o.y = (unsigned)f2bf(a.z) | ((unsigned)f2bf(a.w) << 16);
    o.z = (unsigned)f2bf(b.x) | ((unsigned)f2bf(b.y) << 16);
    o.w = (unsigned)f2bf(b.z) | ((unsigned)f2bf(b.w) << 16);
    *(uint4*)&dst[(size_t)i * 8] = o;
}

// ---------------------------------------------------------------------------
// CSR build
// ---------------------------------------------------------------------------
__global__ __launch_bounds__(256)
void edge_hist(const int* __restrict__ dst, int* __restrict__ deg, int off, int E)
{
    int i = blockIdx.x * 256 + threadIdx.x;
    if (i < E) atomicAdd(&deg[off + dst[i]], 1);
}

__global__ __launch_bounds__(256)
void scan_chunk_sum(const int* __restrict__ deg, int* __restrict__ csum)
{
    __shared__ int sc[256];
    int blk = blockIdx.x, tid = threadIdx.x;
    int base = blk * 1024 + tid * 4;
    int s = 0;
#pragma unroll
    for (int k = 0; k < 4; ++k) { int idx = base + k; if (idx < TOT_N) s += deg[idx]; }
    sc[tid] = s; __syncthreads();
    for (int d = 128; d > 0; d >>= 1) {
        if (tid < d) sc[tid] += sc[tid + d];
        __syncthreads();
    }
    if (tid == 0) csum[blk] = sc[0];
}

__global__ __launch_bounds__(256)
void scan_offsets(const int* __restrict__ csum, int* __restrict__ coff)
{
    __shared__ int sc[256];
    int tid = threadIdx.x;
    int s[5]; int tsum = 0;
#pragma unroll
    for (int k = 0; k < 5; ++k) { int idx = tid * 5 + k; s[k] = (idx < NCH) ? csum[idx] : 0; tsum += s[k]; }
    sc[tid] = tsum; __syncthreads();
    for (int d = 1; d < 256; d <<= 1) {
        int v = (tid >= d) ? sc[tid - d] : 0;
        __syncthreads();
        sc[tid] += v;
        __syncthreads();
    }
    int run = sc[tid] - tsum;   // exclusive
#pragma unroll
    for (int k = 0; k < 5; ++k) { int idx = tid * 5 + k; if (idx < NCH) coff[idx] = run; run += s[k]; }
}

__global__ __launch_bounds__(256)
void scan_write(const int* __restrict__ deg, const int* __restrict__ coff, int* __restrict__ cur)
{
    __shared__ int sc[256];
    int blk = blockIdx.x, tid = threadIdx.x;
    int base = blk * 1024 + tid * 4;
    int v[4]; int tsum = 0;
#pragma unroll
    for (int k = 0; k < 4; ++k) { int idx = base + k; v[k] = (idx < TOT_N) ? deg[idx] : 0; tsum += v[k]; }
    sc[tid] = tsum; __syncthreads();
    for (int d = 1; d < 256; d <<= 1) {
        int t = (tid >= d) ? sc[tid - d] : 0;
        __syncthreads();
        sc[tid] += t;
        __syncthreads();
    }
    int run = coff[blk] + sc[tid] - tsum;
#pragma unroll
    for (int k = 0; k < 4; ++k) { int idx = base + k; if (idx < TOT_N) cur[idx] = run; run += v[k]; }
}

__global__ __launch_bounds__(256)
void edge_pos(const int* __restrict__ src, const int* __restrict__ dst,
              int* __restrict__ cur, int* __restrict__ eidx, int off, int E)
{
    int i = blockIdx.x * 256 + threadIdx.x;
    if (i < E) {
        int p = atomicAdd(&cur[off + dst[i]], 1);
        eidx[p] = src[i];
    }
}

// ---------------------------------------------------------------------------
// Sorted-batch counting: boundary scan -> starts -> counts. No atomics.
// ---------------------------------------------------------------------------
__global__ __launch_bounds__(256)
void batch_starts(const int* __restrict__ batch, int* __restrict__ start, int N)
{
    int i = blockIdx.x * 256 + threadIdx.x;
    if (i > N) return;
    if (i == N) {
        int b = batch[N - 1];
        for (int g = b + 1; g <= G_; ++g) start[g] = N;
    } else {
        int b = batch[i];
        int bp = (i == 0) ? -1 : batch[i - 1];
        for (int g = bp + 1; g <= b; ++g) start[g] = i;
    }
}

__global__ __launch_bounds__(256)
void starts_to_cnt(const int* __restrict__ start, float* __restrict__ cnt)
{
    int g = blockIdx.x * 256 + threadIdx.x;
    if (g < G_) cnt[g] = (float)(start[g + 1] - start[g]);
}

// ---------------------------------------------------------------------------
// Packed weight prep: out[(ks*8+nb)*512 + l*8 + j] = bf16(W1[k][row]),
// row = nb*16 + (l&15), k = ks*32 + (l>>4)*8 + j.
// ---------------------------------------------------------------------------
__global__ __launch_bounds__(256)
void prep_wpack(const float* __restrict__ S0, int L0,
                const float* __restrict__ S1, int L1,
                const float* __restrict__ S2, const float* __restrict__ S2b,
                unsigned short* __restrict__ out, int K1)
{
    int i = blockIdx.x * 256 + threadIdx.x;
    int total = (K1 / 32) * 8 * 512;
    if (i >= total) return;
    int frag = i >> 9;
    int rem  = i & 511;
    int l = rem >> 3, j = rem & 7;
    int ks = frag >> 3, nb = frag & 7;
    int row = nb * 16 + (l & 15);
    int k = ks * 32 + (l >> 4) * 8 + j;
    float v;
    if (k < L0) v = S0[k * 128 + row];
    else if (k < L0 + L1) v = S1[(k - L0) * 128 + row];
    else {
        int kk = k - L0 - L1;
        v = S2[kk * 128 + row];
        if (S2b) v += S2b[kk * 128 + row];
    }
    out[i] = f2bf(v);
}

// ---------------------------------------------------------------------------
// Gather v3 (bf16 sources): 8-lane uint4 groups -> 8 nodes/wave (16 for D=32).
// fp32 accumulate, bf16 mean out.
// ---------------------------------------------------------------------------
template<int D>
__global__ __launch_bounds__(256)
void gather_mean(const int* __restrict__ deg, const int* __restrict__ cur,
                 const int* __restrict__ eidx, int off,
                 const unsigned short* __restrict__ xs,
                 unsigned short* __restrict__ agg, int N)
{
    constexpr int LPG = D / 8;
    constexpr int NPW = 64 / LPG;
    const int wid   = (blockIdx.x * 256 + threadIdx.x) >> 6;
    const int nwave = (gridDim.x * 256) >> 6;
    const int lane  = threadIdx.x & 63;
    const int sub   = lane / LPG;
    const int col8  = (lane % LPG) * 8;

    for (int n = wid * NPW + sub; n < N; n += nwave * NPW) {
        int e_end = cur[off + n];
        int d     = deg[off + n];
        int e0    = e_end - d;
        float acc[8] = {0.f, 0.f, 0.f, 0.f, 0.f, 0.f, 0.f, 0.f};
        int t = 0;
        for (; t + 2 <= d; t += 2) {
            int s0 = eidx[e0 + t];
            int s1 = eidx[e0 + t + 1];
            uint4 a = *(const uint4*)&xs[(size_t)s0 * D + col8];
            uint4 b = *(const uint4*)&xs[(size_t)s1 * D + col8];
            addbf8(acc, a); addbf8(acc, b);
        }
        if (t < d) {
            int s = eidx[e0 + t];
            uint4 a = *(const uint4*)&xs[(size_t)s * D + col8];
            addbf8(acc, a);
        }
        float inv = 1.0f / fmaxf((float)d, 1.0f);
        uint4 o;
        o.x = (unsigned)f2bf(acc[0] * inv) | ((unsigned)f2bf(acc[1] * inv) << 16);
        o.y = (unsigned)f2bf(acc[2] * inv) | ((unsigned)f2bf(acc[3] * inv) << 16);
        o.z = (unsigned)f2bf(acc[4] * inv) | ((unsigned)f2bf(acc[5] * inv) << 16);
        o.w = (unsigned)f2bf(acc[6] * inv) | ((unsigned)f2bf(acc[7] * inv) << 16);
        *(uint4*)&agg[(size_t)n * D + col8] = o;
    }
}

// ---------------------------------------------------------------------------
// MFMA node kernel, register-resident weights, all-bf16 A sources.
// Block = 256 thr (4 waves), one 64-node tile. Wave w owns cols [w*32,w*32+32).
// Pooling: 16-row same-graph fast path via shfl_xor.
// ---------------------------------------------------------------------------
template<int DSa, int DD, bool HAS2, int ASTR, int K1, int MINW>
__global__ __launch_bounds__(256, MINW)
void sage_mfma(const unsigned short* __restrict__ agg1,
               const unsigned short* __restrict__ agg2,
               const unsigned short* __restrict__ xd,
               const unsigned short* __restrict__ W1P,
               const float* __restrict__ bl, const float* __restrict__ bl2,
               const unsigned short* __restrict__ nWP,
               const float* __restrict__ nbp,
               const int* __restrict__ batch,
               float* __restrict__ pool_sum, int N)
{
    constexpr int KST  = K1 / 32;
    constexpr int GCOL = HAS2 ? 2 * DSa : DSa;
    constexpr int XOFF = GCOL;
    constexpr int C8   = K1 / 8;

    __shared__ __align__(16) unsigned short a_sh[64 * ASTR];
    __shared__ __align__(16) unsigned short h_sh[64 * 128];
    __shared__ int batch_sh[64];

    const int tid = threadIdx.x;
    const int w = tid >> 6, l = tid & 63, lg = l >> 4, lr = l & 15;
    const int node0 = blockIdx.x * 64;
    const unsigned swz = (unsigned)(lr & 7) << 4;

    if (tid < 64) batch_sh[tid] = (node0 + tid < N) ? batch[node0 + tid] : -1;

    // ---- stage A tile (bf16 global -> swizzled LDS, uniform 16B chunks) ----
    for (int c = tid; c < 64 * C8; c += 256) {
        int r = c / C8; int col = (c - r * C8) * 8; int node = node0 + r;
        uint4 pk = make_uint4(0u, 0u, 0u, 0u);
        if (node < N) {
            const unsigned short* sp;
            if (col < DSa)                    sp = &agg1[(size_t)node * DSa + col];
            else if (HAS2 && col < 2 * DSa)   sp = &agg2[(size_t)node * DSa + (col - DSa)];
            else                              sp = &xd[(size_t)node * DD + (col - XOFF)];
            pk = *(const uint4*)sp;
        }
        unsigned byte = ((unsigned)(r * ASTR + col) * 2u) ^ ((unsigned)(r & 7) << 4);
        *(uint4*)((char*)a_sh + byte) = pk;
    }

    // ---- stage-1 weights -> registers (coalesced 1KB per fragment) ----
    s16x8 w1[2][KST];
#pragma unroll
    for (int j = 0; j < 2; ++j)
#pragma unroll
        for (int ks = 0; ks < KST; ++ks)
            w1[j][ks] = *(const s16x8*)&W1P[(unsigned)(ks * 8 + (w * 2 + j)) * 512 + (unsigned)l * 8];

    float b1[2];
#pragma unroll
    for (int j = 0; j < 2; ++j) {
        int col = (w * 2 + j) * 16 + lr;
        float b = bl[col];
        if constexpr (HAS2) b += bl2[col];
        b1[j] = b;
    }

    __syncthreads();

    // ---- stage 1: h = A @ W1 ----
    f32x4 acc[4][2];
#pragma unroll
    for (int rf = 0; rf < 4; ++rf)
#pragma unroll
        for (int j = 0; j < 2; ++j) acc[rf][j] = (f32x4){0.f, 0.f, 0.f, 0.f};

#pragma unroll
    for (int ks = 0; ks < KST; ++ks) {
        s16x8 af[4];
#pragma unroll
        for (int rf = 0; rf < 4; ++rf)
            af[rf] = *(const s16x8*)((const char*)a_sh +
                        (((unsigned)((rf * 16 + lr) * ASTR + ks * 32 + lg * 8) * 2u) ^ swz));
#pragma unroll
        for (int rf = 0; rf < 4; ++rf)
#pragma unroll
            for (int j = 0; j < 2; ++j)
                acc[rf][j] = __builtin_amdgcn_mfma_f32_16x16x32_bf16(af[rf], w1[j][ks], acc[rf][j], 0, 0, 0);
    }

    // ---- bias + relu -> bf16 h in LDS ----
#pragma unroll
    for (int rf = 0; rf < 4; ++rf)
#pragma unroll
        for (int j = 0; j < 2; ++j) {
            int col = (w * 2 + j) * 16 + lr;
#pragma unroll
            for (int rg = 0; rg < 4; ++rg) {
                float hv = fmaxf(acc[rf][j][rg] + b1[j], 0.0f);
                int row = rf * 16 + lg * 4 + rg;
                unsigned byte = ((unsigned)(row * 128 + col) * 2u) ^ ((unsigned)(row & 7) << 4);
                *(unsigned short*)((char*)h_sh + byte) = f2bf(hv);
            }
        }

    // ---- stage-2 weights -> registers ----
    s16x8 w2[2][4];
#pragma unroll
    for (int j = 0; j < 2; ++j)
#pragma unroll
        for (int ks = 0; ks < 4; ++ks)
            w2[j][ks] = *(const s16x8*)&nWP[(unsigned)(ks * 8 + (w * 2 + j)) * 512 + (unsigned)l * 8];

    float nbv[2];
#pragma unroll
    for (int j = 0; j < 2; ++j) nbv[j] = nbp[(w * 2 + j) * 16 + lr];

    __syncthreads();

    // ---- stage 2: z = h @ nW ----
    f32x4 acc2[4][2];
#pragma unroll
    for (int rf = 0; rf < 4; ++rf)
#pragma unroll
        for (int j = 0; j < 2; ++j) acc2[rf][j] = (f32x4){0.f, 0.f, 0.f, 0.f};

#pragma unroll
    for (int ks = 0; ks < 4; ++ks) {
        s16x8 hf[4];
#pragma unroll
        for (int rf = 0; rf < 4; ++rf)
            hf[rf] = *(const s16x8*)((const char*)h_sh +
                        (((unsigned)((rf * 16 + lr) * 128 + ks * 32 + lg * 8) * 2u) ^ swz));
#pragma unroll
        for (int rf = 0; rf < 4; ++rf)
#pragma unroll
            for (int j = 0; j < 2; ++j)
                acc2[rf][j] = __builtin_amdgcn_mfma_f32_16x16x32_bf16(hf[rf], w2[j][ks], acc2[rf][j], 0, 0, 0);
    }

    // ---- pooling ----
#pragma unroll
    for (int rf = 0; rf < 4; ++rf) {
        int gf = batch_sh[rf * 16];
        int gl = batch_sh[rf * 16 + 15];
        if (gf == gl && gf >= 0) {
#pragma unroll
            for (int j = 0; j < 2; ++j) {
                float s = acc2[rf][j][0] + acc2[rf][j][1] + acc2[rf][j][2] + acc2[rf][j][3]
                        + 4.0f * nbv[j];
                s += __shfl_xor(s, 16);
                s += __shfl_xor(s, 32);
                if (lg == 0)
                    atomicAdd(&pool_sum[gf * 128 + (w * 2 + j) * 16 + lr], s);
            }
        } else {
            int rbase = rf * 16 + lg * 4;
            int bt[4];
#pragma unroll
            for (int rg = 0; rg < 4; ++rg) bt[rg] = batch_sh[rbase + rg];
#pragma unroll
            for (int j = 0; j < 2; ++j) {
                int col = (w * 2 + j) * 16 + lr;
                float run = acc2[rf][j][0] + nbv[j];
                int cb = bt[0];
#pragma unroll
                for (int rg = 1; rg < 4; ++rg) {
                    float z = acc2[rf][j][rg] + nbv[j];
                    if (bt[rg] == cb) run += z;
                    else {
                        if (cb >= 0) atomicAdd(&pool_sum[cb * 128 + col], run);
                        cb = bt[rg]; run = z;
                    }
                }
                if (cb >= 0) atomicAdd(&pool_sum[cb * 128 + col], run);
            }
        }
    }
}

// ---------------------------------------------------------------------------
__global__ __launch_bounds__(64)
void final_kernel(const float* __restrict__ pool_sum, const float* __restrict__ pool_cnt,
                  const float* __restrict__ gW, const float* __restrict__ gb,
                  float* __restrict__ out)
{
    __shared__ float p_sh[5 * HID];
    int g = blockIdx.x, tid = threadIdx.x;
    for (int i = tid; i < 5 * HID; i += 64) {
        int t  = i >> 7;
        int jj = i & 127;
        float c = fmaxf(pool_cnt[t * G_ + g], 1.0f);
        p_sh[i] = pool_sum[((size_t)t * G_ + g) * HID + jj] / c;
    }
    __syncthreads();
    float acc = gb[tid];
#pragma unroll 8
    for (int k = 0; k < 5 * HID; ++k)
        acc += p_sh[k] * gW[k * 64 + tid];
    out[g * 64 + tid] = acc;
}

// ---------------------------------------------------------------------------
extern "C" void kernel_launch(void* const* d_in, const int* in_sizes, int n_in,
                              void* d_out, int out_size, void* d_ws, size_t ws_size,
                              hipStream_t stream)
{
    const float* x_value       = (const float*)d_in[0];
    const float* x_typ         = (const float*)d_in[1];
    const float* x_size_       = (const float*)d_in[2];
    const float* x_attribute   = (const float*)d_in[3];
    const float* x_instruction = (const float*)d_in[4];
    const float* Wl_vt = (const float*)d_in[5];
    const float* bl_vt = (const float*)d_in[6];
    const float* Wr_vt = (const float*)d_in[7];
    const float* Wl_iv = (const float*)d_in[8];
    const float* bl_iv = (const float*)d_in[9];
    const float* Wr_iv = (const float*)d_in[10];
    const float* Wl_vi = (const float*)d_in[11];
    const float* bl_vi = (const float*)d_in[12];
    const float* Wr_vi = (const float*)d_in[13];
    const float* Wl_va = (const float*)d_in[14];
    const float* bl_va = (const float*)d_in[15];
    const float* Wr_va = (const float*)d_in[16];
    const float* Wl_ts = (const float*)d_in[17];
    const float* bl_ts = (const float*)d_in[18];
    const float* Wr_ts = (const float*)d_in[19];
    const float* Wl_ii = (const float*)d_in[20];
    const float* bl_ii = (const float*)d_in[21];
    const float* Wr_ii = (const float*)d_in[22];
    const float* nW_typ         = (const float*)d_in[23];
    const float* nb_typ         = (const float*)d_in[24];
    const float* nW_value       = (const float*)d_in[25];
    const float* nb_value       = (const float*)d_in[26];
    const float* nW_instruction = (const float*)d_in[27];
    const float* nb_instruction = (const float*)d_in[28];
    const float* nW_attribute   = (const float*)d_in[29];
    const float* nb_attribute   = (const float*)d_in[30];
    const float* nW_size        = (const float*)d_in[31];
    const float* nb_size        = (const float*)d_in[32];
    const float* gW = (const float*)d_in[33];
    const float* gb = (const float*)d_in[34];
    const int* src_vt = (const int*)d_in[35];
    const int* dst_vt = (const int*)d_in[36];
    const int* src_iv = (const int*)d_in[37];
    const int* dst_iv = (const int*)d_in[38];
    const int* src_vi = (const int*)d_in[39];
    const int* dst_vi = (const int*)d_in[40];
    const int* src_va = (const int*)d_in[41];
    const int* dst_va = (const int*)d_in[42];
    const int* src_ts = (const int*)d_in[43];
    const int* dst_ts = (const int*)d_in[44];
    const int* src_ii = (const int*)d_in[45];
    const int* dst_ii = (const int*)d_in[46];
    const int* batch_typ         = (const int*)d_in[47];
    const int* batch_value       = (const int*)d_in[48];
    const int* batch_instruction = (const int*)d_in[49];
    const int* batch_attribute   = (const int*)d_in[50];
    const int* batch_size        = (const int*)d_in[51];

    // ---- workspace layout ----
    int* deg = (int*)d_ws;                                   // TOT_N (zeroed)
    float* pool_sum = (float*)(deg + TOT_N);                 // 5*G*HID (zeroed)
    float* pool_cnt = pool_sum + (size_t)5 * G_ * HID;       // 5*G (zeroed)
    size_t zero_bytes = (size_t)TOT_N * 4 + ((size_t)5 * G_ * HID + 5 * G_) * 4;

    int* cur    = (int*)(pool_cnt + 5 * G_);                 // TOT_N
    int* csum   = cur + TOT_N;                               // NCH
    int* coff   = csum + NCH;                                // NCH
    int* eidx   = coff + NCH;                                // TOT_E
    int* starts = eidx + TOT_E;                              // G_+1 (reused per type)
    // bf16 feature tables
    unsigned short* xb = (unsigned short*)(((uintptr_t)(starts + G_ + 1) + 63) & ~(uintptr_t)63);
    size_t xo = 0;
    unsigned short* xb_value = xb + xo; xo += (size_t)NVv * 64;
    unsigned short* xb_typ   = xb + xo; xo += (size_t)NTv * 32;
    unsigned short* xb_instr = xb + xo; xo += (size_t)NIv * 64;
    unsigned short* xb_attr  = xb + xo; xo += (size_t)NAv * 32;
    unsigned short* xb_size  = xb + xo; xo += (size_t)NSv * 32;
    // bf16 agg buffers
    unsigned short* ab = xb + xo;
    size_t ao = 0;
    unsigned short* agg_vt = ab + ao; ao += (size_t)NTv * 64;
    unsigned short* agg_iv = ab + ao; ao += (size_t)NVv * 64;
    unsigned short* agg_vi = ab + ao; ao += (size_t)NIv * 64;
    unsigned short* agg_va = ab + ao; ao += (size_t)NAv * 64;
    unsigned short* agg_ts = ab + ao; ao += (size_t)NSv * 32;
    unsigned short* agg_ii = ab + ao; ao += (size_t)NIv * 64;
    unsigned short* wt = (unsigned short*)(((uintptr_t)(ab + ao) + 63) & ~(uintptr_t)63);
    size_t wo = 0;
    unsigned short* w1p_vt = wt + wo; wo += 128 * 96;
    unsigned short* w1p_iv = wt + wo; wo += 128 * 128;
    unsigned short* w1p_vi = wt + wo; wo += 128 * 192;
    unsigned short* w1p_va = wt + wo; wo += 128 * 96;
    unsigned short* w1p_ts = wt + wo; wo += 128 * 64;
    unsigned short* nwp_t  = wt + wo; wo += 128 * 128;
    unsigned short* nwp_v  = wt + wo; wo += 128 * 128;
    unsigned short* nwp_i  = wt + wo; wo += 128 * 128;
    unsigned short* nwp_a  = wt + wo; wo += 128 * 128;
    unsigned short* nwp_s  = wt + wo; wo += 128 * 128;

    hipMemsetAsync(d_ws, 0, zero_bytes, stream);

    // bf16 feature tables
    conv_bf16<<<((NVv * 64 / 8) + 255) / 256, 256, 0, stream>>>(x_value,       xb_value, NVv * 64 / 8);
    conv_bf16<<<((NTv * 32 / 8) + 255) / 256, 256, 0, stream>>>(x_typ,         xb_typ,   NTv * 32 / 8);
    conv_bf16<<<((NIv * 64 / 8) + 255) / 256, 256, 0, stream>>>(x_instruction, xb_instr, NIv * 64 / 8);
    conv_bf16<<<((NAv * 32 / 8) + 255) / 256, 256, 0, stream>>>(x_attribute,   xb_attr,  NAv * 32 / 8);
    conv_bf16<<<((NSv * 32 / 8) + 255) / 256, 256, 0, stream>>>(x_size_,       xb_size,  NSv * 32 / 8);

    // packed weight prep (tiny)
    prep_wpack<<<(128 *  96 + 255) / 256, 256, 0, stream>>>(Wl_vt, 64, nullptr, 0, Wr_vt, nullptr, w1p_vt,  96);
    prep_wpack<<<(128 * 128 + 255) / 256, 256, 0, stream>>>(Wl_iv, 64, nullptr, 0, Wr_iv, nullptr, w1p_iv, 128);
    prep_wpack<<<(128 * 192 + 255) / 256, 256, 0, stream>>>(Wl_vi, 64, Wl_ii, 64, Wr_vi, Wr_ii,   w1p_vi, 192);
    prep_wpack<<<(128 *  96 + 255) / 256, 256, 0, stream>>>(Wl_va, 64, nullptr, 0, Wr_va, nullptr, w1p_va,  96);
    prep_wpack<<<(128 *  64 + 255) / 256, 256, 0, stream>>>(Wl_ts, 32, nullptr, 0, Wr_ts, nullptr, w1p_ts,  64);
    prep_wpack<<<(128 * 128 + 255) / 256, 256, 0, stream>>>(nW_typ,         128, nullptr, 0, nullptr, nullptr, nwp_t, 128);
    prep_wpack<<<(128 * 128 + 255) / 256, 256, 0, stream>>>(nW_value,       128, nullptr, 0, nullptr, nullptr, nwp_v, 128);
    prep_wpack<<<(128 * 128 + 255) / 256, 256, 0, stream>>>(nW_instruction, 128, nullptr, 0, nullptr, nullptr, nwp_i, 128);
    prep_wpack<<<(128 * 128 + 255) / 256, 256, 0, stream>>>(nW_attribute,   128, nullptr, 0, nullptr, nullptr, nwp_a, 128);
    prep_wpack<<<(128 * 128 + 255) / 256, 256, 0, stream>>>(nW_size,        128, nullptr, 0, nullptr, nullptr, nwp_s, 128);

    // CSR build
    edge_hist<<<(EVTv + 255) / 256, 256, 0, stream>>>(dst_vt, deg, OFF_VT, EVTv);
    edge_hist<<<(EIVv + 255) / 256, 256, 0, stream>>>(dst_iv, deg, OFF_IV, EIVv);
    edge_hist<<<(EVIv + 255) / 256, 256, 0, stream>>>(dst_vi, deg, OFF_VI, EVIv);
    edge_hist<<<(EVAv + 255) / 256, 256, 0, stream>>>(dst_va, deg, OFF_VA, EVAv);
    edge_hist<<<(ETSv + 255) / 256, 256, 0, stream>>>(dst_ts, deg, OFF_TS, ETSv);
    edge_hist<<<(EIIv + 255) / 256, 256, 0, stream>>>(dst_ii, deg, OFF_II, EIIv);

    scan_chunk_sum<<<NCH, 256, 0, stream>>>(deg, csum);
    scan_offsets<<<1, 256, 0, stream>>>(csum, coff);
    scan_write<<<NCH, 256, 0, stream>>>(deg, coff, cur);

    edge_pos<<<(EVTv + 255) / 256, 256, 0, stream>>>(src_vt, dst_vt, cur, eidx, OFF_VT, EVTv);
    edge_pos<<<(EIVv + 255) / 256, 256, 0, stream>>>(src_iv, dst_iv, cur, eidx, OFF_IV, EIVv);
    edge_pos<<<(EVIv + 255) / 256, 256, 0, stream>>>(src_vi, dst_vi, cur, eidx, OFF_VI, EVIv);
    edge_pos<<<(EVAv + 255) / 256, 256, 0, stream>>>(src_va, dst_va, cur, eidx, OFF_VA, EVAv);
    edge_pos<<<(ETSv + 255) / 256, 256, 0, stream>>>(src_ts, dst_ts, cur, eidx, OFF_TS, ETSv);
    edge_pos<<<(EIIv + 255) / 256, 256, 0, stream>>>(src_ii, dst_ii, cur, eidx, OFF_II, EIIv);

    // sorted-batch counts (no atomics)
    batch_starts<<<(NTv + 1 + 255) / 256, 256, 0, stream>>>(batch_typ, starts, NTv);
    starts_to_cnt<<<(G_ + 255) / 256, 256, 0, stream>>>(starts, pool_cnt + 0 * G_);
    batch_starts<<<(NVv + 1 + 255) / 256, 256, 0, stream>>>(batch_value, starts, NVv);
    starts_to_cnt<<<(G_ + 255) / 256, 256, 0, stream>>>(starts, pool_cnt + 1 * G_);
    batch_starts<<<(NIv + 1 + 255) / 256, 256, 0, stream>>>(batch_instruction, starts, NIv);
    starts_to_cnt<<<(G_ + 255) / 256, 256, 0, stream>>>(starts, pool_cnt + 2 * G_);
    batch_starts<<<(NAv + 1 + 255) / 256, 256, 0, stream>>>(batch_attribute, starts, NAv);
    starts_to_cnt<<<(G_ + 255) / 256, 256, 0, stream>>>(starts, pool_cnt + 3 * G_);
    batch_starts<<<(NSv + 1 + 255) / 256, 256, 0, stream>>>(batch_size, starts, NSv);
    starts_to_cnt<<<(G_ + 255) / 256, 256, 0, stream>>>(starts, pool_cnt + 4 * G_);

    // gathers (bf16 sources, 8-lane groups)
    auto gblk = [](int N, int npw) {
        long waves = ((long)N + npw - 1) / npw;
        long blocks = (waves + 3) / 4;
        return (int)(blocks > 2048 ? 2048 : blocks);
    };
    gather_mean<64><<<gblk(NTv, 8),  256, 0, stream>>>(deg, cur, eidx, OFF_VT, xb_value, agg_vt, NTv);
    gather_mean<64><<<gblk(NVv, 8),  256, 0, stream>>>(deg, cur, eidx, OFF_IV, xb_instr, agg_iv, NVv);
    gather_mean<64><<<gblk(NIv, 8),  256, 0, stream>>>(deg, cur, eidx, OFF_VI, xb_value, agg_vi, NIv);
    gather_mean<64><<<gblk(NAv, 8),  256, 0, stream>>>(deg, cur, eidx, OFF_VA, xb_value, agg_va, NAv);
    gather_mean<32><<<gblk(NSv, 16), 256, 0, stream>>>(deg, cur, eidx, OFF_TS, xb_typ,   agg_ts, NSv);
    gather_mean<64><<<gblk(NIv, 8),  256, 0, stream>>>(deg, cur, eidx, OFF_II, xb_instr, agg_ii, NIv);

    // MFMA node kernels (one 64-node tile per block)
    sage_mfma<64, 32, false, 128,  96, 4><<<(NTv + 63) / 64, 256, 0, stream>>>(
        agg_vt, nullptr, xb_typ, w1p_vt, bl_vt, nullptr,
        nwp_t, nb_typ, batch_typ, pool_sum + (size_t)0 * G_ * HID, NTv);
    sage_mfma<64, 64, false, 128, 128, 4><<<(NVv + 63) / 64, 256, 0, stream>>>(
        agg_iv, nullptr, xb_value, w1p_iv, bl_iv, nullptr,
        nwp_v, nb_value, batch_value, pool_sum + (size_t)1 * G_ * HID, NVv);
    sage_mfma<64, 64, true,  192, 192, 3><<<(NIv + 63) / 64, 256, 0, stream>>>(
        agg_vi, agg_ii, xb_instr, w1p_vi, bl_vi, bl_ii,
        nwp_i, nb_instruction, batch_instruction, pool_sum + (size_t)2 * G_ * HID, NIv);
    sage_mfma<64, 32, false, 128,  96, 4><<<(NAv + 63) / 64, 256, 0, stream>>>(
        agg_va, nullptr, xb_attr, w1p_va, bl_va, nullptr,
        nwp_a, nb_attribute, batch_attribute, pool_sum + (size_t)3 * G_ * HID, NAv);
    sage_mfma<32, 32, false,  64,  64, 4><<<(NSv + 63) / 64, 256, 0, stream>>>(
        agg_ts, nullptr, xb_size, w1p_ts, bl_ts, nullptr,
        nwp_s, nb_size, batch_size, pool_sum + (size_t)4 * G_ * HID, NSv);

    final_kernel<<<G_, 64, 0, stream>>>(pool_sum, pool_cnt, gW, gb, (float*)d_out);
}

// Round 9
// 913.608 us; speedup vs baseline: 2.9017x; 1.1554x over previous
//
#include <hip/hip_runtime.h>

namespace {
constexpr int G_  = 2048;
constexpr int HID = 128;
constexpr int NVv = 500000, NIv = 300000, NTv = 50000, NAv = 50000, NSv = 10000;
constexpr int EVTv = 500000, EIVv = 1500000, EVIv = 1500000, EVAv = 500000, ETSv = 50000, EIIv = 600000;
// concatenated per-(edge-type,dst-node) CSR space
constexpr int OFF_VT = 0;
constexpr int OFF_IV = OFF_VT + NTv;
constexpr int OFF_VI = OFF_IV + NVv;
constexpr int OFF_VA = OFF_VI + NIv;
constexpr int OFF_TS = OFF_VA + NAv;
constexpr int OFF_II = OFF_TS + NSv;
constexpr int TOT_N  = OFF_II + NIv;          // 1210000
constexpr int TOT_E  = EVTv + EIVv + EVIv + EVAv + ETSv + EIIv;  // 4650000
constexpr int NCH    = (TOT_N + 1023) / 1024; // 1182
}

typedef short s16x8 __attribute__((ext_vector_type(8)));
typedef float f32x4 __attribute__((ext_vector_type(4)));

__device__ __forceinline__ float4 ld4(const float* p) { return *(const float4*)p; }

__device__ __forceinline__ unsigned short f2bf(float x) {
    unsigned u = __float_as_uint(x);
    u += 0x7fffu + ((u >> 16) & 1u);
    return (unsigned short)(u >> 16);
}

__device__ __forceinline__ void addbf8(float (&acc)[8], uint4 v) {
    acc[0] += __uint_as_float((v.x & 0xFFFFu) << 16);
    acc[1] += __uint_as_float(v.x & 0xFFFF0000u);
    acc[2] += __uint_as_float((v.y & 0xFFFFu) << 16);
    acc[3] += __uint_as_float(v.y & 0xFFFF0000u);
    acc[4] += __uint_as_float((v.z & 0xFFFFu) << 16);
    acc[5] += __uint_as_float(v.z & 0xFFFF0000u);
    acc[6] += __uint_as_float((v.w & 0xFFFFu) << 16);
    acc[7] += __uint_as_float(v.w & 0xFFFF0000u);
}

// ---------------------------------------------------------------------------
// fp32 -> bf16 table conversion (8 elems/thread)
// ---------------------------------------------------------------------------
__global__ __launch_bounds__(256)
void conv_bf16(const float* __restrict__ src, unsigned short* __restrict__ dst, int n8)
{
    int i = blockIdx.x * 256 + threadIdx.x;
    if (i >= n8) return;
    float4 a = ld4(&src[(size_t)i * 8]);
    float4 b = ld4(&src[(size_t)i * 8 + 4]);
    uint4 o;
    o.x = (unsigned)f2bf(a.x) | ((unsigned)f2bf(a.y) << 16);
    o.y = (unsigned)f2bf(a.z) | ((unsigned)f2bf(a.w) << 16);
    o.z = (unsigned)f2bf(b.x) | ((unsigned)f2bf(b.y) << 16);
    o.w = (unsigned)f2bf(b.z) | ((unsigned)f2bf(b.w) << 16);
    *(uint4*)&dst[(size_t)i * 8] = o;
}

// ---------------------------------------------------------------------------
// CSR build — XCD-localized: block r = blockIdx%8 handles dst range
// [r*N/8, (r+1)*N/8). All writes/atomics for a deg/cur/eidx slice come from
// one XCD -> full-line L2 write coalescing instead of partial-line HBM RMW.
// ---------------------------------------------------------------------------
__global__ __launch_bounds__(256)
void edge_hist(const int* __restrict__ dst, int* __restrict__ deg,
               int off, int E, int N)
{
    int r     = blockIdx.x & 7;
    int chunk = blockIdx.x >> 3;
    int rlo = (int)((long)r * N / 8);
    int rhi = (int)((long)(r + 1) * N / 8);
    int base = chunk * 2048;
#pragma unroll
    for (int k = 0; k < 8; ++k) {
        int i = base + k * 256 + threadIdx.x;
        if (i < E) {
            int d = dst[i];
            if (d >= rlo && d < rhi) atomicAdd(&deg[off + d], 1);
        }
    }
}

__global__ __launch_bounds__(256)
void edge_pos(const int* __restrict__ src, const int* __restrict__ dst,
              int* __restrict__ cur, int* __restrict__ eidx,
              int off, int E, int N)
{
    int r     = blockIdx.x & 7;
    int chunk = blockIdx.x >> 3;
    int rlo = (int)((long)r * N / 8);
    int rhi = (int)((long)(r + 1) * N / 8);
    int base = chunk * 2048;
#pragma unroll
    for (int k = 0; k < 8; ++k) {
        int i = base + k * 256 + threadIdx.x;
        if (i < E) {
            int d = dst[i];
            if (d >= rlo && d < rhi) {
                int p = atomicAdd(&cur[off + d], 1);
                eidx[p] = src[i];
            }
        }
    }
}

__global__ __launch_bounds__(256)
void scan_chunk_sum(const int* __restrict__ deg, int* __restrict__ csum)
{
    __shared__ int sc[256];
    int blk = blockIdx.x, tid = threadIdx.x;
    int base = blk * 1024 + tid * 4;
    int s = 0;
#pragma unroll
    for (int k = 0; k < 4; ++k) { int idx = base + k; if (idx < TOT_N) s += deg[idx]; }
    sc[tid] = s; __syncthreads();
    for (int d = 128; d > 0; d >>= 1) {
        if (tid < d) sc[tid] += sc[tid + d];
        __syncthreads();
    }
    if (tid == 0) csum[blk] = sc[0];
}

__global__ __launch_bounds__(256)
void scan_offsets(const int* __restrict__ csum, int* __restrict__ coff)
{
    __shared__ int sc[256];
    int tid = threadIdx.x;
    int s[5]; int tsum = 0;
#pragma unroll
    for (int k = 0; k < 5; ++k) { int idx = tid * 5 + k; s[k] = (idx < NCH) ? csum[idx] : 0; tsum += s[k]; }
    sc[tid] = tsum; __syncthreads();
    for (int d = 1; d < 256; d <<= 1) {
        int v = (tid >= d) ? sc[tid - d] : 0;
        __syncthreads();
        sc[tid] += v;
        __syncthreads();
    }
    int run = sc[tid] - tsum;   // exclusive
#pragma unroll
    for (int k = 0; k < 5; ++k) { int idx = tid * 5 + k; if (idx < NCH) coff[idx] = run; run += s[k]; }
}

__global__ __launch_bounds__(256)
void scan_write(const int* __restrict__ deg, const int* __restrict__ coff, int* __restrict__ cur)
{
    __shared__ int sc[256];
    int blk = blockIdx.x, tid = threadIdx.x;
    int base = blk * 1024 + tid * 4;
    int v[4]; int tsum = 0;
#pragma unroll
    for (int k = 0; k < 4; ++k) { int idx = base + k; v[k] = (idx < TOT_N) ? deg[idx] : 0; tsum += v[k]; }
    sc[tid] = tsum; __syncthreads();
    for (int d = 1; d < 256; d <<= 1) {
        int t = (tid >= d) ? sc[tid - d] : 0;
        __syncthreads();
        sc[tid] += t;
        __syncthreads();
    }
    int run = coff[blk] + sc[tid] - tsum;
#pragma unroll
    for (int k = 0; k < 4; ++k) { int idx = base + k; if (idx < TOT_N) cur[idx] = run; run += v[k]; }
}

// ---------------------------------------------------------------------------
// Sorted-batch counting: boundary scan -> starts -> counts. No atomics.
// ---------------------------------------------------------------------------
__global__ __launch_bounds__(256)
void batch_starts(const int* __restrict__ batch, int* __restrict__ start, int N)
{
    int i = blockIdx.x * 256 + threadIdx.x;
    if (i > N) return;
    if (i == N) {
        int b = batch[N - 1];
        for (int g = b + 1; g <= G_; ++g) start[g] = N;
    } else {
        int b = batch[i];
        int bp = (i == 0) ? -1 : batch[i - 1];
        for (int g = bp + 1; g <= b; ++g) start[g] = i;
    }
}

__global__ __launch_bounds__(256)
void starts_to_cnt(const int* __restrict__ start, float* __restrict__ cnt)
{
    int g = blockIdx.x * 256 + threadIdx.x;
    if (g < G_) cnt[g] = (float)(start[g + 1] - start[g]);
}

// ---------------------------------------------------------------------------
// Packed weight prep: out[(ks*8+nb)*512 + l*8 + j] = bf16(W1[k][row]),
// row = nb*16 + (l&15), k = ks*32 + (l>>4)*8 + j.
// ---------------------------------------------------------------------------
__global__ __launch_bounds__(256)
void prep_wpack(const float* __restrict__ S0, int L0,
                const float* __restrict__ S1, int L1,
                const float* __restrict__ S2, const float* __restrict__ S2b,
                unsigned short* __restrict__ out, int K1)
{
    int i = blockIdx.x * 256 + threadIdx.x;
    int total = (K1 / 32) * 8 * 512;
    if (i >= total) return;
    int frag = i >> 9;
    int rem  = i & 511;
    int l = rem >> 3, j = rem & 7;
    int ks = frag >> 3, nb = frag & 7;
    int row = nb * 16 + (l & 15);
    int k = ks * 32 + (l >> 4) * 8 + j;
    float v;
    if (k < L0) v = S0[k * 128 + row];
    else if (k < L0 + L1) v = S1[(k - L0) * 128 + row];
    else {
        int kk = k - L0 - L1;
        v = S2[kk * 128 + row];
        if (S2b) v += S2b[kk * 128 + row];
    }
    out[i] = f2bf(v);
}

// ---------------------------------------------------------------------------
// Fused gather + MFMA node kernel. Block = 256 thr (4 waves), one 64-node
// tile. Phase 1: CSR mean-gather straight into the swizzled bf16 A-tile
// (8 lanes per node); x_dst staged alongside. Phase 2/3: two MFMA stages with
// register-resident packed weights; pooled atomics with 16-row fast path.
// ---------------------------------------------------------------------------
template<int DSa, int DD, bool HAS2, int ASTR, int K1, int MINW>
__global__ __launch_bounds__(256, MINW)
void sage_mfma(const int* __restrict__ deg, const int* __restrict__ cur,
               const int* __restrict__ eidx, int off1, int off2,
               const unsigned short* __restrict__ xs1,
               const unsigned short* __restrict__ xs2,
               const unsigned short* __restrict__ xd,
               const unsigned short* __restrict__ W1P,
               const float* __restrict__ bl, const float* __restrict__ bl2,
               const unsigned short* __restrict__ nWP,
               const float* __restrict__ nbp,
               const int* __restrict__ batch,
               float* __restrict__ pool_sum, int N)
{
    constexpr int KST  = K1 / 32;
    constexpr int GCOL = HAS2 ? 2 * DSa : DSa;
    constexpr int XOFF = GCOL;
    constexpr int C8d  = DD / 8;
    constexpr int LPG1 = DSa / 8;        // lanes per gathered node
    constexpr int NPW1 = 64 / LPG1;      // nodes per wave
    constexpr int PASSES = 64 / (4 * NPW1) > 0 ? 64 / (4 * NPW1) : 1;

    __shared__ __align__(16) unsigned short a_sh[64 * ASTR];
    __shared__ __align__(16) unsigned short h_sh[64 * 128];
    __shared__ int batch_sh[64];

    const int tid = threadIdx.x;
    const int w = tid >> 6, l = tid & 63, lg = l >> 4, lr = l & 15;
    const int node0 = blockIdx.x * 64;
    const unsigned swz = (unsigned)(lr & 7) << 4;

    if (tid < 64) batch_sh[tid] = (node0 + tid < N) ? batch[node0 + tid] : -1;

    // ---- stage-1 weights -> registers early (independent of gather) ----
    s16x8 w1[2][KST];
#pragma unroll
    for (int j = 0; j < 2; ++j)
#pragma unroll
        for (int ks = 0; ks < KST; ++ks)
            w1[j][ks] = *(const s16x8*)&W1P[(unsigned)(ks * 8 + (w * 2 + j)) * 512 + (unsigned)l * 8];

    float b1[2];
#pragma unroll
    for (int j = 0; j < 2; ++j) {
        int col = (w * 2 + j) * 16 + lr;
        float b = bl[col];
        if constexpr (HAS2) b += bl2[col];
        b1[j] = b;
    }

    // ---- x_dst staging (bf16 -> swizzled LDS) ----
    for (int c = tid; c < 64 * C8d; c += 256) {
        int r = c / C8d; int col = (c - r * C8d) * 8; int node = node0 + r;
        uint4 pk = make_uint4(0u, 0u, 0u, 0u);
        if (node < N) pk = *(const uint4*)&xd[(size_t)node * DD + col];
        unsigned byte = ((unsigned)(r * ASTR + XOFF + col) * 2u) ^ ((unsigned)(r & 7) << 4);
        *(uint4*)((char*)a_sh + byte) = pk;
    }

    // ---- fused CSR mean gather -> swizzled LDS A-tile ----
    auto gather_rows = [&](int offx, const unsigned short* __restrict__ xsrc, int colbase) {
#pragma unroll
        for (int ps = 0; ps < PASSES; ++ps) {
            int r = ps * (4 * NPW1) + w * NPW1 + (l / LPG1);
            int col8 = (l % LPG1) * 8;
            int node = node0 + r;
            uint4 o = make_uint4(0u, 0u, 0u, 0u);
            if (node < N) {
                int e_end = cur[offx + node];
                int d     = deg[offx + node];
                int e0    = e_end - d;
                float acc[8] = {0.f, 0.f, 0.f, 0.f, 0.f, 0.f, 0.f, 0.f};
                int t = 0;
                for (; t + 2 <= d; t += 2) {
                    int s0 = eidx[e0 + t];
                    int s1 = eidx[e0 + t + 1];
                    addbf8(acc, *(const uint4*)&xsrc[(size_t)s0 * DSa + col8]);
                    addbf8(acc, *(const uint4*)&xsrc[(size_t)s1 * DSa + col8]);
                }
                if (t < d) {
                    int s = eidx[e0 + t];
                    addbf8(acc, *(const uint4*)&xsrc[(size_t)s * DSa + col8]);
                }
                float inv = 1.0f / fmaxf((float)d, 1.0f);
                o.x = (unsigned)f2bf(acc[0] * inv) | ((unsigned)f2bf(acc[1] * inv) << 16);
                o.y = (unsigned)f2bf(acc[2] * inv) | ((unsigned)f2bf(acc[3] * inv) << 16);
                o.z = (unsigned)f2bf(acc[4] * inv) | ((unsigned)f2bf(acc[5] * inv) << 16);
                o.w = (unsigned)f2bf(acc[6] * inv) | ((unsigned)f2bf(acc[7] * inv) << 16);
            }
            unsigned byte = ((unsigned)(r * ASTR + colbase + col8) * 2u) ^ ((unsigned)(r & 7) << 4);
            *(uint4*)((char*)a_sh + byte) = o;
        }
    };
    gather_rows(off1, xs1, 0);
    if constexpr (HAS2) gather_rows(off2, xs2, DSa);

    __syncthreads();

    // ---- stage 1: h = A @ W1 ----
    f32x4 acc[4][2];
#pragma unroll
    for (int rf = 0; rf < 4; ++rf)
#pragma unroll
        for (int j = 0; j < 2; ++j) acc[rf][j] = (f32x4){0.f, 0.f, 0.f, 0.f};

#pragma unroll
    for (int ks = 0; ks < KST; ++ks) {
        s16x8 af[4];
#pragma unroll
        for (int rf = 0; rf < 4; ++rf)
            af[rf] = *(const s16x8*)((const char*)a_sh +
                        (((unsigned)((rf * 16 + lr) * ASTR + ks * 32 + lg * 8) * 2u) ^ swz));
#pragma unroll
        for (int rf = 0; rf < 4; ++rf)
#pragma unroll
            for (int j = 0; j < 2; ++j)
                acc[rf][j] = __builtin_amdgcn_mfma_f32_16x16x32_bf16(af[rf], w1[j][ks], acc[rf][j], 0, 0, 0);
    }

    // ---- bias + relu -> bf16 h in LDS ----
#pragma unroll
    for (int rf = 0; rf < 4; ++rf)
#pragma unroll
        for (int j = 0; j < 2; ++j) {
            int col = (w * 2 + j) * 16 + lr;
#pragma unroll
            for (int rg = 0; rg < 4; ++rg) {
                float hv = fmaxf(acc[rf][j][rg] + b1[j], 0.0f);
                int row = rf * 16 + lg * 4 + rg;
                unsigned byte = ((unsigned)(row * 128 + col) * 2u) ^ ((unsigned)(row & 7) << 4);
                *(unsigned short*)((char*)h_sh + byte) = f2bf(hv);
            }
        }

    // ---- stage-2 weights -> registers ----
    s16x8 w2[2][4];
#pragma unroll
    for (int j = 0; j < 2; ++j)
#pragma unroll
        for (int ks = 0; ks < 4; ++ks)
            w2[j][ks] = *(const s16x8*)&nWP[(unsigned)(ks * 8 + (w * 2 + j)) * 512 + (unsigned)l * 8];

    float nbv[2];
#pragma unroll
    for (int j = 0; j < 2; ++j) nbv[j] = nbp[(w * 2 + j) * 16 + lr];

    __syncthreads();

    // ---- stage 2: z = h @ nW ----
    f32x4 acc2[4][2];
#pragma unroll
    for (int rf = 0; rf < 4; ++rf)
#pragma unroll
        for (int j = 0; j < 2; ++j) acc2[rf][j] = (f32x4){0.f, 0.f, 0.f, 0.f};

#pragma unroll
    for (int ks = 0; ks < 4; ++ks) {
        s16x8 hf[4];
#pragma unroll
        for (int rf = 0; rf < 4; ++rf)
            hf[rf] = *(const s16x8*)((const char*)h_sh +
                        (((unsigned)((rf * 16 + lr) * 128 + ks * 32 + lg * 8) * 2u) ^ swz));
#pragma unroll
        for (int rf = 0; rf < 4; ++rf)
#pragma unroll
            for (int j = 0; j < 2; ++j)
                acc2[rf][j] = __builtin_amdgcn_mfma_f32_16x16x32_bf16(hf[rf], w2[j][ks], acc2[rf][j], 0, 0, 0);
    }

    // ---- pooling ----
#pragma unroll
    for (int rf = 0; rf < 4; ++rf) {
        int gf = batch_sh[rf * 16];
        int gl = batch_sh[rf * 16 + 15];
        if (gf == gl && gf >= 0) {
#pragma unroll
            for (int j = 0; j < 2; ++j) {
                float s = acc2[rf][j][0] + acc2[rf][j][1] + acc2[rf][j][2] + acc2[rf][j][3]
                        + 4.0f * nbv[j];
                s += __shfl_xor(s, 16);
                s += __shfl_xor(s, 32);
                if (lg == 0)
                    atomicAdd(&pool_sum[gf * 128 + (w * 2 + j) * 16 + lr], s);
            }
        } else {
            int rbase = rf * 16 + lg * 4;
            int bt[4];
#pragma unroll
            for (int rg = 0; rg < 4; ++rg) bt[rg] = batch_sh[rbase + rg];
#pragma unroll
            for (int j = 0; j < 2; ++j) {
                int col = (w * 2 + j) * 16 + lr;
                float run = acc2[rf][j][0] + nbv[j];
                int cb = bt[0];
#pragma unroll
                for (int rg = 1; rg < 4; ++rg) {
                    float z = acc2[rf][j][rg] + nbv[j];
                    if (bt[rg] == cb) run += z;
                    else {
                        if (cb >= 0) atomicAdd(&pool_sum[cb * 128 + col], run);
                        cb = bt[rg]; run = z;
                    }
                }
                if (cb >= 0) atomicAdd(&pool_sum[cb * 128 + col], run);
            }
        }
    }
}

// ---------------------------------------------------------------------------
__global__ __launch_bounds__(64)
void final_kernel(const float* __restrict__ pool_sum, const float* __restrict__ pool_cnt,
                  const float* __restrict__ gW, const float* __restrict__ gb,
                  float* __restrict__ out)
{
    __shared__ float p_sh[5 * HID];
    int g = blockIdx.x, tid = threadIdx.x;
    for (int i = tid; i < 5 * HID; i += 64) {
        int t  = i >> 7;
        int jj = i & 127;
        float c = fmaxf(pool_cnt[t * G_ + g], 1.0f);
        p_sh[i] = pool_sum[((size_t)t * G_ + g) * HID + jj] / c;
    }
    __syncthreads();
    float acc = gb[tid];
#pragma unroll 8
    for (int k = 0; k < 5 * HID; ++k)
        acc += p_sh[k] * gW[k * 64 + tid];
    out[g * 64 + tid] = acc;
}

// ---------------------------------------------------------------------------
extern "C" void kernel_launch(void* const* d_in, const int* in_sizes, int n_in,
                              void* d_out, int out_size, void* d_ws, size_t ws_size,
                              hipStream_t stream)
{
    const float* x_value       = (const float*)d_in[0];
    const float* x_typ         = (const float*)d_in[1];
    const float* x_size_       = (const float*)d_in[2];
    const float* x_attribute   = (const float*)d_in[3];
    const float* x_instruction = (const float*)d_in[4];
    const float* Wl_vt = (const float*)d_in[5];
    const float* bl_vt = (const float*)d_in[6];
    const float* Wr_vt = (const float*)d_in[7];
    const float* Wl_iv = (const float*)d_in[8];
    const float* bl_iv = (const float*)d_in[9];
    const float* Wr_iv = (const float*)d_in[10];
    const float* Wl_vi = (const float*)d_in[11];
    const float* bl_vi = (const float*)d_in[12];
    const float* Wr_vi = (const float*)d_in[13];
    const float* Wl_va = (const float*)d_in[14];
    const float* bl_va = (const float*)d_in[15];
    const float* Wr_va = (const float*)d_in[16];
    const float* Wl_ts = (const float*)d_in[17];
    const float* bl_ts = (const float*)d_in[18];
    const float* Wr_ts = (const float*)d_in[19];
    const float* Wl_ii = (const float*)d_in[20];
    const float* bl_ii = (const float*)d_in[21];
    const float* Wr_ii = (const float*)d_in[22];
    const float* nW_typ         = (const float*)d_in[23];
    const float* nb_typ         = (const float*)d_in[24];
    const float* nW_value       = (const float*)d_in[25];
    const float* nb_value       = (const float*)d_in[26];
    const float* nW_instruction = (const float*)d_in[27];
    const float* nb_instruction = (const float*)d_in[28];
    const float* nW_attribute   = (const float*)d_in[29];
    const float* nb_attribute   = (const float*)d_in[30];
    const float* nW_size        = (const float*)d_in[31];
    const float* nb_size        = (const float*)d_in[32];
    const float* gW = (const float*)d_in[33];
    const float* gb = (const float*)d_in[34];
    const int* src_vt = (const int*)d_in[35];
    const int* dst_vt = (const int*)d_in[36];
    const int* src_iv = (const int*)d_in[37];
    const int* dst_iv = (const int*)d_in[38];
    const int* src_vi = (const int*)d_in[39];
    const int* dst_vi = (const int*)d_in[40];
    const int* src_va = (const int*)d_in[41];
    const int* dst_va = (const int*)d_in[42];
    const int* src_ts = (const int*)d_in[43];
    const int* dst_ts = (const int*)d_in[44];
    const int* src_ii = (const int*)d_in[45];
    const int* dst_ii = (const int*)d_in[46];
    const int* batch_typ         = (const int*)d_in[47];
    const int* batch_value       = (const int*)d_in[48];
    const int* batch_instruction = (const int*)d_in[49];
    const int* batch_attribute   = (const int*)d_in[50];
    const int* batch_size        = (const int*)d_in[51];

    // ---- workspace layout ----
    int* deg = (int*)d_ws;                                   // TOT_N (zeroed)
    float* pool_sum = (float*)(deg + TOT_N);                 // 5*G*HID (zeroed)
    float* pool_cnt = pool_sum + (size_t)5 * G_ * HID;       // 5*G (zeroed)
    size_t zero_bytes = (size_t)TOT_N * 4 + ((size_t)5 * G_ * HID + 5 * G_) * 4;

    int* cur    = (int*)(pool_cnt + 5 * G_);                 // TOT_N
    int* csum   = cur + TOT_N;                               // NCH
    int* coff   = csum + NCH;                                // NCH
    int* eidx   = coff + NCH;                                // TOT_E
    int* starts = eidx + TOT_E;                              // G_+1 (reused per type)
    // bf16 feature tables
    unsigned short* xb = (unsigned short*)(((uintptr_t)(starts + G_ + 1) + 63) & ~(uintptr_t)63);
    size_t xo = 0;
    unsigned short* xb_value = xb + xo; xo += (size_t)NVv * 64;
    unsigned short* xb_typ   = xb + xo; xo += (size_t)NTv * 32;
    unsigned short* xb_instr = xb + xo; xo += (size_t)NIv * 64;
    unsigned short* xb_attr  = xb + xo; xo += (size_t)NAv * 32;
    unsigned short* xb_size  = xb + xo; xo += (size_t)NSv * 32;
    unsigned short* wt = (unsigned short*)(((uintptr_t)(xb + xo) + 63) & ~(uintptr_t)63);
    size_t wo = 0;
    unsigned short* w1p_vt = wt + wo; wo += 128 * 96;
    unsigned short* w1p_iv = wt + wo; wo += 128 * 128;
    unsigned short* w1p_vi = wt + wo; wo += 128 * 192;
    unsigned short* w1p_va = wt + wo; wo += 128 * 96;
    unsigned short* w1p_ts = wt + wo; wo += 128 * 64;
    unsigned short* nwp_t  = wt + wo; wo += 128 * 128;
    unsigned short* nwp_v  = wt + wo; wo += 128 * 128;
    unsigned short* nwp_i  = wt + wo; wo += 128 * 128;
    unsigned short* nwp_a  = wt + wo; wo += 128 * 128;
    unsigned short* nwp_s  = wt + wo; wo += 128 * 128;

    hipMemsetAsync(d_ws, 0, zero_bytes, stream);

    // bf16 feature tables
    conv_bf16<<<((NVv * 64 / 8) + 255) / 256, 256, 0, stream>>>(x_value,       xb_value, NVv * 64 / 8);
    conv_bf16<<<((NTv * 32 / 8) + 255) / 256, 256, 0, stream>>>(x_typ,         xb_typ,   NTv * 32 / 8);
    conv_bf16<<<((NIv * 64 / 8) + 255) / 256, 256, 0, stream>>>(x_instruction, xb_instr, NIv * 64 / 8);
    conv_bf16<<<((NAv * 32 / 8) + 255) / 256, 256, 0, stream>>>(x_attribute,   xb_attr,  NAv * 32 / 8);
    conv_bf16<<<((NSv * 32 / 8) + 255) / 256, 256, 0, stream>>>(x_size_,       xb_size,  NSv * 32 / 8);

    // packed weight prep (tiny)
    prep_wpack<<<(128 *  96 + 255) / 256, 256, 0, stream>>>(Wl_vt, 64, nullptr, 0, Wr_vt, nullptr, w1p_vt,  96);
    prep_wpack<<<(128 * 128 + 255) / 256, 256, 0, stream>>>(Wl_iv, 64, nullptr, 0, Wr_iv, nullptr, w1p_iv, 128);
    prep_wpack<<<(128 * 192 + 255) / 256, 256, 0, stream>>>(Wl_vi, 64, Wl_ii, 64, Wr_vi, Wr_ii,   w1p_vi, 192);
    prep_wpack<<<(128 *  96 + 255) / 256, 256, 0, stream>>>(Wl_va, 64, nullptr, 0, Wr_va, nullptr, w1p_va,  96);
    prep_wpack<<<(128 *  64 + 255) / 256, 256, 0, stream>>>(Wl_ts, 32, nullptr, 0, Wr_ts, nullptr, w1p_ts,  64);
    prep_wpack<<<(128 * 128 + 255) / 256, 256, 0, stream>>>(nW_typ,         128, nullptr, 0, nullptr, nullptr, nwp_t, 128);
    prep_wpack<<<(128 * 128 + 255) / 256, 256, 0, stream>>>(nW_value,       128, nullptr, 0, nullptr, nullptr, nwp_v, 128);
    prep_wpack<<<(128 * 128 + 255) / 256, 256, 0, stream>>>(nW_instruction, 128, nullptr, 0, nullptr, nullptr, nwp_i, 128);
    prep_wpack<<<(128 * 128 + 255) / 256, 256, 0, stream>>>(nW_attribute,   128, nullptr, 0, nullptr, nullptr, nwp_a, 128);
    prep_wpack<<<(128 * 128 + 255) / 256, 256, 0, stream>>>(nW_size,        128, nullptr, 0, nullptr, nullptr, nwp_s, 128);

    // CSR build (XCD-localized: grid = chunks*8, block handles dst-range blockIdx%8)
    auto egrid = [](int E) { return ((E + 2047) / 2048) * 8; };
    edge_hist<<<egrid(EVTv), 256, 0, stream>>>(dst_vt, deg, OFF_VT, EVTv, NTv);
    edge_hist<<<egrid(EIVv), 256, 0, stream>>>(dst_iv, deg, OFF_IV, EIVv, NVv);
    edge_hist<<<egrid(EVIv), 256, 0, stream>>>(dst_vi, deg, OFF_VI, EVIv, NIv);
    edge_hist<<<egrid(EVAv), 256, 0, stream>>>(dst_va, deg, OFF_VA, EVAv, NAv);
    edge_hist<<<egrid(ETSv), 256, 0, stream>>>(dst_ts, deg, OFF_TS, ETSv, NSv);
    edge_hist<<<egrid(EIIv), 256, 0, stream>>>(dst_ii, deg, OFF_II, EIIv, NIv);

    scan_chunk_sum<<<NCH, 256, 0, stream>>>(deg, csum);
    scan_offsets<<<1, 256, 0, stream>>>(csum, coff);
    scan_write<<<NCH, 256, 0, stream>>>(deg, coff, cur);

    edge_pos<<<egrid(EVTv), 256, 0, stream>>>(src_vt, dst_vt, cur, eidx, OFF_VT, EVTv, NTv);
    edge_pos<<<egrid(EIVv), 256, 0, stream>>>(src_iv, dst_iv, cur, eidx, OFF_IV, EIVv, NVv);
    edge_pos<<<egrid(EVIv), 256, 0, stream>>>(src_vi, dst_vi, cur, eidx, OFF_VI, EVIv, NIv);
    edge_pos<<<egrid(EVAv), 256, 0, stream>>>(src_va, dst_va, cur, eidx, OFF_VA, EVAv, NAv);
    edge_pos<<<egrid(ETSv), 256, 0, stream>>>(src_ts, dst_ts, cur, eidx, OFF_TS, ETSv, NSv);
    edge_pos<<<egrid(EIIv), 256, 0, stream>>>(src_ii, dst_ii, cur, eidx, OFF_II, EIIv, NIv);

    // sorted-batch counts (no atomics)
    batch_starts<<<(NTv + 1 + 255) / 256, 256, 0, stream>>>(batch_typ, starts, NTv);
    starts_to_cnt<<<(G_ + 255) / 256, 256, 0, stream>>>(starts, pool_cnt + 0 * G_);
    batch_starts<<<(NVv + 1 + 255) / 256, 256, 0, stream>>>(batch_value, starts, NVv);
    starts_to_cnt<<<(G_ + 255) / 256, 256, 0, stream>>>(starts, pool_cnt + 1 * G_);
    batch_starts<<<(NIv + 1 + 255) / 256, 256, 0, stream>>>(batch_instruction, starts, NIv);
    starts_to_cnt<<<(G_ + 255) / 256, 256, 0, stream>>>(starts, pool_cnt + 2 * G_);
    batch_starts<<<(NAv + 1 + 255) / 256, 256, 0, stream>>>(batch_attribute, starts, NAv);
    starts_to_cnt<<<(G_ + 255) / 256, 256, 0, stream>>>(starts, pool_cnt + 3 * G_);
    batch_starts<<<(NSv + 1 + 255) / 256, 256, 0, stream>>>(batch_size, starts, NSv);
    starts_to_cnt<<<(G_ + 255) / 256, 256, 0, stream>>>(starts, pool_cnt + 4 * G_);

    // fused gather + MFMA node kernels (one 64-node tile per block)
    sage_mfma<64, 32, false, 128,  96, 4><<<(NTv + 63) / 64, 256, 0, stream>>>(
        deg, cur, eidx, OFF_VT, 0, xb_value, nullptr, xb_typ,
        w1p_vt, bl_vt, nullptr, nwp_t, nb_typ, batch_typ,
        pool_sum + (size_t)0 * G_ * HID, NTv);
    sage_mfma<64, 64, false, 128, 128, 4><<<(NVv + 63) / 64, 256, 0, stream>>>(
        deg, cur, eidx, OFF_IV, 0, xb_instr, nullptr, xb_value,
        w1p_iv, bl_iv, nullptr, nwp_v, nb_value, batch_value,
        pool_sum + (size_t)1 * G_ * HID, NVv);
    sage_mfma<64, 64, true,  192, 192, 3><<<(NIv + 63) / 64, 256, 0, stream>>>(
        deg, cur, eidx, OFF_VI, OFF_II, xb_value, xb_instr, xb_instr,
        w1p_vi, bl_vi, bl_ii, nwp_i, nb_instruction, batch_instruction,
        pool_sum + (size_t)2 * G_ * HID, NIv);
    sage_mfma<64, 32, false, 128,  96, 4><<<(NAv + 63) / 64, 256, 0, stream>>>(
        deg, cur, eidx, OFF_VA, 0, xb_value, nullptr, xb_attr,
        w1p_va, bl_va, nullptr, nwp_a, nb_attribute, batch_attribute,
        pool_sum + (size_t)3 * G_ * HID, NAv);
    sage_mfma<32, 32, false,  64,  64, 4><<<(NSv + 63) / 64, 256, 0, stream>>>(
        deg, cur, eidx, OFF_TS, 0, xb_typ, nullptr, xb_size,
        w1p_ts, bl_ts, nullptr, nwp_s, nb_size, batch_size,
        pool_sum + (size_t)4 * G_ * HID, NSv);

    final_kernel<<<G_, 64, 0, stream>>>(pool_sum, pool_cnt, gW, gb, (float*)d_out);
}

// Round 10
// 855.348 us; speedup vs baseline: 3.0994x; 1.0681x over previous
//
#include <hip/hip_runtime.h>

namespace {
constexpr int G_  = 2048;
constexpr int HID = 128;
constexpr int NVv = 500000, NIv = 300000, NTv = 50000, NAv = 50000, NSv = 10000;
constexpr int EVTv = 500000, EIVv = 1500000, EVIv = 1500000, EVAv = 500000, ETSv = 50000, EIIv = 600000;
// concatenated per-(edge-type,dst-node) CSR space
constexpr int OFF_VT = 0;
constexpr int OFF_IV = OFF_VT + NTv;
constexpr int OFF_VI = OFF_IV + NVv;
constexpr int OFF_VA = OFF_VI + NIv;
constexpr int OFF_TS = OFF_VA + NAv;
constexpr int OFF_II = OFF_TS + NSv;
constexpr int TOT_N  = OFF_II + NIv;          // 1210000
constexpr int TOT_E  = EVTv + EIVv + EVIv + EVAv + ETSv + EIIv;  // 4650000
constexpr int NCH    = (TOT_N + 1023) / 1024; // 1182
}

typedef short s16x8 __attribute__((ext_vector_type(8)));
typedef float f32x4 __attribute__((ext_vector_type(4)));

__device__ __forceinline__ float4 ld4(const float* p) { return *(const float4*)p; }

__device__ __forceinline__ unsigned short f2bf(float x) {
    unsigned u = __float_as_uint(x);
    u += 0x7fffu + ((u >> 16) & 1u);
    return (unsigned short)(u >> 16);
}

__device__ __forceinline__ void addbf8(float (&acc)[8], uint4 v) {
    acc[0] += __uint_as_float((v.x & 0xFFFFu) << 16);
    acc[1] += __uint_as_float(v.x & 0xFFFF0000u);
    acc[2] += __uint_as_float((v.y & 0xFFFFu) << 16);
    acc[3] += __uint_as_float(v.y & 0xFFFF0000u);
    acc[4] += __uint_as_float((v.z & 0xFFFFu) << 16);
    acc[5] += __uint_as_float(v.z & 0xFFFF0000u);
    acc[6] += __uint_as_float((v.w & 0xFFFFu) << 16);
    acc[7] += __uint_as_float(v.w & 0xFFFF0000u);
}

// ---------------------------------------------------------------------------
// fp32 -> bf16 table conversion (8 elems/thread)
// ---------------------------------------------------------------------------
__global__ __launch_bounds__(256)
void conv_bf16(const float* __restrict__ src, unsigned short* __restrict__ dst, int n8)
{
    int i = blockIdx.x * 256 + threadIdx.x;
    if (i >= n8) return;
    float4 a = ld4(&src[(size_t)i * 8]);
    float4 b = ld4(&src[(size_t)i * 8 + 4]);
    uint4 o;
    o.x = (unsigned)f2bf(a.x) | ((unsigned)f2bf(a.y) << 16);
    o.y = (unsigned)f2bf(a.z) | ((unsigned)f2bf(a.w) << 16);
    o.z = (unsigned)f2bf(b.x) | ((unsigned)f2bf(b.y) << 16);
    o.w = (unsigned)f2bf(b.z) | ((unsigned)f2bf(b.w) << 16);
    *(uint4*)&dst[(size_t)i * 8] = o;
}

// ---------------------------------------------------------------------------
// CSR build — XCD-localized (block r = blockIdx%8 owns dst slice r)
// ---------------------------------------------------------------------------
__global__ __launch_bounds__(256)
void edge_hist(const int* __restrict__ dst, int* __restrict__ deg,
               int off, int E, int N)
{
    int r     = blockIdx.x & 7;
    int chunk = blockIdx.x >> 3;
    int rlo = (int)((long)r * N / 8);
    int rhi = (int)((long)(r + 1) * N / 8);
    int base = chunk * 2048;
#pragma unroll
    for (int k = 0; k < 8; ++k) {
        int i = base + k * 256 + threadIdx.x;
        if (i < E) {
            int d = dst[i];
            if (d >= rlo && d < rhi) atomicAdd(&deg[off + d], 1);
        }
    }
}

__global__ __launch_bounds__(256)
void edge_pos(const int* __restrict__ src, const int* __restrict__ dst,
              int* __restrict__ cur, int* __restrict__ eidx,
              int off, int E, int N)
{
    int r     = blockIdx.x & 7;
    int chunk = blockIdx.x >> 3;
    int rlo = (int)((long)r * N / 8);
    int rhi = (int)((long)(r + 1) * N / 8);
    int base = chunk * 2048;
#pragma unroll
    for (int k = 0; k < 8; ++k) {
        int i = base + k * 256 + threadIdx.x;
        if (i < E) {
            int d = dst[i];
            if (d >= rlo && d < rhi) {
                int p = atomicAdd(&cur[off + d], 1);
                eidx[p] = src[i];
            }
        }
    }
}

__global__ __launch_bounds__(256)
void scan_chunk_sum(const int* __restrict__ deg, int* __restrict__ csum)
{
    __shared__ int sc[256];
    int blk = blockIdx.x, tid = threadIdx.x;
    int base = blk * 1024 + tid * 4;
    int s = 0;
#pragma unroll
    for (int k = 0; k < 4; ++k) { int idx = base + k; if (idx < TOT_N) s += deg[idx]; }
    sc[tid] = s; __syncthreads();
    for (int d = 128; d > 0; d >>= 1) {
        if (tid < d) sc[tid] += sc[tid + d];
        __syncthreads();
    }
    if (tid == 0) csum[blk] = sc[0];
}

__global__ __launch_bounds__(256)
void scan_offsets(const int* __restrict__ csum, int* __restrict__ coff)
{
    __shared__ int sc[256];
    int tid = threadIdx.x;
    int s[5]; int tsum = 0;
#pragma unroll
    for (int k = 0; k < 5; ++k) { int idx = tid * 5 + k; s[k] = (idx < NCH) ? csum[idx] : 0; tsum += s[k]; }
    sc[tid] = tsum; __syncthreads();
    for (int d = 1; d < 256; d <<= 1) {
        int v = (tid >= d) ? sc[tid - d] : 0;
        __syncthreads();
        sc[tid] += v;
        __syncthreads();
    }
    int run = sc[tid] - tsum;   // exclusive
#pragma unroll
    for (int k = 0; k < 5; ++k) { int idx = tid * 5 + k; if (idx < NCH) coff[idx] = run; run += s[k]; }
}

__global__ __launch_bounds__(256)
void scan_write(const int* __restrict__ deg, const int* __restrict__ coff, int* __restrict__ cur)
{
    __shared__ int sc[256];
    int blk = blockIdx.x, tid = threadIdx.x;
    int base = blk * 1024 + tid * 4;
    int v[4]; int tsum = 0;
#pragma unroll
    for (int k = 0; k < 4; ++k) { int idx = base + k; v[k] = (idx < TOT_N) ? deg[idx] : 0; tsum += v[k]; }
    sc[tid] = tsum; __syncthreads();
    for (int d = 1; d < 256; d <<= 1) {
        int t = (tid >= d) ? sc[tid - d] : 0;
        __syncthreads();
        sc[tid] += t;
        __syncthreads();
    }
    int run = coff[blk] + sc[tid] - tsum;
#pragma unroll
    for (int k = 0; k < 4; ++k) { int idx = base + k; if (idx < TOT_N) cur[idx] = run; run += v[k]; }
}

// ---------------------------------------------------------------------------
// Sorted-batch boundary scan -> per-type starts array (G_+1 entries).
// ---------------------------------------------------------------------------
__global__ __launch_bounds__(256)
void batch_starts(const int* __restrict__ batch, int* __restrict__ start, int N)
{
    int i = blockIdx.x * 256 + threadIdx.x;
    if (i > N) return;
    if (i == N) {
        int b = batch[N - 1];
        for (int g = b + 1; g <= G_; ++g) start[g] = N;
    } else {
        int b = batch[i];
        int bp = (i == 0) ? -1 : batch[i - 1];
        for (int g = bp + 1; g <= b; ++g) start[g] = i;
    }
}

// ---------------------------------------------------------------------------
// Packed weight prep: out[(ks*8+nb)*512 + l*8 + j] = bf16(W1[k][row]),
// row = nb*16 + (l&15), k = ks*32 + (l>>4)*8 + j.
// ---------------------------------------------------------------------------
__global__ __launch_bounds__(256)
void prep_wpack(const float* __restrict__ S0, int L0,
                const float* __restrict__ S1, int L1,
                const float* __restrict__ S2, const float* __restrict__ S2b,
                unsigned short* __restrict__ out, int K1)
{
    int i = blockIdx.x * 256 + threadIdx.x;
    int total = (K1 / 32) * 8 * 512;
    if (i >= total) return;
    int frag = i >> 9;
    int rem  = i & 511;
    int l = rem >> 3, j = rem & 7;
    int ks = frag >> 3, nb = frag & 7;
    int row = nb * 16 + (l & 15);
    int k = ks * 32 + (l >> 4) * 8 + j;
    float v;
    if (k < L0) v = S0[k * 128 + row];
    else if (k < L0 + L1) v = S1[(k - L0) * 128 + row];
    else {
        int kk = k - L0 - L1;
        v = S2[kk * 128 + row];
        if (S2b) v += S2b[kk * 128 + row];
    }
    out[i] = f2bf(v);
}

// ---------------------------------------------------------------------------
// Fused gather + MFMA node kernel. Block = 256 thr (4 waves), one 64-node
// tile. Phase 1: CSR mean-gather (unroll-4 MLP) + x_dst -> swizzled bf16
// A-tile in u_sh. Phase 2: stage-1 MFMA. Phase 3: h overwrites u_sh (union,
// barrier-fenced). Phase 4: stage-2 MFMA + pooled atomics.
// ---------------------------------------------------------------------------
template<int DSa, int DD, bool HAS2, int ASTR, int K1, int MINW>
__global__ __launch_bounds__(256, MINW)
void sage_mfma(const int* __restrict__ deg, const int* __restrict__ cur,
               const int* __restrict__ eidx, int off1, int off2,
               const unsigned short* __restrict__ xs1,
               const unsigned short* __restrict__ xs2,
               const unsigned short* __restrict__ xd,
               const unsigned short* __restrict__ W1P,
               const float* __restrict__ bl, const float* __restrict__ bl2,
               const unsigned short* __restrict__ nWP,
               const float* __restrict__ nbp,
               const int* __restrict__ batch,
               float* __restrict__ pool_sum, int N)
{
    constexpr int KST  = K1 / 32;
    constexpr int GCOL = HAS2 ? 2 * DSa : DSa;
    constexpr int XOFF = GCOL;
    constexpr int C8d  = DD / 8;
    constexpr int LPG1 = DSa / 8;        // lanes per gathered node
    constexpr int NPW1 = 64 / LPG1;      // nodes per wave
    constexpr int PASSES = 64 / (4 * NPW1) > 0 ? 64 / (4 * NPW1) : 1;
    constexpr int UELEM = (64 * ASTR > 64 * 128) ? 64 * ASTR : 64 * 128;

    __shared__ __align__(16) unsigned short u_sh[UELEM];   // A-tile, then h
    __shared__ int batch_sh[64];
    unsigned short* a_sh = u_sh;
    unsigned short* h_sh = u_sh;

    const int tid = threadIdx.x;
    const int w = tid >> 6, l = tid & 63, lg = l >> 4, lr = l & 15;
    const int node0 = blockIdx.x * 64;
    const unsigned swz = (unsigned)(lr & 7) << 4;

    if (tid < 64) batch_sh[tid] = (node0 + tid < N) ? batch[node0 + tid] : -1;

    // ---- stage-1 weights -> registers early (independent of gather) ----
    s16x8 w1[2][KST];
#pragma unroll
    for (int j = 0; j < 2; ++j)
#pragma unroll
        for (int ks = 0; ks < KST; ++ks)
            w1[j][ks] = *(const s16x8*)&W1P[(unsigned)(ks * 8 + (w * 2 + j)) * 512 + (unsigned)l * 8];

    float b1[2];
#pragma unroll
    for (int j = 0; j < 2; ++j) {
        int col = (w * 2 + j) * 16 + lr;
        float b = bl[col];
        if constexpr (HAS2) b += bl2[col];
        b1[j] = b;
    }

    // ---- x_dst staging (bf16 -> swizzled LDS) ----
    for (int c = tid; c < 64 * C8d; c += 256) {
        int r = c / C8d; int col = (c - r * C8d) * 8; int node = node0 + r;
        uint4 pk = make_uint4(0u, 0u, 0u, 0u);
        if (node < N) pk = *(const uint4*)&xd[(size_t)node * DD + col];
        unsigned byte = ((unsigned)(r * ASTR + XOFF + col) * 2u) ^ ((unsigned)(r & 7) << 4);
        *(uint4*)((char*)a_sh + byte) = pk;
    }

    // ---- fused CSR mean gather -> swizzled LDS A-tile (unroll-4) ----
    auto gather_rows = [&](int offx, const unsigned short* __restrict__ xsrc, int colbase) {
#pragma unroll
        for (int ps = 0; ps < PASSES; ++ps) {
            int r = ps * (4 * NPW1) + w * NPW1 + (l / LPG1);
            int col8 = (l % LPG1) * 8;
            int node = node0 + r;
            uint4 o = make_uint4(0u, 0u, 0u, 0u);
            if (node < N) {
                int e_end = cur[offx + node];
                int d     = deg[offx + node];
                int e0    = e_end - d;
                float acc[8] = {0.f, 0.f, 0.f, 0.f, 0.f, 0.f, 0.f, 0.f};
                int t = 0;
                for (; t + 4 <= d; t += 4) {
                    int s0 = eidx[e0 + t];
                    int s1 = eidx[e0 + t + 1];
                    int s2 = eidx[e0 + t + 2];
                    int s3 = eidx[e0 + t + 3];
                    uint4 v0 = *(const uint4*)&xsrc[(size_t)s0 * DSa + col8];
                    uint4 v1 = *(const uint4*)&xsrc[(size_t)s1 * DSa + col8];
                    uint4 v2 = *(const uint4*)&xsrc[(size_t)s2 * DSa + col8];
                    uint4 v3 = *(const uint4*)&xsrc[(size_t)s3 * DSa + col8];
                    addbf8(acc, v0); addbf8(acc, v1); addbf8(acc, v2); addbf8(acc, v3);
                }
                for (; t < d; ++t) {
                    int s = eidx[e0 + t];
                    addbf8(acc, *(const uint4*)&xsrc[(size_t)s * DSa + col8]);
                }
                float inv = 1.0f / fmaxf((float)d, 1.0f);
                o.x = (unsigned)f2bf(acc[0] * inv) | ((unsigned)f2bf(acc[1] * inv) << 16);
                o.y = (unsigned)f2bf(acc[2] * inv) | ((unsigned)f2bf(acc[3] * inv) << 16);
                o.z = (unsigned)f2bf(acc[4] * inv) | ((unsigned)f2bf(acc[5] * inv) << 16);
                o.w = (unsigned)f2bf(acc[6] * inv) | ((unsigned)f2bf(acc[7] * inv) << 16);
            }
            unsigned byte = ((unsigned)(r * ASTR + colbase + col8) * 2u) ^ ((unsigned)(r & 7) << 4);
            *(uint4*)((char*)a_sh + byte) = o;
        }
    };
    gather_rows(off1, xs1, 0);
    if constexpr (HAS2) gather_rows(off2, xs2, DSa);

    __syncthreads();

    // ---- stage 1: h = A @ W1 ----
    f32x4 acc[4][2];
#pragma unroll
    for (int rf = 0; rf < 4; ++rf)
#pragma unroll
        for (int j = 0; j < 2; ++j) acc[rf][j] = (f32x4){0.f, 0.f, 0.f, 0.f};

#pragma unroll
    for (int ks = 0; ks < KST; ++ks) {
        s16x8 af[4];
#pragma unroll
        for (int rf = 0; rf < 4; ++rf)
            af[rf] = *(const s16x8*)((const char*)a_sh +
                        (((unsigned)((rf * 16 + lr) * ASTR + ks * 32 + lg * 8) * 2u) ^ swz));
#pragma unroll
        for (int rf = 0; rf < 4; ++rf)
#pragma unroll
            for (int j = 0; j < 2; ++j)
                acc[rf][j] = __builtin_amdgcn_mfma_f32_16x16x32_bf16(af[rf], w1[j][ks], acc[rf][j], 0, 0, 0);
    }

    __syncthreads();   // all A-tile reads done before h overwrites the union

    // ---- bias + relu -> bf16 h in LDS (overwrites A-tile) ----
#pragma unroll
    for (int rf = 0; rf < 4; ++rf)
#pragma unroll
        for (int j = 0; j < 2; ++j) {
            int col = (w * 2 + j) * 16 + lr;
#pragma unroll
            for (int rg = 0; rg < 4; ++rg) {
                float hv = fmaxf(acc[rf][j][rg] + b1[j], 0.0f);
                int row = rf * 16 + lg * 4 + rg;
                unsigned byte = ((unsigned)(row * 128 + col) * 2u) ^ ((unsigned)(row & 7) << 4);
                *(unsigned short*)((char*)h_sh + byte) = f2bf(hv);
            }
        }

    // ---- stage-2 weights -> registers ----
    s16x8 w2[2][4];
#pragma unroll
    for (int j = 0; j < 2; ++j)
#pragma unroll
        for (int ks = 0; ks < 4; ++ks)
            w2[j][ks] = *(const s16x8*)&nWP[(unsigned)(ks * 8 + (w * 2 + j)) * 512 + (unsigned)l * 8];

    float nbv[2];
#pragma unroll
    for (int j = 0; j < 2; ++j) nbv[j] = nbp[(w * 2 + j) * 16 + lr];

    __syncthreads();

    // ---- stage 2: z = h @ nW ----
    f32x4 acc2[4][2];
#pragma unroll
    for (int rf = 0; rf < 4; ++rf)
#pragma unroll
        for (int j = 0; j < 2; ++j) acc2[rf][j] = (f32x4){0.f, 0.f, 0.f, 0.f};

#pragma unroll
    for (int ks = 0; ks < 4; ++ks) {
        s16x8 hf[4];
#pragma unroll
        for (int rf = 0; rf < 4; ++rf)
            hf[rf] = *(const s16x8*)((const char*)h_sh +
                        (((unsigned)((rf * 16 + lr) * 128 + ks * 32 + lg * 8) * 2u) ^ swz));
#pragma unroll
        for (int rf = 0; rf < 4; ++rf)
#pragma unroll
            for (int j = 0; j < 2; ++j)
                acc2[rf][j] = __builtin_amdgcn_mfma_f32_16x16x32_bf16(hf[rf], w2[j][ks], acc2[rf][j], 0, 0, 0);
    }

    // ---- pooling ----
#pragma unroll
    for (int rf = 0; rf < 4; ++rf) {
        int gf = batch_sh[rf * 16];
        int gl = batch_sh[rf * 16 + 15];
        if (gf == gl && gf >= 0) {
#pragma unroll
            for (int j = 0; j < 2; ++j) {
                float s = acc2[rf][j][0] + acc2[rf][j][1] + acc2[rf][j][2] + acc2[rf][j][3]
                        + 4.0f * nbv[j];
                s += __shfl_xor(s, 16);
                s += __shfl_xor(s, 32);
                if (lg == 0)
                    atomicAdd(&pool_sum[gf * 128 + (w * 2 + j) * 16 + lr], s);
            }
        } else {
            int rbase = rf * 16 + lg * 4;
            int bt[4];
#pragma unroll
            for (int rg = 0; rg < 4; ++rg) bt[rg] = batch_sh[rbase + rg];
#pragma unroll
            for (int j = 0; j < 2; ++j) {
                int col = (w * 2 + j) * 16 + lr;
                float run = acc2[rf][j][0] + nbv[j];
                int cb = bt[0];
#pragma unroll
                for (int rg = 1; rg < 4; ++rg) {
                    float z = acc2[rf][j][rg] + nbv[j];
                    if (bt[rg] == cb) run += z;
                    else {
                        if (cb >= 0) atomicAdd(&pool_sum[cb * 128 + col], run);
                        cb = bt[rg]; run = z;
                    }
                }
                if (cb >= 0) atomicAdd(&pool_sum[cb * 128 + col], run);
            }
        }
    }
}

// ---------------------------------------------------------------------------
// Final: counts derived from per-type starts arrays (no pool_cnt buffer).
// ---------------------------------------------------------------------------
__global__ __launch_bounds__(64)
void final_kernel(const float* __restrict__ pool_sum, const int* __restrict__ starts_all,
                  const float* __restrict__ gW, const float* __restrict__ gb,
                  float* __restrict__ out)
{
    __shared__ float p_sh[5 * HID];
    int g = blockIdx.x, tid = threadIdx.x;
    for (int i = tid; i < 5 * HID; i += 64) {
        int t  = i >> 7;
        int jj = i & 127;
        const int* st = starts_all + t * (G_ + 1);
        float c = fmaxf((float)(st[g + 1] - st[g]), 1.0f);
        p_sh[i] = pool_sum[((size_t)t * G_ + g) * HID + jj] / c;
    }
    __syncthreads();
    float acc = gb[tid];
#pragma unroll 8
    for (int k = 0; k < 5 * HID; ++k)
        acc += p_sh[k] * gW[k * 64 + tid];
    out[g * 64 + tid] = acc;
}

// ---------------------------------------------------------------------------
extern "C" void kernel_launch(void* const* d_in, const int* in_sizes, int n_in,
                              void* d_out, int out_size, void* d_ws, size_t ws_size,
                              hipStream_t stream)
{
    const float* x_value       = (const float*)d_in[0];
    const float* x_typ         = (const float*)d_in[1];
    const float* x_size_       = (const float*)d_in[2];
    const float* x_attribute   = (const float*)d_in[3];
    const float* x_instruction = (const float*)d_in[4];
    const float* Wl_vt = (const float*)d_in[5];
    const float* bl_vt = (const float*)d_in[6];
    const float* Wr_vt = (const float*)d_in[7];
    const float* Wl_iv = (const float*)d_in[8];
    const float* bl_iv = (const float*)d_in[9];
    const float* Wr_iv = (const float*)d_in[10];
    const float* Wl_vi = (const float*)d_in[11];
    const float* bl_vi = (const float*)d_in[12];
    const float* Wr_vi = (const float*)d_in[13];
    const float* Wl_va = (const float*)d_in[14];
    const float* bl_va = (const float*)d_in[15];
    const float* Wr_va = (const float*)d_in[16];
    const float* Wl_ts = (const float*)d_in[17];
    const float* bl_ts = (const float*)d_in[18];
    const float* Wr_ts = (const float*)d_in[19];
    const float* Wl_ii = (const float*)d_in[20];
    const float* bl_ii = (const float*)d_in[21];
    const float* Wr_ii = (const float*)d_in[22];
    const float* nW_typ         = (const float*)d_in[23];
    const float* nb_typ         = (const float*)d_in[24];
    const float* nW_value       = (const float*)d_in[25];
    const float* nb_value       = (const float*)d_in[26];
    const float* nW_instruction = (const float*)d_in[27];
    const float* nb_instruction = (const float*)d_in[28];
    const float* nW_attribute   = (const float*)d_in[29];
    const float* nb_attribute   = (const float*)d_in[30];
    const float* nW_size        = (const float*)d_in[31];
    const float* nb_size        = (const float*)d_in[32];
    const float* gW = (const float*)d_in[33];
    const float* gb = (const float*)d_in[34];
    const int* src_vt = (const int*)d_in[35];
    const int* dst_vt = (const int*)d_in[36];
    const int* src_iv = (const int*)d_in[37];
    const int* dst_iv = (const int*)d_in[38];
    const int* src_vi = (const int*)d_in[39];
    const int* dst_vi = (const int*)d_in[40];
    const int* src_va = (const int*)d_in[41];
    const int* dst_va = (const int*)d_in[42];
    const int* src_ts = (const int*)d_in[43];
    const int* dst_ts = (const int*)d_in[44];
    const int* src_ii = (const int*)d_in[45];
    const int* dst_ii = (const int*)d_in[46];
    const int* batch_typ         = (const int*)d_in[47];
    const int* batch_value       = (const int*)d_in[48];
    const int* batch_instruction = (const int*)d_in[49];
    const int* batch_attribute   = (const int*)d_in[50];
    const int* batch_size        = (const int*)d_in[51];

    // ---- workspace layout ----
    int* deg = (int*)d_ws;                                   // TOT_N (zeroed)
    float* pool_sum = (float*)(deg + TOT_N);                 // 5*G*HID (zeroed)
    size_t zero_bytes = (size_t)TOT_N * 4 + (size_t)5 * G_ * HID * 4;

    int* cur        = (int*)(pool_sum + (size_t)5 * G_ * HID);  // TOT_N
    int* csum       = cur + TOT_N;                              // NCH
    int* coff       = csum + NCH;                               // NCH
    int* eidx       = coff + NCH;                               // TOT_E
    int* starts_all = eidx + TOT_E;                             // 5*(G_+1)
    // bf16 feature tables
    unsigned short* xb = (unsigned short*)(((uintptr_t)(starts_all + 5 * (G_ + 1)) + 63) & ~(uintptr_t)63);
    size_t xo = 0;
    unsigned short* xb_value = xb + xo; xo += (size_t)NVv * 64;
    unsigned short* xb_typ   = xb + xo; xo += (size_t)NTv * 32;
    unsigned short* xb_instr = xb + xo; xo += (size_t)NIv * 64;
    unsigned short* xb_attr  = xb + xo; xo += (size_t)NAv * 32;
    unsigned short* xb_size  = xb + xo; xo += (size_t)NSv * 32;
    unsigned short* wt = (unsigned short*)(((uintptr_t)(xb + xo) + 63) & ~(uintptr_t)63);
    size_t wo = 0;
    unsigned short* w1p_vt = wt + wo; wo += 128 * 96;
    unsigned short* w1p_iv = wt + wo; wo += 128 * 128;
    unsigned short* w1p_vi = wt + wo; wo += 128 * 192;
    unsigned short* w1p_va = wt + wo; wo += 128 * 96;
    unsigned short* w1p_ts = wt + wo; wo += 128 * 64;
    unsigned short* nwp_t  = wt + wo; wo += 128 * 128;
    unsigned short* nwp_v  = wt + wo; wo += 128 * 128;
    unsigned short* nwp_i  = wt + wo; wo += 128 * 128;
    unsigned short* nwp_a  = wt + wo; wo += 128 * 128;
    unsigned short* nwp_s  = wt + wo; wo += 128 * 128;

    hipMemsetAsync(d_ws, 0, zero_bytes, stream);

    // bf16 feature tables
    conv_bf16<<<((NVv * 64 / 8) + 255) / 256, 256, 0, stream>>>(x_value,       xb_value, NVv * 64 / 8);
    conv_bf16<<<((NTv * 32 / 8) + 255) / 256, 256, 0, stream>>>(x_typ,         xb_typ,   NTv * 32 / 8);
    conv_bf16<<<((NIv * 64 / 8) + 255) / 256, 256, 0, stream>>>(x_instruction, xb_instr, NIv * 64 / 8);
    conv_bf16<<<((NAv * 32 / 8) + 255) / 256, 256, 0, stream>>>(x_attribute,   xb_attr,  NAv * 32 / 8);
    conv_bf16<<<((NSv * 32 / 8) + 255) / 256, 256, 0, stream>>>(x_size_,       xb_size,  NSv * 32 / 8);

    // packed weight prep (tiny)
    prep_wpack<<<(128 *  96 + 255) / 256, 256, 0, stream>>>(Wl_vt, 64, nullptr, 0, Wr_vt, nullptr, w1p_vt,  96);
    prep_wpack<<<(128 * 128 + 255) / 256, 256, 0, stream>>>(Wl_iv, 64, nullptr, 0, Wr_iv, nullptr, w1p_iv, 128);
    prep_wpack<<<(128 * 192 + 255) / 256, 256, 0, stream>>>(Wl_vi, 64, Wl_ii, 64, Wr_vi, Wr_ii,   w1p_vi, 192);
    prep_wpack<<<(128 *  96 + 255) / 256, 256, 0, stream>>>(Wl_va, 64, nullptr, 0, Wr_va, nullptr, w1p_va,  96);
    prep_wpack<<<(128 *  64 + 255) / 256, 256, 0, stream>>>(Wl_ts, 32, nullptr, 0, Wr_ts, nullptr, w1p_ts,  64);
    prep_wpack<<<(128 * 128 + 255) / 256, 256, 0, stream>>>(nW_typ,         128, nullptr, 0, nullptr, nullptr, nwp_t, 128);
    prep_wpack<<<(128 * 128 + 255) / 256, 256, 0, stream>>>(nW_value,       128, nullptr, 0, nullptr, nullptr, nwp_v, 128);
    prep_wpack<<<(128 * 128 + 255) / 256, 256, 0, stream>>>(nW_instruction, 128, nullptr, 0, nullptr, nullptr, nwp_i, 128);
    prep_wpack<<<(128 * 128 + 255) / 256, 256, 0, stream>>>(nW_attribute,   128, nullptr, 0, nullptr, nullptr, nwp_a, 128);
    prep_wpack<<<(128 * 128 + 255) / 256, 256, 0, stream>>>(nW_size,        128, nullptr, 0, nullptr, nullptr, nwp_s, 128);

    // CSR build (XCD-localized)
    auto egrid = [](int E) { return ((E + 2047) / 2048) * 8; };
    edge_hist<<<egrid(EVTv), 256, 0, stream>>>(dst_vt, deg, OFF_VT, EVTv, NTv);
    edge_hist<<<egrid(EIVv), 256, 0, stream>>>(dst_iv, deg, OFF_IV, EIVv, NVv);
    edge_hist<<<egrid(EVIv), 256, 0, stream>>>(dst_vi, deg, OFF_VI, EVIv, NIv);
    edge_hist<<<egrid(EVAv), 256, 0, stream>>>(dst_va, deg, OFF_VA, EVAv, NAv);
    edge_hist<<<egrid(ETSv), 256, 0, stream>>>(dst_ts, deg, OFF_TS, ETSv, NSv);
    edge_hist<<<egrid(EIIv), 256, 0, stream>>>(dst_ii, deg, OFF_II, EIIv, NIv);

    scan_chunk_sum<<<NCH, 256, 0, stream>>>(deg, csum);
    scan_offsets<<<1, 256, 0, stream>>>(csum, coff);
    scan_write<<<NCH, 256, 0, stream>>>(deg, coff, cur);

    edge_pos<<<egrid(EVTv), 256, 0, stream>>>(src_vt, dst_vt, cur, eidx, OFF_VT, EVTv, NTv);
    edge_pos<<<egrid(EIVv), 256, 0, stream>>>(src_iv, dst_iv, cur, eidx, OFF_IV, EIVv, NVv);
    edge_pos<<<egrid(EVIv), 256, 0, stream>>>(src_vi, dst_vi, cur, eidx, OFF_VI, EVIv, NIv);
    edge_pos<<<egrid(EVAv), 256, 0, stream>>>(src_va, dst_va, cur, eidx, OFF_VA, EVAv, NAv);
    edge_pos<<<egrid(ETSv), 256, 0, stream>>>(src_ts, dst_ts, cur, eidx, OFF_TS, ETSv, NSv);
    edge_pos<<<egrid(EIIv), 256, 0, stream>>>(src_ii, dst_ii, cur, eidx, OFF_II, EIIv, NIv);

    // sorted-batch starts (no atomics); counts derived in final_kernel
    batch_starts<<<(NTv + 1 + 255) / 256, 256, 0, stream>>>(batch_typ,         starts_all + 0 * (G_ + 1), NTv);
    batch_starts<<<(NVv + 1 + 255) / 256, 256, 0, stream>>>(batch_value,       starts_all + 1 * (G_ + 1), NVv);
    batch_starts<<<(NIv + 1 + 255) / 256, 256, 0, stream>>>(batch_instruction, starts_all + 2 * (G_ + 1), NIv);
    batch_starts<<<(NAv + 1 + 255) / 256, 256, 0, stream>>>(batch_attribute,   starts_all + 3 * (G_ + 1), NAv);
    batch_starts<<<(NSv + 1 + 255) / 256, 256, 0, stream>>>(batch_size,        starts_all + 4 * (G_ + 1), NSv);

    // fused gather + MFMA node kernels (one 64-node tile per block)
    sage_mfma<64, 32, false, 128,  96, 4><<<(NTv + 63) / 64, 256, 0, stream>>>(
        deg, cur, eidx, OFF_VT, 0, xb_value, nullptr, xb_typ,
        w1p_vt, bl_vt, nullptr, nwp_t, nb_typ, batch_typ,
        pool_sum + (size_t)0 * G_ * HID, NTv);
    sage_mfma<64, 64, false, 128, 128, 4><<<(NVv + 63) / 64, 256, 0, stream>>>(
        deg, cur, eidx, OFF_IV, 0, xb_instr, nullptr, xb_value,
        w1p_iv, bl_iv, nullptr, nwp_v, nb_value, batch_value,
        pool_sum + (size_t)1 * G_ * HID, NVv);
    sage_mfma<64, 64, true,  192, 192, 3><<<(NIv + 63) / 64, 256, 0, stream>>>(
        deg, cur, eidx, OFF_VI, OFF_II, xb_value, xb_instr, xb_instr,
        w1p_vi, bl_vi, bl_ii, nwp_i, nb_instruction, batch_instruction,
        pool_sum + (size_t)2 * G_ * HID, NIv);
    sage_mfma<64, 32, false, 128,  96, 4><<<(NAv + 63) / 64, 256, 0, stream>>>(
        deg, cur, eidx, OFF_VA, 0, xb_value, nullptr, xb_attr,
        w1p_va, bl_va, nullptr, nwp_a, nb_attribute, batch_attribute,
        pool_sum + (size_t)3 * G_ * HID, NAv);
    sage_mfma<32, 32, false,  64,  64, 4><<<(NSv + 63) / 64, 256, 0, stream>>>(
        deg, cur, eidx, OFF_TS, 0, xb_typ, nullptr, xb_size,
        w1p_ts, bl_ts, nullptr, nwp_s, nb_size, batch_size,
        pool_sum + (size_t)4 * G_ * HID, NSv);

    final_kernel<<<G_, 64, 0, stream>>>(pool_sum, starts_all, gW, gb, (float*)d_out);
}

// Round 11
// 839.851 us; speedup vs baseline: 3.1565x; 1.0185x over previous
//
#include <hip/hip_runtime.h>

namespace {
constexpr int G_  = 2048;
constexpr int HID = 128;
constexpr int NVv = 500000, NIv = 300000, NTv = 50000, NAv = 50000, NSv = 10000;
constexpr int EVTv = 500000, EIVv = 1500000, EVIv = 1500000, EVAv = 500000, ETSv = 50000, EIIv = 600000;
// concatenated per-(edge-type,dst-node) CSR space
constexpr int OFF_VT = 0;
constexpr int OFF_IV = OFF_VT + NTv;
constexpr int OFF_VI = OFF_IV + NVv;
constexpr int OFF_VA = OFF_VI + NIv;
constexpr int OFF_TS = OFF_VA + NAv;
constexpr int OFF_II = OFF_TS + NSv;
constexpr int TOT_N  = OFF_II + NIv;          // 1210000
constexpr int TOT_E  = EVTv + EIVv + EVIv + EVAv + ETSv + EIIv;  // 4650000
constexpr int NCH    = (TOT_N + 1023) / 1024; // 1182

constexpr int egrid_c(int E) { return ((E + 2047) / 2048) * 8; }
constexpr int HG_VT = egrid_c(EVTv), HG_IV = egrid_c(EIVv), HG_VI = egrid_c(EVIv);
constexpr int HG_VA = egrid_c(EVAv), HG_TS = egrid_c(ETSv), HG_II = egrid_c(EIIv);
constexpr int HG_TOT = HG_VT + HG_IV + HG_VI + HG_VA + HG_TS + HG_II;

constexpr int C8_V = NVv * 64 / 8, C8_T = NTv * 32 / 8, C8_I = NIv * 64 / 8;
constexpr int C8_A = NAv * 32 / 8, C8_S = NSv * 32 / 8;
constexpr int CB_V = (C8_V + 255) / 256, CB_T = (C8_T + 255) / 256, CB_I = (C8_I + 255) / 256;
constexpr int CB_A = (C8_A + 255) / 256, CB_S = (C8_S + 255) / 256;
constexpr int CB_TOT = CB_V + CB_T + CB_I + CB_A + CB_S;

constexpr int BSB_T = (NTv + 256) / 256, BSB_V = (NVv + 256) / 256, BSB_I = (NIv + 256) / 256;
constexpr int BSB_A = (NAv + 256) / 256, BSB_S = (NSv + 256) / 256;
constexpr int BSB_TOT = BSB_T + BSB_V + BSB_I + BSB_A + BSB_S;

constexpr int SB_V = (NVv + 63) / 64, SB_I = (NIv + 63) / 64, SB_T = (NTv + 63) / 64;
constexpr int SB_A = (NAv + 63) / 64, SB_S = (NSv + 63) / 64;
constexpr int SB_TOT = SB_V + SB_I + SB_T + SB_A + SB_S;

constexpr int SMEM_TILE = 64 * 192 * 2;           // max A-tile bytes (instr)
constexpr int SMEM_BYTES = SMEM_TILE + 64 * 4;    // + batch_sh
}

typedef short s16x8 __attribute__((ext_vector_type(8)));
typedef float f32x4 __attribute__((ext_vector_type(4)));

__device__ __forceinline__ float4 ld4(const float* p) { return *(const float4*)p; }

__device__ __forceinline__ unsigned short f2bf(float x) {
    unsigned u = __float_as_uint(x);
    u += 0x7fffu + ((u >> 16) & 1u);
    return (unsigned short)(u >> 16);
}

__device__ __forceinline__ void addbf8(float (&acc)[8], uint4 v) {
    acc[0] += __uint_as_float((v.x & 0xFFFFu) << 16);
    acc[1] += __uint_as_float(v.x & 0xFFFF0000u);
    acc[2] += __uint_as_float((v.y & 0xFFFFu) << 16);
    acc[3] += __uint_as_float(v.y & 0xFFFF0000u);
    acc[4] += __uint_as_float((v.z & 0xFFFFu) << 16);
    acc[5] += __uint_as_float(v.z & 0xFFFF0000u);
    acc[6] += __uint_as_float((v.w & 0xFFFFu) << 16);
    acc[7] += __uint_as_float(v.w & 0xFFFF0000u);
}

// ---------------------------------------------------------------------------
// Fused fp32 -> bf16 conversion for all 5 tables
// ---------------------------------------------------------------------------
__global__ __launch_bounds__(256)
void conv_all(const float* __restrict__ xv, const float* __restrict__ xt,
              const float* __restrict__ xi, const float* __restrict__ xa,
              const float* __restrict__ xs,
              unsigned short* __restrict__ bv, unsigned short* __restrict__ bt,
              unsigned short* __restrict__ bi, unsigned short* __restrict__ ba,
              unsigned short* __restrict__ bs)
{
    int b = blockIdx.x;
    const float* src; unsigned short* dst; int n8;
    if (b < CB_V) { src = xv; dst = bv; n8 = C8_V; }
    else if ((b -= CB_V) < CB_T) { src = xt; dst = bt; n8 = C8_T; }
    else if ((b -= CB_T) < CB_I) { src = xi; dst = bi; n8 = C8_I; }
    else if ((b -= CB_I) < CB_A) { src = xa; dst = ba; n8 = C8_A; }
    else { b -= CB_A; src = xs; dst = bs; n8 = C8_S; }
    int i = b * 256 + threadIdx.x;
    if (i >= n8) return;
    float4 a = ld4(&src[(size_t)i * 8]);
    float4 c = ld4(&src[(size_t)i * 8 + 4]);
    uint4 o;
    o.x = (unsigned)f2bf(a.x) | ((unsigned)f2bf(a.y) << 16);
    o.y = (unsigned)f2bf(a.z) | ((unsigned)f2bf(a.w) << 16);
    o.z = (unsigned)f2bf(c.x) | ((unsigned)f2bf(c.y) << 16);
    o.w = (unsigned)f2bf(c.z) | ((unsigned)f2bf(c.w) << 16);
    *(uint4*)&dst[(size_t)i * 8] = o;
}

// ---------------------------------------------------------------------------
// Fused CSR histogram / position-scatter (XCD-localized within each segment)
// ---------------------------------------------------------------------------
__device__ __forceinline__ void hist_body(const int* __restrict__ dst, int* __restrict__ deg,
                                          int off, int E, int N, int b)
{
    int r = b & 7, chunk = b >> 3;
    int rlo = (int)((long)r * N / 8);
    int rhi = (int)((long)(r + 1) * N / 8);
    int base = chunk * 2048;
#pragma unroll
    for (int k = 0; k < 8; ++k) {
        int i = base + k * 256 + threadIdx.x;
        if (i < E) {
            int d = dst[i];
            if (d >= rlo && d < rhi) atomicAdd(&deg[off + d], 1);
        }
    }
}

__global__ __launch_bounds__(256)
void edge_hist_all(const int* __restrict__ d_vt, const int* __restrict__ d_iv,
                   const int* __restrict__ d_vi, const int* __restrict__ d_va,
                   const int* __restrict__ d_ts, const int* __restrict__ d_ii,
                   int* __restrict__ deg)
{
    int b = blockIdx.x;
    if (b < HG_VT) { hist_body(d_vt, deg, OFF_VT, EVTv, NTv, b); return; }
    if ((b -= HG_VT) < HG_IV) { hist_body(d_iv, deg, OFF_IV, EIVv, NVv, b); return; }
    if ((b -= HG_IV) < HG_VI) { hist_body(d_vi, deg, OFF_VI, EVIv, NIv, b); return; }
    if ((b -= HG_VI) < HG_VA) { hist_body(d_va, deg, OFF_VA, EVAv, NAv, b); return; }
    if ((b -= HG_VA) < HG_TS) { hist_body(d_ts, deg, OFF_TS, ETSv, NSv, b); return; }
    b -= HG_TS;              hist_body(d_ii, deg, OFF_II, EIIv, NIv, b);
}

__device__ __forceinline__ void pos_body(const int* __restrict__ src, const int* __restrict__ dst,
                                         int* __restrict__ cur, int* __restrict__ eidx,
                                         int off, int E, int N, int b)
{
    int r = b & 7, chunk = b >> 3;
    int rlo = (int)((long)r * N / 8);
    int rhi = (int)((long)(r + 1) * N / 8);
    int base = chunk * 2048;
#pragma unroll
    for (int k = 0; k < 8; ++k) {
        int i = base + k * 256 + threadIdx.x;
        if (i < E) {
            int d = dst[i];
            if (d >= rlo && d < rhi) {
                int p = atomicAdd(&cur[off + d], 1);
                eidx[p] = src[i];
            }
        }
    }
}

__global__ __launch_bounds__(256)
void edge_pos_all(const int* __restrict__ s_vt, const int* __restrict__ d_vt,
                  const int* __restrict__ s_iv, const int* __restrict__ d_iv,
                  const int* __restrict__ s_vi, const int* __restrict__ d_vi,
                  const int* __restrict__ s_va, const int* __restrict__ d_va,
                  const int* __restrict__ s_ts, const int* __restrict__ d_ts,
                  const int* __restrict__ s_ii, const int* __restrict__ d_ii,
                  int* __restrict__ cur, int* __restrict__ eidx)
{
    int b = blockIdx.x;
    if (b < HG_VT) { pos_body(s_vt, d_vt, cur, eidx, OFF_VT, EVTv, NTv, b); return; }
    if ((b -= HG_VT) < HG_IV) { pos_body(s_iv, d_iv, cur, eidx, OFF_IV, EIVv, NVv, b); return; }
    if ((b -= HG_IV) < HG_VI) { pos_body(s_vi, d_vi, cur, eidx, OFF_VI, EVIv, NIv, b); return; }
    if ((b -= HG_VI) < HG_VA) { pos_body(s_va, d_va, cur, eidx, OFF_VA, EVAv, NAv, b); return; }
    if ((b -= HG_VA) < HG_TS) { pos_body(s_ts, d_ts, cur, eidx, OFF_TS, ETSv, NSv, b); return; }
    b -= HG_TS;              pos_body(s_ii, d_ii, cur, eidx, OFF_II, EIIv, NIv, b);
}

// ---------------------------------------------------------------------------
// Scans (unchanged)
// ---------------------------------------------------------------------------
__global__ __launch_bounds__(256)
void scan_chunk_sum(const int* __restrict__ deg, int* __restrict__ csum)
{
    __shared__ int sc[256];
    int blk = blockIdx.x, tid = threadIdx.x;
    int base = blk * 1024 + tid * 4;
    int s = 0;
#pragma unroll
    for (int k = 0; k < 4; ++k) { int idx = base + k; if (idx < TOT_N) s += deg[idx]; }
    sc[tid] = s; __syncthreads();
    for (int d = 128; d > 0; d >>= 1) {
        if (tid < d) sc[tid] += sc[tid + d];
        __syncthreads();
    }
    if (tid == 0) csum[blk] = sc[0];
}

__global__ __launch_bounds__(256)
void scan_offsets(const int* __restrict__ csum, int* __restrict__ coff)
{
    __shared__ int sc[256];
    int tid = threadIdx.x;
    int s[5]; int tsum = 0;
#pragma unroll
    for (int k = 0; k < 5; ++k) { int idx = tid * 5 + k; s[k] = (idx < NCH) ? csum[idx] : 0; tsum += s[k]; }
    sc[tid] = tsum; __syncthreads();
    for (int d = 1; d < 256; d <<= 1) {
        int v = (tid >= d) ? sc[tid - d] : 0;
        __syncthreads();
        sc[tid] += v;
        __syncthreads();
    }
    int run = sc[tid] - tsum;   // exclusive
#pragma unroll
    for (int k = 0; k < 5; ++k) { int idx = tid * 5 + k; if (idx < NCH) coff[idx] = run; run += s[k]; }
}

__global__ __launch_bounds__(256)
void scan_write(const int* __restrict__ deg, const int* __restrict__ coff, int* __restrict__ cur)
{
    __shared__ int sc[256];
    int blk = blockIdx.x, tid = threadIdx.x;
    int base = blk * 1024 + tid * 4;
    int v[4]; int tsum = 0;
#pragma unroll
    for (int k = 0; k < 4; ++k) { int idx = base + k; v[k] = (idx < TOT_N) ? deg[idx] : 0; tsum += v[k]; }
    sc[tid] = tsum; __syncthreads();
    for (int d = 1; d < 256; d <<= 1) {
        int t = (tid >= d) ? sc[tid - d] : 0;
        __syncthreads();
        sc[tid] += t;
        __syncthreads();
    }
    int run = coff[blk] + sc[tid] - tsum;
#pragma unroll
    for (int k = 0; k < 4; ++k) { int idx = base + k; if (idx < TOT_N) cur[idx] = run; run += v[k]; }
}

// ---------------------------------------------------------------------------
// Fused sorted-batch boundary scans -> 5 starts arrays
// ---------------------------------------------------------------------------
__device__ __forceinline__ void starts_body(const int* __restrict__ batch, int* __restrict__ start,
                                            int N, int b)
{
    int i = b * 256 + threadIdx.x;
    if (i > N) return;
    if (i == N) {
        int v = batch[N - 1];
        for (int g = v + 1; g <= G_; ++g) start[g] = N;
    } else {
        int v = batch[i];
        int vp = (i == 0) ? -1 : batch[i - 1];
        for (int g = vp + 1; g <= v; ++g) start[g] = i;
    }
}

__global__ __launch_bounds__(256)
void batch_starts_all(const int* __restrict__ bt, const int* __restrict__ bv,
                      const int* __restrict__ bi, const int* __restrict__ ba,
                      const int* __restrict__ bs, int* __restrict__ starts_all)
{
    int b = blockIdx.x;
    if (b < BSB_T) { starts_body(bt, starts_all + 0 * (G_ + 1), NTv, b); return; }
    if ((b -= BSB_T) < BSB_V) { starts_body(bv, starts_all + 1 * (G_ + 1), NVv, b); return; }
    if ((b -= BSB_V) < BSB_I) { starts_body(bi, starts_all + 2 * (G_ + 1), NIv, b); return; }
    if ((b -= BSB_I) < BSB_A) { starts_body(ba, starts_all + 3 * (G_ + 1), NAv, b); return; }
    b -= BSB_A;               starts_body(bs, starts_all + 4 * (G_ + 1), NSv, b);
}

// ---------------------------------------------------------------------------
// Packed weight prep (10 tiny launches, unchanged)
// ---------------------------------------------------------------------------
__global__ __launch_bounds__(256)
void prep_wpack(const float* __restrict__ S0, int L0,
                const float* __restrict__ S1, int L1,
                const float* __restrict__ S2, const float* __restrict__ S2b,
                unsigned short* __restrict__ out, int K1)
{
    int i = blockIdx.x * 256 + threadIdx.x;
    int total = (K1 / 32) * 8 * 512;
    if (i >= total) return;
    int frag = i >> 9;
    int rem  = i & 511;
    int l = rem >> 3, j = rem & 7;
    int ks = frag >> 3, nb = frag & 7;
    int row = nb * 16 + (l & 15);
    int k = ks * 32 + (l >> 4) * 8 + j;
    float v;
    if (k < L0) v = S0[k * 128 + row];
    else if (k < L0 + L1) v = S1[(k - L0) * 128 + row];
    else {
        int kk = k - L0 - L1;
        v = S2[kk * 128 + row];
        if (S2b) v += S2b[kk * 128 + row];
    }
    out[i] = f2bf(v);
}

// ---------------------------------------------------------------------------
// Fused gather + MFMA body. One 64-node tile per block (4 waves).
// Gather: batched width-8 index/row loads (2 latency rounds per batch).
// LDS union: A-tile then h (barrier-fenced). Register-resident weights.
// ---------------------------------------------------------------------------
template<int DSa, int DD, bool HAS2, int ASTR, int K1>
__device__ __forceinline__ void sage_body(int blk, char* sm,
               const int* __restrict__ deg, const int* __restrict__ cur,
               const int* __restrict__ eidx, int off1, int off2,
               const unsigned short* __restrict__ xs1,
               const unsigned short* __restrict__ xs2,
               const unsigned short* __restrict__ xd,
               const unsigned short* __restrict__ W1P,
               const float* __restrict__ bl, const float* __restrict__ bl2,
               const unsigned short* __restrict__ nWP,
               const float* __restrict__ nbp,
               const int* __restrict__ batch,
               float* __restrict__ pool_sum, int N)
{
    constexpr int KST  = K1 / 32;
    constexpr int GCOL = HAS2 ? 2 * DSa : DSa;
    constexpr int XOFF = GCOL;
    constexpr int C8d  = DD / 8;
    constexpr int LPG1 = DSa / 8;
    constexpr int NPW1 = 64 / LPG1;
    constexpr int PASSES = 64 / (4 * NPW1) > 0 ? 64 / (4 * NPW1) : 1;

    unsigned short* a_sh = (unsigned short*)sm;
    unsigned short* h_sh = (unsigned short*)sm;
    int* batch_sh = (int*)(sm + SMEM_TILE);

    const int tid = threadIdx.x;
    const int w = tid >> 6, l = tid & 63, lg = l >> 4, lr = l & 15;
    const int node0 = blk * 64;
    const unsigned swz = (unsigned)(lr & 7) << 4;

    if (tid < 64) batch_sh[tid] = (node0 + tid < N) ? batch[node0 + tid] : -1;

    // ---- x_dst staging (bf16 -> swizzled LDS) ----
    for (int c = tid; c < 64 * C8d; c += 256) {
        int r = c / C8d; int col = (c - r * C8d) * 8; int node = node0 + r;
        uint4 pk = make_uint4(0u, 0u, 0u, 0u);
        if (node < N) pk = *(const uint4*)&xd[(size_t)node * DD + col];
        unsigned byte = ((unsigned)(r * ASTR + XOFF + col) * 2u) ^ ((unsigned)(r & 7) << 4);
        *(uint4*)((char*)a_sh + byte) = pk;
    }

    // ---- batched CSR mean gather -> swizzled LDS A-tile ----
    auto gather_rows = [&](int offx, const unsigned short* __restrict__ xsrc, int colbase) {
#pragma unroll
        for (int ps = 0; ps < PASSES; ++ps) {
            int r = ps * (4 * NPW1) + w * NPW1 + (l / LPG1);
            int col8 = (l % LPG1) * 8;
            int node = node0 + r;
            uint4 o = make_uint4(0u, 0u, 0u, 0u);
            if (node < N) {
                int e_end = cur[offx + node];
                int d     = deg[offx + node];
                int e0    = e_end - d;
                float acc[8] = {0.f, 0.f, 0.f, 0.f, 0.f, 0.f, 0.f, 0.f};
                for (int t = 0; t < d; t += 8) {
                    int rem = d - t;
                    int idx[8];
#pragma unroll
                    for (int k = 0; k < 8; ++k)
                        idx[k] = (k < rem) ? eidx[e0 + t + k] : 0;
                    uint4 v[8];
#pragma unroll
                    for (int k = 0; k < 8; ++k)
                        if (k < rem) v[k] = *(const uint4*)&xsrc[(size_t)idx[k] * DSa + col8];
#pragma unroll
                    for (int k = 0; k < 8; ++k)
                        if (k < rem) addbf8(acc, v[k]);
                }
                float inv = 1.0f / fmaxf((float)d, 1.0f);
                o.x = (unsigned)f2bf(acc[0] * inv) | ((unsigned)f2bf(acc[1] * inv) << 16);
                o.y = (unsigned)f2bf(acc[2] * inv) | ((unsigned)f2bf(acc[3] * inv) << 16);
                o.z = (unsigned)f2bf(acc[4] * inv) | ((unsigned)f2bf(acc[5] * inv) << 16);
                o.w = (unsigned)f2bf(acc[6] * inv) | ((unsigned)f2bf(acc[7] * inv) << 16);
            }
            unsigned byte = ((unsigned)(r * ASTR + colbase + col8) * 2u) ^ ((unsigned)(r & 7) << 4);
            *(uint4*)((char*)a_sh + byte) = o;
        }
    };
    gather_rows(off1, xs1, 0);
    if constexpr (HAS2) gather_rows(off2, xs2, DSa);

    // ---- stage-1 weights -> registers ----
    s16x8 w1[2][KST];
#pragma unroll
    for (int j = 0; j < 2; ++j)
#pragma unroll
        for (int ks = 0; ks < KST; ++ks)
            w1[j][ks] = *(const s16x8*)&W1P[(unsigned)(ks * 8 + (w * 2 + j)) * 512 + (unsigned)l * 8];

    float b1[2];
#pragma unroll
    for (int j = 0; j < 2; ++j) {
        int col = (w * 2 + j) * 16 + lr;
        float b = bl[col];
        if constexpr (HAS2) b += bl2[col];
        b1[j] = b;
    }

    __syncthreads();

    // ---- stage 1: h = A @ W1 ----
    f32x4 acc[4][2];
#pragma unroll
    for (int rf = 0; rf < 4; ++rf)
#pragma unroll
        for (int j = 0; j < 2; ++j) acc[rf][j] = (f32x4){0.f, 0.f, 0.f, 0.f};

#pragma unroll
    for (int ks = 0; ks < KST; ++ks) {
        s16x8 af[4];
#pragma unroll
        for (int rf = 0; rf < 4; ++rf)
            af[rf] = *(const s16x8*)((const char*)a_sh +
                        (((unsigned)((rf * 16 + lr) * ASTR + ks * 32 + lg * 8) * 2u) ^ swz));
#pragma unroll
        for (int rf = 0; rf < 4; ++rf)
#pragma unroll
            for (int j = 0; j < 2; ++j)
                acc[rf][j] = __builtin_amdgcn_mfma_f32_16x16x32_bf16(af[rf], w1[j][ks], acc[rf][j], 0, 0, 0);
    }

    __syncthreads();   // A-tile reads complete before h overwrites the union

    // ---- bias + relu -> bf16 h in LDS ----
#pragma unroll
    for (int rf = 0; rf < 4; ++rf)
#pragma unroll
        for (int j = 0; j < 2; ++j) {
            int col = (w * 2 + j) * 16 + lr;
#pragma unroll
            for (int rg = 0; rg < 4; ++rg) {
                float hv = fmaxf(acc[rf][j][rg] + b1[j], 0.0f);
                int row = rf * 16 + lg * 4 + rg;
                unsigned byte = ((unsigned)(row * 128 + col) * 2u) ^ ((unsigned)(row & 7) << 4);
                *(unsigned short*)((char*)h_sh + byte) = f2bf(hv);
            }
        }

    // ---- stage-2 weights -> registers ----
    s16x8 w2[2][4];
#pragma unroll
    for (int j = 0; j < 2; ++j)
#pragma unroll
        for (int ks = 0; ks < 4; ++ks)
            w2[j][ks] = *(const s16x8*)&nWP[(unsigned)(ks * 8 + (w * 2 + j)) * 512 + (unsigned)l * 8];

    float nbv[2];
#pragma unroll
    for (int j = 0; j < 2; ++j) nbv[j] = nbp[(w * 2 + j) * 16 + lr];

    __syncthreads();

    // ---- stage 2: z = h @ nW ----
    f32x4 acc2[4][2];
#pragma unroll
    for (int rf = 0; rf < 4; ++rf)
#pragma unroll
        for (int j = 0; j < 2; ++j) acc2[rf][j] = (f32x4){0.f, 0.f, 0.f, 0.f};

#pragma unroll
    for (int ks = 0; ks < 4; ++ks) {
        s16x8 hf[4];
#pragma unroll
        for (int rf = 0; rf < 4; ++rf)
            hf[rf] = *(const s16x8*)((const char*)h_sh +
                        (((unsigned)((rf * 16 + lr) * 128 + ks * 32 + lg * 8) * 2u) ^ swz));
#pragma unroll
        for (int rf = 0; rf < 4; ++rf)
#pragma unroll
            for (int j = 0; j < 2; ++j)
                acc2[rf][j] = __builtin_amdgcn_mfma_f32_16x16x32_bf16(hf[rf], w2[j][ks], acc2[rf][j], 0, 0, 0);
    }

    // ---- pooling ----
#pragma unroll
    for (int rf = 0; rf < 4; ++rf) {
        int gf = batch_sh[rf * 16];
        int gl = batch_sh[rf * 16 + 15];
        if (gf == gl && gf >= 0) {
#pragma unroll
            for (int j = 0; j < 2; ++j) {
                float s = acc2[rf][j][0] + acc2[rf][j][1] + acc2[rf][j][2] + acc2[rf][j][3]
                        + 4.0f * nbv[j];
                s += __shfl_xor(s, 16);
                s += __shfl_xor(s, 32);
                if (lg == 0)
                    atomicAdd(&pool_sum[gf * 128 + (w * 2 + j) * 16 + lr], s);
            }
        } else {
            int rbase = rf * 16 + lg * 4;
            int bt[4];
#pragma unroll
            for (int rg = 0; rg < 4; ++rg) bt[rg] = batch_sh[rbase + rg];
#pragma unroll
            for (int j = 0; j < 2; ++j) {
                int col = (w * 2 + j) * 16 + lr;
                float run = acc2[rf][j][0] + nbv[j];
                int cb = bt[0];
#pragma unroll
                for (int rg = 1; rg < 4; ++rg) {
                    float z = acc2[rf][j][rg] + nbv[j];
                    if (bt[rg] == cb) run += z;
                    else {
                        if (cb >= 0) atomicAdd(&pool_sum[cb * 128 + col], run);
                        cb = bt[rg]; run = z;
                    }
                }
                if (cb >= 0) atomicAdd(&pool_sum[cb * 128 + col], run);
            }
        }
    }
}

// ---------------------------------------------------------------------------
// Fused dispatcher over all 5 node types (value first; short types in tail).
// ---------------------------------------------------------------------------
__global__ __launch_bounds__(256, 3)
void sage_all(const int* __restrict__ deg, const int* __restrict__ cur,
              const int* __restrict__ eidx,
              const unsigned short* __restrict__ xbv, const unsigned short* __restrict__ xbt,
              const unsigned short* __restrict__ xbi, const unsigned short* __restrict__ xba,
              const unsigned short* __restrict__ xbs,
              const unsigned short* __restrict__ w1p_vt, const unsigned short* __restrict__ w1p_iv,
              const unsigned short* __restrict__ w1p_vi, const unsigned short* __restrict__ w1p_va,
              const unsigned short* __restrict__ w1p_ts,
              const unsigned short* __restrict__ nwp_t, const unsigned short* __restrict__ nwp_v,
              const unsigned short* __restrict__ nwp_i, const unsigned short* __restrict__ nwp_a,
              const unsigned short* __restrict__ nwp_s,
              const float* __restrict__ bl_vt, const float* __restrict__ bl_iv,
              const float* __restrict__ bl_vi, const float* __restrict__ bl_va,
              const float* __restrict__ bl_ts, const float* __restrict__ bl_ii,
              const float* __restrict__ nb_t, const float* __restrict__ nb_v,
              const float* __restrict__ nb_i, const float* __restrict__ nb_a,
              const float* __restrict__ nb_s,
              const int* __restrict__ batch_t, const int* __restrict__ batch_v,
              const int* __restrict__ batch_i, const int* __restrict__ batch_a,
              const int* __restrict__ batch_s,
              float* __restrict__ pool_sum)
{
    extern __shared__ char dynsm[];
    int b = blockIdx.x;
    if (b < SB_V) {
        sage_body<64, 64, false, 128, 128>(b, dynsm, deg, cur, eidx, OFF_IV, 0,
            xbi, nullptr, xbv, w1p_iv, bl_iv, nullptr, nwp_v, nb_v, batch_v,
            pool_sum + (size_t)1 * G_ * HID, NVv);
        return;
    }
    if ((b -= SB_V) < SB_I) {
        sage_body<64, 64, true, 192, 192>(b, dynsm, deg, cur, eidx, OFF_VI, OFF_II,
            xbv, xbi, xbi, w1p_vi, bl_vi, bl_ii, nwp_i, nb_i, batch_i,
            pool_sum + (size_t)2 * G_ * HID, NIv);
        return;
    }
    if ((b -= SB_I) < SB_T) {
        sage_body<64, 32, false, 128, 96>(b, dynsm, deg, cur, eidx, OFF_VT, 0,
            xbv, nullptr, xbt, w1p_vt, bl_vt, nullptr, nwp_t, nb_t, batch_t,
            pool_sum + (size_t)0 * G_ * HID, NTv);
        return;
    }
    if ((b -= SB_T) < SB_A) {
        sage_body<64, 32, false, 128, 96>(b, dynsm, deg, cur, eidx, OFF_VA, 0,
            xbv, nullptr, xba, w1p_va, bl_va, nullptr, nwp_a, nb_a, batch_a,
            pool_sum + (size_t)3 * G_ * HID, NAv);
        return;
    }
    b -= SB_A;
    sage_body<32, 32, false, 64, 64>(b, dynsm, deg, cur, eidx, OFF_TS, 0,
        xbt, nullptr, xbs, w1p_ts, bl_ts, nullptr, nwp_s, nb_s, batch_s,
        pool_sum + (size_t)4 * G_ * HID, NSv);
}

// ---------------------------------------------------------------------------
__global__ __launch_bounds__(64)
void final_kernel(const float* __restrict__ pool_sum, const int* __restrict__ starts_all,
                  const float* __restrict__ gW, const float* __restrict__ gb,
                  float* __restrict__ out)
{
    __shared__ float p_sh[5 * HID];
    int g = blockIdx.x, tid = threadIdx.x;
    for (int i = tid; i < 5 * HID; i += 64) {
        int t  = i >> 7;
        int jj = i & 127;
        const int* st = starts_all + t * (G_ + 1);
        float c = fmaxf((float)(st[g + 1] - st[g]), 1.0f);
        p_sh[i] = pool_sum[((size_t)t * G_ + g) * HID + jj] / c;
    }
    __syncthreads();
    float acc = gb[tid];
#pragma unroll 8
    for (int k = 0; k < 5 * HID; ++k)
        acc += p_sh[k] * gW[k * 64 + tid];
    out[g * 64 + tid] = acc;
}

// ---------------------------------------------------------------------------
extern "C" void kernel_launch(void* const* d_in, const int* in_sizes, int n_in,
                              void* d_out, int out_size, void* d_ws, size_t ws_size,
                              hipStream_t stream)
{
    const float* x_value       = (const float*)d_in[0];
    const float* x_typ         = (const float*)d_in[1];
    const float* x_size_       = (const float*)d_in[2];
    const float* x_attribute   = (const float*)d_in[3];
    const float* x_instruction = (const float*)d_in[4];
    const float* Wl_vt = (const float*)d_in[5];
    const float* bl_vt = (const float*)d_in[6];
    const float* Wr_vt = (const float*)d_in[7];
    const float* Wl_iv = (const float*)d_in[8];
    const float* bl_iv = (const float*)d_in[9];
    const float* Wr_iv = (const float*)d_in[10];
    const float* Wl_vi = (const float*)d_in[11];
    const float* bl_vi = (const float*)d_in[12];
    const float* Wr_vi = (const float*)d_in[13];
    const float* Wl_va = (const float*)d_in[14];
    const float* bl_va = (const float*)d_in[15];
    const float* Wr_va = (const float*)d_in[16];
    const float* Wl_ts = (const float*)d_in[17];
    const float* bl_ts = (const float*)d_in[18];
    const float* Wr_ts = (const float*)d_in[19];
    const float* Wl_ii = (const float*)d_in[20];
    const float* bl_ii = (const float*)d_in[21];
    const float* Wr_ii = (const float*)d_in[22];
    const float* nW_typ         = (const float*)d_in[23];
    const float* nb_typ         = (const float*)d_in[24];
    const float* nW_value       = (const float*)d_in[25];
    const float* nb_value       = (const float*)d_in[26];
    const float* nW_instruction = (const float*)d_in[27];
    const float* nb_instruction = (const float*)d_in[28];
    const float* nW_attribute   = (const float*)d_in[29];
    const float* nb_attribute   = (const float*)d_in[30];
    const float* nW_size        = (const float*)d_in[31];
    const float* nb_size        = (const float*)d_in[32];
    const float* gW = (const float*)d_in[33];
    const float* gb = (const float*)d_in[34];
    const int* src_vt = (const int*)d_in[35];
    const int* dst_vt = (const int*)d_in[36];
    const int* src_iv = (const int*)d_in[37];
    const int* dst_iv = (const int*)d_in[38];
    const int* src_vi = (const int*)d_in[39];
    const int* dst_vi = (const int*)d_in[40];
    const int* src_va = (const int*)d_in[41];
    const int* dst_va = (const int*)d_in[42];
    const int* src_ts = (const int*)d_in[43];
    const int* dst_ts = (const int*)d_in[44];
    const int* src_ii = (const int*)d_in[45];
    const int* dst_ii = (const int*)d_in[46];
    const int* batch_typ         = (const int*)d_in[47];
    const int* batch_value       = (const int*)d_in[48];
    const int* batch_instruction = (const int*)d_in[49];
    const int* batch_attribute   = (const int*)d_in[50];
    const int* batch_size        = (const int*)d_in[51];

    // ---- workspace layout ----
    int* deg = (int*)d_ws;                                   // TOT_N (zeroed)
    float* pool_sum = (float*)(deg + TOT_N);                 // 5*G*HID (zeroed)
    size_t zero_bytes = (size_t)TOT_N * 4 + (size_t)5 * G_ * HID * 4;

    int* cur        = (int*)(pool_sum + (size_t)5 * G_ * HID);  // TOT_N
    int* csum       = cur + TOT_N;                              // NCH
    int* coff       = csum + NCH;                               // NCH
    int* eidx       = coff + NCH;                               // TOT_E
    int* starts_all = eidx + TOT_E;                             // 5*(G_+1)
    // bf16 feature tables
    unsigned short* xb = (unsigned short*)(((uintptr_t)(starts_all + 5 * (G_ + 1)) + 63) & ~(uintptr_t)63);
    size_t xo = 0;
    unsigned short* xb_value = xb + xo; xo += (size_t)NVv * 64;
    unsigned short* xb_typ   = xb + xo; xo += (size_t)NTv * 32;
    unsigned short* xb_instr = xb + xo; xo += (size_t)NIv * 64;
    unsigned short* xb_attr  = xb + xo; xo += (size_t)NAv * 32;
    unsigned short* xb_size  = xb + xo; xo += (size_t)NSv * 32;
    unsigned short* wt = (unsigned short*)(((uintptr_t)(xb + xo) + 63) & ~(uintptr_t)63);
    size_t wo = 0;
    unsigned short* w1p_vt = wt + wo; wo += 128 * 96;
    unsigned short* w1p_iv = wt + wo; wo += 128 * 128;
    unsigned short* w1p_vi = wt + wo; wo += 128 * 192;
    unsigned short* w1p_va = wt + wo; wo += 128 * 96;
    unsigned short* w1p_ts = wt + wo; wo += 128 * 64;
    unsigned short* nwp_t  = wt + wo; wo += 128 * 128;
    unsigned short* nwp_v  = wt + wo; wo += 128 * 128;
    unsigned short* nwp_i  = wt + wo; wo += 128 * 128;
    unsigned short* nwp_a  = wt + wo; wo += 128 * 128;
    unsigned short* nwp_s  = wt + wo; wo += 128 * 128;

    hipMemsetAsync(d_ws, 0, zero_bytes, stream);

    // fused bf16 feature-table conversion
    conv_all<<<CB_TOT, 256, 0, stream>>>(x_value, x_typ, x_instruction, x_attribute, x_size_,
                                         xb_value, xb_typ, xb_instr, xb_attr, xb_size);

    // packed weight prep (tiny)
    prep_wpack<<<(128 *  96 + 255) / 256, 256, 0, stream>>>(Wl_vt, 64, nullptr, 0, Wr_vt, nullptr, w1p_vt,  96);
    prep_wpack<<<(128 * 128 + 255) / 256, 256, 0, stream>>>(Wl_iv, 64, nullptr, 0, Wr_iv, nullptr, w1p_iv, 128);
    prep_wpack<<<(128 * 192 + 255) / 256, 256, 0, stream>>>(Wl_vi, 64, Wl_ii, 64, Wr_vi, Wr_ii,   w1p_vi, 192);
    prep_wpack<<<(128 *  96 + 255) / 256, 256, 0, stream>>>(Wl_va, 64, nullptr, 0, Wr_va, nullptr, w1p_va,  96);
    prep_wpack<<<(128 *  64 + 255) / 256, 256, 0, stream>>>(Wl_ts, 32, nullptr, 0, Wr_ts, nullptr, w1p_ts,  64);
    prep_wpack<<<(128 * 128 + 255) / 256, 256, 0, stream>>>(nW_typ,         128, nullptr, 0, nullptr, nullptr, nwp_t, 128);
    prep_wpack<<<(128 * 128 + 255) / 256, 256, 0, stream>>>(nW_value,       128, nullptr, 0, nullptr, nullptr, nwp_v, 128);
    prep_wpack<<<(128 * 128 + 255) / 256, 256, 0, stream>>>(nW_instruction, 128, nullptr, 0, nullptr, nullptr, nwp_i, 128);
    prep_wpack<<<(128 * 128 + 255) / 256, 256, 0, stream>>>(nW_attribute,   128, nullptr, 0, nullptr, nullptr, nwp_a, 128);
    prep_wpack<<<(128 * 128 + 255) / 256, 256, 0, stream>>>(nW_size,        128, nullptr, 0, nullptr, nullptr, nwp_s, 128);

    // fused CSR build (XCD-localized inside each type segment)
    edge_hist_all<<<HG_TOT, 256, 0, stream>>>(dst_vt, dst_iv, dst_vi, dst_va, dst_ts, dst_ii, deg);

    scan_chunk_sum<<<NCH, 256, 0, stream>>>(deg, csum);
    scan_offsets<<<1, 256, 0, stream>>>(csum, coff);
    scan_write<<<NCH, 256, 0, stream>>>(deg, coff, cur);

    edge_pos_all<<<HG_TOT, 256, 0, stream>>>(src_vt, dst_vt, src_iv, dst_iv, src_vi, dst_vi,
                                             src_va, dst_va, src_ts, dst_ts, src_ii, dst_ii,
                                             cur, eidx);

    // fused sorted-batch boundary scans
    batch_starts_all<<<BSB_TOT, 256, 0, stream>>>(batch_typ, batch_value, batch_instruction,
                                                  batch_attribute, batch_size, starts_all);

    // fused gather + MFMA over all node types
    sage_all<<<SB_TOT, 256, SMEM_BYTES, stream>>>(
        deg, cur, eidx,
        xb_value, xb_typ, xb_instr, xb_attr, xb_size,
        w1p_vt, w1p_iv, w1p_vi, w1p_va, w1p_ts,
        nwp_t, nwp_v, nwp_i, nwp_a, nwp_s,
        bl_vt, bl_iv, bl_vi, bl_va, bl_ts, bl_ii,
        nb_typ, nb_value, nb_instruction, nb_attribute, nb_size,
        batch_typ, batch_value, batch_instruction, batch_attribute, batch_size,
        pool_sum);

    final_kernel<<<G_, 64, 0, stream>>>(pool_sum, starts_all, gW, gb, (float*)d_out);
}